// Round 1
// baseline (3519.931 us; speedup 1.0000x reference)
//
#include <hip/hip_runtime.h>

// VGAE encoder: 3x GCNConv (improved=True) on N=100000 nodes, E=1600000 edges.
// Key restructuring: Agg(X @ W) == Agg(X) @ W (aggregation is linear), so:
//   ax = Agg(x);  h = relu(ax @ W1 + b1);  ah = Agg(h);
//   z_mean = ah @ Wm + bm;  z_logstd = ah @ Ws + bs.
// Only TWO edge passes instead of three.

#define DIM 128
#define LAT 32

// deg[i] = 2 (self loop weight, improved=True)
__global__ void k_deg_init(float* __restrict__ deg, int N) {
    int i = blockIdx.x * blockDim.x + threadIdx.x;
    if (i < N) deg[i] = 2.0f;
}

// deg[dst[e]] += ew[e]
__global__ void k_deg_acc(const int* __restrict__ dst, const float* __restrict__ ew,
                          float* __restrict__ deg, int E) {
    int e = blockIdx.x * blockDim.x + threadIdx.x;
    if (e < E) unsafeAtomicAdd(&deg[dst[e]], ew[e]);
}

// in-place deg -> dinv = rsqrt(deg) (deg >= 2 always, keep the >0 guard to match ref)
__global__ void k_dinv(float* __restrict__ deg, int N) {
    int i = blockIdx.x * blockDim.x + threadIdx.x;
    if (i < N) {
        float d = deg[i];
        deg[i] = (d > 0.0f) ? rsqrtf(d) : 0.0f;
    }
}

// out[i][:] = 2*dinv[i]^2 * xin[i][:]   (self-loop contribution == scatter init)
// one thread per float4, N*32 threads
__global__ void k_selfloop_init(const float* __restrict__ xin, const float* __restrict__ dinv,
                                float* __restrict__ out, int N) {
    int i = blockIdx.x * blockDim.x + threadIdx.x;
    int node = i >> 5;
    if (node < N) {
        float s = dinv[node];
        s = 2.0f * s * s;
        float4 v = reinterpret_cast<const float4*>(xin)[i];
        v.x *= s; v.y *= s; v.z *= s; v.w *= s;
        reinterpret_cast<float4*>(out)[i] = v;
    }
}

// one wavefront (64 lanes) per edge; lane handles 2 consecutive floats
__global__ void k_agg(const int* __restrict__ src, const int* __restrict__ dst,
                      const float* __restrict__ ew, const float* __restrict__ dinv,
                      const float* __restrict__ xin, float* __restrict__ out, int E) {
    int gid = blockIdx.x * blockDim.x + threadIdx.x;
    int e = gid >> 6;
    int lane = gid & 63;
    if (e >= E) return;
    int s = src[e];
    int d = dst[e];
    float nrm = dinv[s] * ew[e] * dinv[d];
    float2 v = reinterpret_cast<const float2*>(xin + (size_t)s * DIM)[lane];
    float* o = out + (size_t)d * DIM + lane * 2;
    unsafeAtomicAdd(o + 0, v.x * nrm);
    unsafeAtomicAdd(o + 1, v.y * nrm);
}

// H = relu(A @ W + b), A:[N,128], W:[128,128]. Block = 16 rows x 128 cols;
// thread (col, ty) computes 8 rows. W rows broadcast from L2 (64KB, stays hot).
__global__ __launch_bounds__(256) void k_gemm_relu(const float* __restrict__ A,
                                                   const float* __restrict__ W,
                                                   const float* __restrict__ b,
                                                   float* __restrict__ H, int N) {
    const int col = threadIdx.x & 127;
    const int ty = threadIdx.x >> 7;        // 0..1
    const int row0 = blockIdx.x * 16 + ty * 8;
    float acc[8];
#pragma unroll
    for (int j = 0; j < 8; ++j) acc[j] = 0.0f;
    const float* a = A + (size_t)row0 * DIM;
    for (int k = 0; k < DIM; k += 4) {
        float w0 = W[(k + 0) * DIM + col];
        float w1 = W[(k + 1) * DIM + col];
        float w2 = W[(k + 2) * DIM + col];
        float w3 = W[(k + 3) * DIM + col];
#pragma unroll
        for (int j = 0; j < 8; ++j) {
            float4 v = *reinterpret_cast<const float4*>(a + j * DIM + k);
            acc[j] = fmaf(v.x, w0, acc[j]);
            acc[j] = fmaf(v.y, w1, acc[j]);
            acc[j] = fmaf(v.z, w2, acc[j]);
            acc[j] = fmaf(v.w, w3, acc[j]);
        }
    }
    float bb = b[col];
#pragma unroll
    for (int j = 0; j < 8; ++j) {
        int r = row0 + j;
        if (r < N) {
            float v = acc[j] + bb;
            H[(size_t)r * DIM + col] = (v > 0.0f) ? v : 0.0f;
        }
    }
}

// fused final GEMM: [N,128] @ [128,64] where cols 0..31 -> Wm/bm -> outm,
// cols 32..63 -> Ws/bs -> outs. Wcat staged in LDS (32KB).
__global__ __launch_bounds__(256) void k_gemm2(const float* __restrict__ A,
                                               const float* __restrict__ Wm,
                                               const float* __restrict__ bm,
                                               const float* __restrict__ Ws,
                                               const float* __restrict__ bs,
                                               float* __restrict__ outm,
                                               float* __restrict__ outs, int N) {
    __shared__ float wl[DIM * 64];
    for (int idx = threadIdx.x; idx < DIM * 64; idx += 256) {
        int k = idx >> 6;
        int c = idx & 63;
        wl[idx] = (c < LAT) ? Wm[k * LAT + c] : Ws[k * LAT + (c - LAT)];
    }
    __syncthreads();
    const int col = threadIdx.x & 63;
    const int ty = threadIdx.x >> 6;        // 0..3
    const int row0 = blockIdx.x * 16 + ty * 4;
    float acc[4];
#pragma unroll
    for (int j = 0; j < 4; ++j) acc[j] = 0.0f;
    const float* a = A + (size_t)row0 * DIM;
    for (int k = 0; k < DIM; k += 4) {
        float w0 = wl[(k + 0) * 64 + col];
        float w1 = wl[(k + 1) * 64 + col];
        float w2 = wl[(k + 2) * 64 + col];
        float w3 = wl[(k + 3) * 64 + col];
#pragma unroll
        for (int j = 0; j < 4; ++j) {
            float4 v = *reinterpret_cast<const float4*>(a + j * DIM + k);
            acc[j] = fmaf(v.x, w0, acc[j]);
            acc[j] = fmaf(v.y, w1, acc[j]);
            acc[j] = fmaf(v.z, w2, acc[j]);
            acc[j] = fmaf(v.w, w3, acc[j]);
        }
    }
    float bias = (col < LAT) ? bm[col] : bs[col - LAT];
#pragma unroll
    for (int j = 0; j < 4; ++j) {
        int r = row0 + j;
        if (r < N) {
            float v = acc[j] + bias;
            if (col < LAT)
                outm[(size_t)r * LAT + col] = v;
            else
                outs[(size_t)r * LAT + (col - LAT)] = v;
        }
    }
}

extern "C" void kernel_launch(void* const* d_in, const int* in_sizes, int n_in,
                              void* d_out, int out_size, void* d_ws, size_t ws_size,
                              hipStream_t stream) {
    const float* x  = (const float*)d_in[0];
    const int*   ei = (const int*)d_in[1];
    const float* ew = (const float*)d_in[2];
    const float* W1 = (const float*)d_in[3];
    const float* b1 = (const float*)d_in[4];
    const float* Wm = (const float*)d_in[5];
    const float* bm = (const float*)d_in[6];
    const float* Ws = (const float*)d_in[7];
    const float* bs = (const float*)d_in[8];

    const int N = in_sizes[0] / DIM;     // 100000
    const int E = in_sizes[1] / 2;       // 1600000
    const int* src = ei;
    const int* dst = ei + E;

    // workspace layout (floats): dinv [N, padded], ax [N*128], h [N*128]; ah reuses ax
    float* dinv = (float*)d_ws;
    float* ax = dinv + (((size_t)N + 63) & ~(size_t)63);
    float* h = ax + (size_t)N * DIM;

    float* outm = (float*)d_out;
    float* outs = outm + (size_t)N * LAT;

    const int B = 256;
    // 1. degrees -> dinv
    k_deg_init<<<(N + B - 1) / B, B, 0, stream>>>(dinv, N);
    k_deg_acc<<<(E + B - 1) / B, B, 0, stream>>>(dst, ew, dinv, E);
    k_dinv<<<(N + B - 1) / B, B, 0, stream>>>(dinv, N);

    // 2. ax = Agg(x)
    k_selfloop_init<<<((size_t)N * 32 + B - 1) / B, B, 0, stream>>>(x, dinv, ax, N);
    k_agg<<<((size_t)E * 64 + B - 1) / B, B, 0, stream>>>(src, dst, ew, dinv, x, ax, E);

    // 3. h = relu(ax @ W1 + b1)
    k_gemm_relu<<<(N + 15) / 16, B, 0, stream>>>(ax, W1, b1, h, N);

    // 4. ah = Agg(h)  (reuse ax buffer)
    k_selfloop_init<<<((size_t)N * 32 + B - 1) / B, B, 0, stream>>>(h, dinv, ax, N);
    k_agg<<<((size_t)E * 64 + B - 1) / B, B, 0, stream>>>(src, dst, ew, dinv, h, ax, E);

    // 5. outputs
    k_gemm2<<<(N + 15) / 16, B, 0, stream>>>(ax, Wm, bm, Ws, bs, outm, outs, N);
}

// Round 3
// 1135.106 us; speedup vs baseline: 3.1010x; 3.1010x over previous
//
#include <hip/hip_runtime.h>

// VGAE encoder: 3x GCNConv (improved=True), N=100000, E=1600000.
// Restructuring:
//   Agg(X @ W) == Agg(X) @ W  (aggregation linear)  =>
//   ax = Agg(x); h = relu(ax@W1+b1)  [in-place over ax, barrier-protected];
//   hw = h @ [Wm|Ws]  [N,64]; z = Agg(hw) + [bm|bs]   (second agg on 64 dims, not 128)
// Aggregation via on-device CSR (by dst) + per-node gather-reduce: NO float atomics.

#define DIM 128
#define LAT 32
#define SCAN_ELEMS 1024   // 256 threads x 4

__global__ void k_deg_init(float* __restrict__ deg, int N) {
    int i = blockIdx.x * blockDim.x + threadIdx.x;
    if (i < N) deg[i] = 2.0f;   // improved=True self-loop weight
}

// histogram of dst (for CSR) + weighted degree accumulation, one pass
__global__ void k_edge_hist(const int* __restrict__ dst, const float* __restrict__ ew,
                            float* __restrict__ deg, int* __restrict__ counts, int E) {
    int e = blockIdx.x * blockDim.x + threadIdx.x;
    if (e < E) {
        int d = dst[e];
        atomicAdd(&counts[d], 1);
        unsafeAtomicAdd(&deg[d], ew[e]);
    }
}

__global__ void k_dinv(float* __restrict__ deg, int N) {
    int i = blockIdx.x * blockDim.x + threadIdx.x;
    if (i < N) {
        float d = deg[i];
        deg[i] = (d > 0.0f) ? rsqrtf(d) : 0.0f;
    }
}

// ---- exclusive scan of counts -> rowptr (3 kernels) ----
__global__ __launch_bounds__(256) void k_scan1(const int* __restrict__ counts,
                                               int* __restrict__ rowptr,
                                               int* __restrict__ bsums, int N) {
    __shared__ int sdata[256];
    const int t = threadIdx.x;
    const int base = blockIdx.x * SCAN_ELEMS + t * 4;
    int v[4];
#pragma unroll
    for (int j = 0; j < 4; ++j) {
        int idx = base + j;
        v[j] = (idx < N) ? counts[idx] : 0;
    }
    int tot = v[0] + v[1] + v[2] + v[3];
    sdata[t] = tot;
    __syncthreads();
    for (int off = 1; off < 256; off <<= 1) {
        int x = 0;
        if (t >= off) x = sdata[t - off];
        __syncthreads();
        if (t >= off) sdata[t] += x;
        __syncthreads();
    }
    int running = sdata[t] - tot;   // exclusive prefix of this thread within block
#pragma unroll
    for (int j = 0; j < 4; ++j) {
        int idx = base + j;
        if (idx < N) rowptr[idx] = running;
        running += v[j];
    }
    if (t == 255) bsums[blockIdx.x] = sdata[255];
}

__global__ void k_scan2(int* __restrict__ bsums, int* __restrict__ rowptr, int NB, int N, int E) {
    // single thread: exclusive scan of block sums; set rowptr[N]=E
    int running = 0;
    for (int b = 0; b < NB; ++b) {
        int t = bsums[b];
        bsums[b] = running;
        running += t;
    }
    rowptr[N] = E;
}

__global__ void k_scan3(int* __restrict__ rowptr, const int* __restrict__ bsums, int N) {
    int i = blockIdx.x * blockDim.x + threadIdx.x;
    if (i < N) rowptr[i] += bsums[i >> 10];
}

// scatter edges into CSR slots: record = {src, norm bits}
__global__ void k_scatter(const int* __restrict__ src, const int* __restrict__ dst,
                          const float* __restrict__ ew, const float* __restrict__ dinv,
                          const int* __restrict__ rowptr, int* __restrict__ cursor,
                          int2* __restrict__ csr, int E) {
    int e = blockIdx.x * blockDim.x + threadIdx.x;
    if (e < E) {
        int s = src[e];
        int d = dst[e];
        float nrm = dinv[s] * ew[e] * dinv[d];
        int pos = rowptr[d] + atomicAdd(&cursor[d], 1);
        csr[pos] = make_int2(s, __float_as_int(nrm));
    }
}

// one wave per node, lane = float2 of the 128-dim row; acc init = self-loop term
__global__ __launch_bounds__(256) void k_gather128(const int2* __restrict__ csr,
                                                   const int* __restrict__ rowptr,
                                                   const float* __restrict__ dinv,
                                                   const float* __restrict__ xin,
                                                   float* __restrict__ out, int N) {
    int node = (blockIdx.x * 256 + threadIdx.x) >> 6;
    int lane = threadIdx.x & 63;
    if (node >= N) return;
    float s = dinv[node];
    float sl = 2.0f * s * s;
    float2 acc = reinterpret_cast<const float2*>(xin + (size_t)node * DIM)[lane];
    acc.x *= sl; acc.y *= sl;
    int p = rowptr[node], end = rowptr[node + 1];
    for (; p + 1 < end; p += 2) {
        int2 e0 = csr[p];
        int2 e1 = csr[p + 1];
        float n0 = __int_as_float(e0.y);
        float n1 = __int_as_float(e1.y);
        float2 u0 = reinterpret_cast<const float2*>(xin + (size_t)e0.x * DIM)[lane];
        float2 u1 = reinterpret_cast<const float2*>(xin + (size_t)e1.x * DIM)[lane];
        acc.x = fmaf(u0.x, n0, acc.x); acc.y = fmaf(u0.y, n0, acc.y);
        acc.x = fmaf(u1.x, n1, acc.x); acc.y = fmaf(u1.y, n1, acc.y);
    }
    if (p < end) {
        int2 e0 = csr[p];
        float n0 = __int_as_float(e0.y);
        float2 u0 = reinterpret_cast<const float2*>(xin + (size_t)e0.x * DIM)[lane];
        acc.x = fmaf(u0.x, n0, acc.x); acc.y = fmaf(u0.y, n0, acc.y);
    }
    reinterpret_cast<float2*>(out + (size_t)node * DIM)[lane] = acc;
}

// H = relu(A @ W + b), supports A == H (in-place):
// the __syncthreads() after the k-loop guarantees every wave in the block has
// consumed ALL its reads of the block's 16 rows into registers before any
// wave writes (waves write disjoint col-halves but read the full 128 cols).
// Blocks own disjoint rows, so no cross-block hazard.
__global__ __launch_bounds__(256) void k_gemm_relu(const float* __restrict__ A,
                                                   const float* __restrict__ W,
                                                   const float* __restrict__ b,
                                                   float* __restrict__ H, int N) {
    const int col = threadIdx.x & 127;
    const int ty = threadIdx.x >> 7;        // 0..1
    const int row0 = blockIdx.x * 16 + ty * 8;
    float acc[8];
#pragma unroll
    for (int j = 0; j < 8; ++j) acc[j] = 0.0f;
    const float* a = A + (size_t)row0 * DIM;
    for (int k = 0; k < DIM; k += 4) {
        float w0 = W[(k + 0) * DIM + col];
        float w1 = W[(k + 1) * DIM + col];
        float w2 = W[(k + 2) * DIM + col];
        float w3 = W[(k + 3) * DIM + col];
#pragma unroll
        for (int j = 0; j < 8; ++j) {
            float4 v = *reinterpret_cast<const float4*>(a + j * DIM + k);
            acc[j] = fmaf(v.x, w0, acc[j]);
            acc[j] = fmaf(v.y, w1, acc[j]);
            acc[j] = fmaf(v.z, w2, acc[j]);
            acc[j] = fmaf(v.w, w3, acc[j]);
        }
    }
    __syncthreads();   // in-place safety: all reads done before any write
    float bb = b[col];
#pragma unroll
    for (int j = 0; j < 8; ++j) {
        int r = row0 + j;
        if (r < N) {
            float v = acc[j] + bb;
            H[(size_t)r * DIM + col] = (v > 0.0f) ? v : 0.0f;
        }
    }
}

// hw = H @ [Wm|Ws]  -> [N,64] contiguous, no bias (bias added in gather64)
__global__ __launch_bounds__(256) void k_gemmcat(const float* __restrict__ A,
                                                 const float* __restrict__ Wm,
                                                 const float* __restrict__ Ws,
                                                 float* __restrict__ hw, int N) {
    __shared__ float wl[DIM * 64];
    for (int idx = threadIdx.x; idx < DIM * 64; idx += 256) {
        int k = idx >> 6;
        int c = idx & 63;
        wl[idx] = (c < LAT) ? Wm[k * LAT + c] : Ws[k * LAT + (c - LAT)];
    }
    __syncthreads();
    const int col = threadIdx.x & 63;
    const int ty = threadIdx.x >> 6;        // 0..3
    const int row0 = blockIdx.x * 16 + ty * 4;
    float acc[4];
#pragma unroll
    for (int j = 0; j < 4; ++j) acc[j] = 0.0f;
    const float* a = A + (size_t)row0 * DIM;
    for (int k = 0; k < DIM; k += 4) {
        float w0 = wl[(k + 0) * 64 + col];
        float w1 = wl[(k + 1) * 64 + col];
        float w2 = wl[(k + 2) * 64 + col];
        float w3 = wl[(k + 3) * 64 + col];
#pragma unroll
        for (int j = 0; j < 4; ++j) {
            float4 v = *reinterpret_cast<const float4*>(a + j * DIM + k);
            acc[j] = fmaf(v.x, w0, acc[j]);
            acc[j] = fmaf(v.y, w1, acc[j]);
            acc[j] = fmaf(v.z, w2, acc[j]);
            acc[j] = fmaf(v.w, w3, acc[j]);
        }
    }
#pragma unroll
    for (int j = 0; j < 4; ++j) {
        int r = row0 + j;
        if (r < N) hw[(size_t)r * 64 + col] = acc[j];
    }
}

// one wave per node over 64 dims; adds bias, writes split outputs
__global__ __launch_bounds__(256) void k_gather64(const int2* __restrict__ csr,
                                                  const int* __restrict__ rowptr,
                                                  const float* __restrict__ dinv,
                                                  const float* __restrict__ hw,
                                                  const float* __restrict__ bm,
                                                  const float* __restrict__ bs,
                                                  float* __restrict__ outm,
                                                  float* __restrict__ outs, int N) {
    int node = (blockIdx.x * 256 + threadIdx.x) >> 6;
    int lane = threadIdx.x & 63;
    if (node >= N) return;
    float s = dinv[node];
    float sl = 2.0f * s * s;
    float acc = hw[(size_t)node * 64 + lane] * sl;
    int p = rowptr[node], end = rowptr[node + 1];
    for (; p + 1 < end; p += 2) {
        int2 e0 = csr[p];
        int2 e1 = csr[p + 1];
        float n0 = __int_as_float(e0.y);
        float n1 = __int_as_float(e1.y);
        float u0 = hw[(size_t)e0.x * 64 + lane];
        float u1 = hw[(size_t)e1.x * 64 + lane];
        acc = fmaf(u0, n0, acc);
        acc = fmaf(u1, n1, acc);
    }
    if (p < end) {
        int2 e0 = csr[p];
        acc = fmaf(hw[(size_t)e0.x * 64 + lane], __int_as_float(e0.y), acc);
    }
    float val = acc + ((lane < LAT) ? bm[lane] : bs[lane - LAT]);
    if (lane < LAT)
        outm[(size_t)node * LAT + lane] = val;
    else
        outs[(size_t)node * LAT + (lane - LAT)] = val;
}

extern "C" void kernel_launch(void* const* d_in, const int* in_sizes, int n_in,
                              void* d_out, int out_size, void* d_ws, size_t ws_size,
                              hipStream_t stream) {
    const float* x  = (const float*)d_in[0];
    const int*   ei = (const int*)d_in[1];
    const float* ew = (const float*)d_in[2];
    const float* W1 = (const float*)d_in[3];
    const float* b1 = (const float*)d_in[4];
    const float* Wm = (const float*)d_in[5];
    const float* bm = (const float*)d_in[6];
    const float* Ws = (const float*)d_in[7];
    const float* bs = (const float*)d_in[8];

    const int N = in_sizes[0] / DIM;     // 100000
    const int E = in_sizes[1] / 2;       // 1600000
    const int* src = ei;
    const int* dst = ei + E;

    // ---- workspace layout (~91 MB) ----
    char* w = (char*)d_ws;
    float* axh  = (float*)w;                 w += (size_t)N * DIM * 4;       // 51.2 MB (ax, then h in place)
    float* hw   = (float*)w;                 w += (size_t)N * 64 * 4;        // 25.6 MB
    float* dinv = (float*)w;                 w += (size_t)N * 4;
    int*   counts = (int*)w;                 w += (size_t)N * 4;
    int*   rowptr = (int*)w;                 w += (size_t)(N + 1) * 4;
    w = (char*)(((size_t)w + 255) & ~(size_t)255);
    int*   bsums  = (int*)w;                 w += 1024 * 4;
    w = (char*)(((size_t)w + 255) & ~(size_t)255);
    int2*  csr    = (int2*)w;                // 12.8 MB

    float* outm = (float*)d_out;
    float* outs = outm + (size_t)N * LAT;

    const int B = 256;
    const int NB = (N + SCAN_ELEMS - 1) / SCAN_ELEMS;   // 98

    // 1. degree + dst histogram
    hipMemsetAsync(counts, 0, (size_t)N * 4, stream);
    k_deg_init<<<(N + B - 1) / B, B, 0, stream>>>(dinv, N);
    k_edge_hist<<<(E + B - 1) / B, B, 0, stream>>>(dst, ew, dinv, counts, E);
    k_dinv<<<(N + B - 1) / B, B, 0, stream>>>(dinv, N);

    // 2. CSR build: scan + scatter
    k_scan1<<<NB, B, 0, stream>>>(counts, rowptr, bsums, N);
    k_scan2<<<1, 1, 0, stream>>>(bsums, rowptr, NB, N, E);
    k_scan3<<<(N + B - 1) / B, B, 0, stream>>>(rowptr, bsums, N);
    hipMemsetAsync(counts, 0, (size_t)N * 4, stream);   // reuse as cursor
    k_scatter<<<(E + B - 1) / B, B, 0, stream>>>(src, dst, ew, dinv, rowptr, counts, csr, E);

    // 3. ax = Agg(x)
    k_gather128<<<(N + 3) / 4, B, 0, stream>>>(csr, rowptr, dinv, x, axh, N);

    // 4. h = relu(ax @ W1 + b1) in place (barrier-protected)
    k_gemm_relu<<<(N + 15) / 16, B, 0, stream>>>(axh, W1, b1, axh, N);

    // 5. hw = h @ [Wm|Ws]
    k_gemmcat<<<(N + 15) / 16, B, 0, stream>>>(axh, Wm, Ws, hw, N);

    // 6. z = Agg(hw) + bias -> outputs
    k_gather64<<<(N + 3) / 4, B, 0, stream>>>(csr, rowptr, dinv, hw, bm, bs, outm, outs, N);
}

// Round 4
// 690.232 us; speedup vs baseline: 5.0996x; 1.6445x over previous
//
#include <hip/hip_runtime.h>

// VGAE encoder: 3x GCNConv (improved=True), N=100000, E=1600000.
//   ax = Agg(x); hw = relu(ax@W1+b1) @ [Wm|Ws]  (FUSED, h never materialized);
//   z = Agg(hw) + [bm|bs]   (second agg on 64 dims)
// Aggregation via on-device CSR (by dst) + per-node gather-reduce: NO float atomics.
// R4: fused MLP kernel with unroll discipline — R3's k_gemmcat spilled
// (VGPR=256, 775 MB scratch writes, 480 us for a 25 us GEMM).

#define DIM 128
#define LAT 32
#define SCAN_ELEMS 1024   // 256 threads x 4

__global__ void k_deg_init(float* __restrict__ deg, int N) {
    int i = blockIdx.x * blockDim.x + threadIdx.x;
    if (i < N) deg[i] = 2.0f;   // improved=True self-loop weight
}

// histogram of dst (for CSR) + weighted degree accumulation, one pass
__global__ void k_edge_hist(const int* __restrict__ dst, const float* __restrict__ ew,
                            float* __restrict__ deg, int* __restrict__ counts, int E) {
    int e = blockIdx.x * blockDim.x + threadIdx.x;
    if (e < E) {
        int d = dst[e];
        atomicAdd(&counts[d], 1);
        unsafeAtomicAdd(&deg[d], ew[e]);
    }
}

__global__ void k_dinv(float* __restrict__ deg, int N) {
    int i = blockIdx.x * blockDim.x + threadIdx.x;
    if (i < N) {
        float d = deg[i];
        deg[i] = (d > 0.0f) ? rsqrtf(d) : 0.0f;
    }
}

// ---- exclusive scan of counts -> rowptr (3 kernels) ----
__global__ __launch_bounds__(256) void k_scan1(const int* __restrict__ counts,
                                               int* __restrict__ rowptr,
                                               int* __restrict__ bsums, int N) {
    __shared__ int sdata[256];
    const int t = threadIdx.x;
    const int base = blockIdx.x * SCAN_ELEMS + t * 4;
    int v[4];
#pragma unroll
    for (int j = 0; j < 4; ++j) {
        int idx = base + j;
        v[j] = (idx < N) ? counts[idx] : 0;
    }
    int tot = v[0] + v[1] + v[2] + v[3];
    sdata[t] = tot;
    __syncthreads();
    for (int off = 1; off < 256; off <<= 1) {
        int x = 0;
        if (t >= off) x = sdata[t - off];
        __syncthreads();
        if (t >= off) sdata[t] += x;
        __syncthreads();
    }
    int running = sdata[t] - tot;   // exclusive prefix of this thread within block
#pragma unroll
    for (int j = 0; j < 4; ++j) {
        int idx = base + j;
        if (idx < N) rowptr[idx] = running;
        running += v[j];
    }
    if (t == 255) bsums[blockIdx.x] = sdata[255];
}

__global__ void k_scan2(int* __restrict__ bsums, int* __restrict__ rowptr, int NB, int N, int E) {
    int running = 0;
    for (int b = 0; b < NB; ++b) {
        int t = bsums[b];
        bsums[b] = running;
        running += t;
    }
    rowptr[N] = E;
}

__global__ void k_scan3(int* __restrict__ rowptr, const int* __restrict__ bsums, int N) {
    int i = blockIdx.x * blockDim.x + threadIdx.x;
    if (i < N) rowptr[i] += bsums[i >> 10];
}

// scatter edges into CSR slots: record = {src, norm bits}
__global__ void k_scatter(const int* __restrict__ src, const int* __restrict__ dst,
                          const float* __restrict__ ew, const float* __restrict__ dinv,
                          const int* __restrict__ rowptr, int* __restrict__ cursor,
                          int2* __restrict__ csr, int E) {
    int e = blockIdx.x * blockDim.x + threadIdx.x;
    if (e < E) {
        int s = src[e];
        int d = dst[e];
        float nrm = dinv[s] * ew[e] * dinv[d];
        int pos = rowptr[d] + atomicAdd(&cursor[d], 1);
        csr[pos] = make_int2(s, __float_as_int(nrm));
    }
}

// one wave per node, lane = float2 of the 128-dim row; acc init = self-loop term
__global__ __launch_bounds__(256) void k_gather128(const int2* __restrict__ csr,
                                                   const int* __restrict__ rowptr,
                                                   const float* __restrict__ dinv,
                                                   const float* __restrict__ xin,
                                                   float* __restrict__ out, int N) {
    int node = (blockIdx.x * 256 + threadIdx.x) >> 6;
    int lane = threadIdx.x & 63;
    if (node >= N) return;
    float s = dinv[node];
    float sl = 2.0f * s * s;
    float2 acc = reinterpret_cast<const float2*>(xin + (size_t)node * DIM)[lane];
    acc.x *= sl; acc.y *= sl;
    int p = rowptr[node], end = rowptr[node + 1];
    for (; p + 1 < end; p += 2) {
        int2 e0 = csr[p];
        int2 e1 = csr[p + 1];
        float n0 = __int_as_float(e0.y);
        float n1 = __int_as_float(e1.y);
        float2 u0 = reinterpret_cast<const float2*>(xin + (size_t)e0.x * DIM)[lane];
        float2 u1 = reinterpret_cast<const float2*>(xin + (size_t)e1.x * DIM)[lane];
        acc.x = fmaf(u0.x, n0, acc.x); acc.y = fmaf(u0.y, n0, acc.y);
        acc.x = fmaf(u1.x, n1, acc.x); acc.y = fmaf(u1.y, n1, acc.y);
    }
    if (p < end) {
        int2 e0 = csr[p];
        float n0 = __int_as_float(e0.y);
        float2 u0 = reinterpret_cast<const float2*>(xin + (size_t)e0.x * DIM)[lane];
        acc.x = fmaf(u0.x, n0, acc.x); acc.y = fmaf(u0.y, n0, acc.y);
    }
    reinterpret_cast<float2*>(out + (size_t)node * DIM)[lane] = acc;
}

// FUSED: hw = relu(A @ W1 + b1) @ [Wm|Ws].  A:[N,128] -> hw:[N,64].
// 16 rows per block. Phase 1: h-tile (16x128) into LDS. Phase 2: x Wcat (LDS).
// #pragma unroll 1 on k-loops: R3's gemmcat let the compiler fully unroll,
// spilled at VGPR=256 (775 MB scratch traffic). ILP comes from the j-loops.
__global__ __launch_bounds__(256) void k_fused_mlp(const float* __restrict__ A,
                                                   const float* __restrict__ W1,
                                                   const float* __restrict__ b1,
                                                   const float* __restrict__ Wm,
                                                   const float* __restrict__ Ws,
                                                   float* __restrict__ hw, int N) {
    __shared__ float hs[16][DIM];       // 8 KB h-tile
    __shared__ float wl[DIM * 64];      // 32 KB [Wm|Ws] interleaved

    // stage Wcat
    for (int idx = threadIdx.x; idx < DIM * 64; idx += 256) {
        int k = idx >> 6;
        int c = idx & 63;
        wl[idx] = (c < LAT) ? Wm[k * LAT + c] : Ws[k * LAT + (c - LAT)];
    }

    // ---- phase 1: h = relu(A @ W1 + b1) for 16 rows ----
    const int col = threadIdx.x & 127;
    const int ty = threadIdx.x >> 7;        // 0..1
    const int row0 = blockIdx.x * 16 + ty * 8;
    float acc[8];
#pragma unroll
    for (int j = 0; j < 8; ++j) acc[j] = 0.0f;
    const float* a = A + (size_t)row0 * DIM;
#pragma unroll 1
    for (int k = 0; k < DIM; k += 4) {
        float w0 = W1[(k + 0) * DIM + col];
        float w1 = W1[(k + 1) * DIM + col];
        float w2 = W1[(k + 2) * DIM + col];
        float w3 = W1[(k + 3) * DIM + col];
#pragma unroll
        for (int j = 0; j < 8; ++j) {
            float4 v = *reinterpret_cast<const float4*>(a + j * DIM + k);
            acc[j] = fmaf(v.x, w0, acc[j]);
            acc[j] = fmaf(v.y, w1, acc[j]);
            acc[j] = fmaf(v.z, w2, acc[j]);
            acc[j] = fmaf(v.w, w3, acc[j]);
        }
    }
    float bb = b1[col];
    __syncthreads();   // wl staging done; also orders hs writes below
#pragma unroll
    for (int j = 0; j < 8; ++j) {
        float v = acc[j] + bb;
        hs[ty * 8 + j][col] = (v > 0.0f) ? v : 0.0f;
    }
    __syncthreads();

    // ---- phase 2: hw-tile = h-tile @ Wcat ----
    const int col2 = threadIdx.x & 63;      // 0..63
    const int ty2 = threadIdx.x >> 6;       // 0..3 (wave-uniform)
    const int r0 = ty2 * 4;
    float acc2[4];
#pragma unroll
    for (int j = 0; j < 4; ++j) acc2[j] = 0.0f;
#pragma unroll 4
    for (int k = 0; k < DIM; ++k) {
        float w = wl[k * 64 + col2];
#pragma unroll
        for (int j = 0; j < 4; ++j)
            acc2[j] = fmaf(hs[r0 + j][k], w, acc2[j]);
    }
#pragma unroll
    for (int j = 0; j < 4; ++j) {
        int r = blockIdx.x * 16 + r0 + j;
        if (r < N) hw[(size_t)r * 64 + col2] = acc2[j];
    }
}

// one wave per node over 64 dims; adds bias, writes split outputs
__global__ __launch_bounds__(256) void k_gather64(const int2* __restrict__ csr,
                                                  const int* __restrict__ rowptr,
                                                  const float* __restrict__ dinv,
                                                  const float* __restrict__ hw,
                                                  const float* __restrict__ bm,
                                                  const float* __restrict__ bs,
                                                  float* __restrict__ outm,
                                                  float* __restrict__ outs, int N) {
    int node = (blockIdx.x * 256 + threadIdx.x) >> 6;
    int lane = threadIdx.x & 63;
    if (node >= N) return;
    float s = dinv[node];
    float sl = 2.0f * s * s;
    float acc = hw[(size_t)node * 64 + lane] * sl;
    int p = rowptr[node], end = rowptr[node + 1];
    for (; p + 1 < end; p += 2) {
        int2 e0 = csr[p];
        int2 e1 = csr[p + 1];
        float n0 = __int_as_float(e0.y);
        float n1 = __int_as_float(e1.y);
        float u0 = hw[(size_t)e0.x * 64 + lane];
        float u1 = hw[(size_t)e1.x * 64 + lane];
        acc = fmaf(u0, n0, acc);
        acc = fmaf(u1, n1, acc);
    }
    if (p < end) {
        int2 e0 = csr[p];
        acc = fmaf(hw[(size_t)e0.x * 64 + lane], __int_as_float(e0.y), acc);
    }
    float val = acc + ((lane < LAT) ? bm[lane] : bs[lane - LAT]);
    if (lane < LAT)
        outm[(size_t)node * LAT + lane] = val;
    else
        outs[(size_t)node * LAT + (lane - LAT)] = val;
}

extern "C" void kernel_launch(void* const* d_in, const int* in_sizes, int n_in,
                              void* d_out, int out_size, void* d_ws, size_t ws_size,
                              hipStream_t stream) {
    const float* x  = (const float*)d_in[0];
    const int*   ei = (const int*)d_in[1];
    const float* ew = (const float*)d_in[2];
    const float* W1 = (const float*)d_in[3];
    const float* b1 = (const float*)d_in[4];
    const float* Wm = (const float*)d_in[5];
    const float* bm = (const float*)d_in[6];
    const float* Ws = (const float*)d_in[7];
    const float* bs = (const float*)d_in[8];

    const int N = in_sizes[0] / DIM;     // 100000
    const int E = in_sizes[1] / 2;       // 1600000
    const int* src = ei;
    const int* dst = ei + E;

    // ---- workspace layout (~91 MB) ----
    char* w = (char*)d_ws;
    float* ax   = (float*)w;                 w += (size_t)N * DIM * 4;       // 51.2 MB
    float* hw   = (float*)w;                 w += (size_t)N * 64 * 4;        // 25.6 MB
    float* dinv = (float*)w;                 w += (size_t)N * 4;
    int*   counts = (int*)w;                 w += (size_t)N * 4;
    int*   rowptr = (int*)w;                 w += (size_t)(N + 1) * 4;
    w = (char*)(((size_t)w + 255) & ~(size_t)255);
    int*   bsums  = (int*)w;                 w += 1024 * 4;
    w = (char*)(((size_t)w + 255) & ~(size_t)255);
    int2*  csr    = (int2*)w;                // 12.8 MB

    float* outm = (float*)d_out;
    float* outs = outm + (size_t)N * LAT;

    const int B = 256;
    const int NB = (N + SCAN_ELEMS - 1) / SCAN_ELEMS;   // 98

    // 1. degree + dst histogram
    hipMemsetAsync(counts, 0, (size_t)N * 4, stream);
    k_deg_init<<<(N + B - 1) / B, B, 0, stream>>>(dinv, N);
    k_edge_hist<<<(E + B - 1) / B, B, 0, stream>>>(dst, ew, dinv, counts, E);
    k_dinv<<<(N + B - 1) / B, B, 0, stream>>>(dinv, N);

    // 2. CSR build: scan + scatter
    k_scan1<<<NB, B, 0, stream>>>(counts, rowptr, bsums, N);
    k_scan2<<<1, 1, 0, stream>>>(bsums, rowptr, NB, N, E);
    k_scan3<<<(N + B - 1) / B, B, 0, stream>>>(rowptr, bsums, N);
    hipMemsetAsync(counts, 0, (size_t)N * 4, stream);   // reuse as cursor
    k_scatter<<<(E + B - 1) / B, B, 0, stream>>>(src, dst, ew, dinv, rowptr, counts, csr, E);

    // 3. ax = Agg(x)
    k_gather128<<<(N + 3) / 4, B, 0, stream>>>(csr, rowptr, dinv, x, ax, N);

    // 4+5 fused. hw = relu(ax@W1+b1) @ [Wm|Ws]
    k_fused_mlp<<<(N + 15) / 16, B, 0, stream>>>(ax, W1, b1, Wm, Ws, hw, N);

    // 6. z = Agg(hw) + bias -> outputs
    k_gather64<<<(N + 3) / 4, B, 0, stream>>>(csr, rowptr, dinv, hw, bm, bs, outm, outs, N);
}

// Round 5
// 514.420 us; speedup vs baseline: 6.8425x; 1.3418x over previous
//
#include <hip/hip_runtime.h>

// VGAE encoder: 3x GCNConv (improved=True), N=100000, E=1600000.
//   ax = Agg(x) [bf16]; hw = relu(ax@W1+b1) @ [Wm|Ws] via MFMA (h in LDS only);
//   z = Agg(hw) + [bm|bs]
// R5: MLP on matrix cores. R4's fused_mlp was LDS-issue-bound (640 ds_read_b32
// per thread in phase 2, ~150us of LDS issue). MFMA replaces ~1500 lane-FMAs
// per thread with 48 wave-MFMAs + b128 fragment loads.

#define DIM 128
#define LAT 32
#define SCAN_ELEMS 1024   // 256 threads x 4

typedef short bf16x8 __attribute__((ext_vector_type(8)));
typedef float f32x4 __attribute__((ext_vector_type(4)));

__device__ __forceinline__ unsigned short f2bf(float f) {   // RNE
    unsigned u = __float_as_uint(f);
    return (unsigned short)((u + 0x7fffu + ((u >> 16) & 1u)) >> 16);
}

__global__ void k_deg_init(float* __restrict__ deg, int N) {
    int i = blockIdx.x * blockDim.x + threadIdx.x;
    if (i < N) deg[i] = 2.0f;   // improved=True self-loop weight
}

__global__ void k_edge_hist(const int* __restrict__ dst, const float* __restrict__ ew,
                            float* __restrict__ deg, int* __restrict__ counts, int E) {
    int e = blockIdx.x * blockDim.x + threadIdx.x;
    if (e < E) {
        int d = dst[e];
        atomicAdd(&counts[d], 1);
        unsafeAtomicAdd(&deg[d], ew[e]);
    }
}

__global__ void k_dinv(float* __restrict__ deg, int N) {
    int i = blockIdx.x * blockDim.x + threadIdx.x;
    if (i < N) {
        float d = deg[i];
        deg[i] = (d > 0.0f) ? rsqrtf(d) : 0.0f;
    }
}

// ---- exclusive scan of counts -> rowptr ----
__global__ __launch_bounds__(256) void k_scan1(const int* __restrict__ counts,
                                               int* __restrict__ rowptr,
                                               int* __restrict__ bsums, int N) {
    __shared__ int sdata[256];
    const int t = threadIdx.x;
    const int base = blockIdx.x * SCAN_ELEMS + t * 4;
    int v[4];
#pragma unroll
    for (int j = 0; j < 4; ++j) {
        int idx = base + j;
        v[j] = (idx < N) ? counts[idx] : 0;
    }
    int tot = v[0] + v[1] + v[2] + v[3];
    sdata[t] = tot;
    __syncthreads();
    for (int off = 1; off < 256; off <<= 1) {
        int x = 0;
        if (t >= off) x = sdata[t - off];
        __syncthreads();
        if (t >= off) sdata[t] += x;
        __syncthreads();
    }
    int running = sdata[t] - tot;
#pragma unroll
    for (int j = 0; j < 4; ++j) {
        int idx = base + j;
        if (idx < N) rowptr[idx] = running;
        running += v[j];
    }
    if (t == 255) bsums[blockIdx.x] = sdata[255];
}

__global__ void k_scan2(int* __restrict__ bsums, int* __restrict__ rowptr, int NB, int N, int E) {
    int running = 0;
    for (int b = 0; b < NB; ++b) {
        int t = bsums[b];
        bsums[b] = running;
        running += t;
    }
    rowptr[N] = E;
}

__global__ void k_scan3(int* __restrict__ rowptr, const int* __restrict__ bsums, int N) {
    int i = blockIdx.x * blockDim.x + threadIdx.x;
    if (i < N) rowptr[i] += bsums[i >> 10];
}

// scatter edges into CSR slots: record = {src, norm bits}
__global__ void k_scatter(const int* __restrict__ src, const int* __restrict__ dst,
                          const float* __restrict__ ew, const float* __restrict__ dinv,
                          const int* __restrict__ rowptr, int* __restrict__ cursor,
                          int2* __restrict__ csr, int E) {
    int e = blockIdx.x * blockDim.x + threadIdx.x;
    if (e < E) {
        int s = src[e];
        int d = dst[e];
        float nrm = dinv[s] * ew[e] * dinv[d];
        int pos = rowptr[d] + atomicAdd(&cursor[d], 1);
        csr[pos] = make_int2(s, __float_as_int(nrm));
    }
}

// weight prep: w1t[c][k] = bf16(W1[k][c]); wct[c][k] = bf16([Wm|Ws][k][c])
__global__ void k_prep_w(const float* __restrict__ W1, const float* __restrict__ Wm,
                         const float* __restrict__ Ws, unsigned short* __restrict__ w1t,
                         unsigned short* __restrict__ wct) {
    int i = blockIdx.x * 256 + threadIdx.x;
    if (i < DIM * DIM) {
        int c = i >> 7, k = i & 127;
        w1t[c * DIM + k] = f2bf(W1[k * DIM + c]);
    }
    i -= DIM * DIM;
    if (i >= 0 && i < 64 * DIM) {
        int c = i >> 7, k = i & 127;
        wct[c * DIM + k] = f2bf((c < LAT) ? Wm[k * LAT + c] : Ws[k * LAT + (c - LAT)]);
    }
}

// one wave per node; f32 gather math, bf16 output (MFMA A-operand)
__global__ __launch_bounds__(256) void k_gather128(const int2* __restrict__ csr,
                                                   const int* __restrict__ rowptr,
                                                   const float* __restrict__ dinv,
                                                   const float* __restrict__ xin,
                                                   unsigned* __restrict__ axb_u, int N) {
    int node = (blockIdx.x * 256 + threadIdx.x) >> 6;
    int lane = threadIdx.x & 63;
    if (node >= N) return;
    float s = dinv[node];
    float sl = 2.0f * s * s;
    float2 acc = reinterpret_cast<const float2*>(xin + (size_t)node * DIM)[lane];
    acc.x *= sl; acc.y *= sl;
    int p = rowptr[node], end = rowptr[node + 1];
    for (; p + 1 < end; p += 2) {
        int2 e0 = csr[p];
        int2 e1 = csr[p + 1];
        float n0 = __int_as_float(e0.y);
        float n1 = __int_as_float(e1.y);
        float2 u0 = reinterpret_cast<const float2*>(xin + (size_t)e0.x * DIM)[lane];
        float2 u1 = reinterpret_cast<const float2*>(xin + (size_t)e1.x * DIM)[lane];
        acc.x = fmaf(u0.x, n0, acc.x); acc.y = fmaf(u0.y, n0, acc.y);
        acc.x = fmaf(u1.x, n1, acc.x); acc.y = fmaf(u1.y, n1, acc.y);
    }
    if (p < end) {
        int2 e0 = csr[p];
        float n0 = __int_as_float(e0.y);
        float2 u0 = reinterpret_cast<const float2*>(xin + (size_t)e0.x * DIM)[lane];
        acc.x = fmaf(u0.x, n0, acc.x); acc.y = fmaf(u0.y, n0, acc.y);
    }
    axb_u[(size_t)node * 64 + lane] =
        (unsigned)f2bf(acc.x) | ((unsigned)f2bf(acc.y) << 16);
}

// MFMA MLP: hw = relu(axb @ W1 + b1) @ Wcat.  Block = 64 rows, 4 waves x 16 rows.
// Fragment layout (16x16x32 bf16, m89/m92-verified):
//   A: lane holds A[row=lane&15][k=(lane>>4)*8 + j], j=0..7  (one b128)
//   B: lane holds B[k=(lane>>4)*8 + j][col=lane&15]          (Wt[col][k] -> b128)
//   D: lane holds D[row=(lane>>4)*4 + r][col=lane&15], r=0..3
__global__ __launch_bounds__(256) void k_mfma_mlp(const unsigned short* __restrict__ axb,
                                                  const unsigned short* __restrict__ w1t,
                                                  const unsigned short* __restrict__ wct,
                                                  const float* __restrict__ b1,
                                                  float* __restrict__ hw, int N) {
    __shared__ __align__(16) unsigned short hs[4][16][136];  // +8 pad: bank spread
    const int wave = threadIdx.x >> 6;
    const int lane = threadIdx.x & 63;
    const int lrow = lane & 15;
    const int lk = lane >> 4;            // 0..3
    const int R0 = blockIdx.x * 64 + wave * 16;
    const bool active = (R0 < N);        // N%16==0: active waves fully in-bounds

    if (active) {
        f32x4 acc[8];
#pragma unroll
        for (int t = 0; t < 8; ++t) acc[t] = (f32x4){0.f, 0.f, 0.f, 0.f};
        const unsigned short* arow = axb + (size_t)(R0 + lrow) * DIM + lk * 8;
#pragma unroll
        for (int kt = 0; kt < 4; ++kt) {
            bf16x8 a = *reinterpret_cast<const bf16x8*>(arow + kt * 32);
#pragma unroll
            for (int t = 0; t < 8; ++t) {
                bf16x8 b = *reinterpret_cast<const bf16x8*>(
                    w1t + (size_t)(t * 16 + lrow) * DIM + kt * 32 + lk * 8);
                acc[t] = __builtin_amdgcn_mfma_f32_16x16x32_bf16(a, b, acc[t], 0, 0, 0);
            }
        }
        // bias + relu -> bf16 h-tile in LDS
#pragma unroll
        for (int t = 0; t < 8; ++t) {
#pragma unroll
            for (int r = 0; r < 4; ++r) {
                int col = t * 16 + lrow;
                float v = acc[t][r] + b1[col];
                hs[wave][lk * 4 + r][col] = f2bf(v > 0.f ? v : 0.f);
            }
        }
    }
    __syncthreads();
    if (active) {
        f32x4 acc2[4];
#pragma unroll
        for (int t = 0; t < 4; ++t) acc2[t] = (f32x4){0.f, 0.f, 0.f, 0.f};
        const unsigned short* hrow = &hs[wave][lrow][0];
#pragma unroll
        for (int kt = 0; kt < 4; ++kt) {
            bf16x8 a = *reinterpret_cast<const bf16x8*>(hrow + kt * 32 + lk * 8);
#pragma unroll
            for (int t = 0; t < 4; ++t) {
                bf16x8 b = *reinterpret_cast<const bf16x8*>(
                    wct + (size_t)(t * 16 + lrow) * DIM + kt * 32 + lk * 8);
                acc2[t] = __builtin_amdgcn_mfma_f32_16x16x32_bf16(a, b, acc2[t], 0, 0, 0);
            }
        }
#pragma unroll
        for (int t = 0; t < 4; ++t)
#pragma unroll
            for (int r = 0; r < 4; ++r)
                hw[(size_t)(R0 + lk * 4 + r) * 64 + t * 16 + lrow] = acc2[t][r];
    }
}

// one wave per node over 64 dims; adds bias, writes split outputs
__global__ __launch_bounds__(256) void k_gather64(const int2* __restrict__ csr,
                                                  const int* __restrict__ rowptr,
                                                  const float* __restrict__ dinv,
                                                  const float* __restrict__ hw,
                                                  const float* __restrict__ bm,
                                                  const float* __restrict__ bs,
                                                  float* __restrict__ outm,
                                                  float* __restrict__ outs, int N) {
    int node = (blockIdx.x * 256 + threadIdx.x) >> 6;
    int lane = threadIdx.x & 63;
    if (node >= N) return;
    float s = dinv[node];
    float sl = 2.0f * s * s;
    float acc = hw[(size_t)node * 64 + lane] * sl;
    int p = rowptr[node], end = rowptr[node + 1];
    for (; p + 1 < end; p += 2) {
        int2 e0 = csr[p];
        int2 e1 = csr[p + 1];
        float n0 = __int_as_float(e0.y);
        float n1 = __int_as_float(e1.y);
        float u0 = hw[(size_t)e0.x * 64 + lane];
        float u1 = hw[(size_t)e1.x * 64 + lane];
        acc = fmaf(u0, n0, acc);
        acc = fmaf(u1, n1, acc);
    }
    if (p < end) {
        int2 e0 = csr[p];
        acc = fmaf(hw[(size_t)e0.x * 64 + lane], __int_as_float(e0.y), acc);
    }
    float val = acc + ((lane < LAT) ? bm[lane] : bs[lane - LAT]);
    if (lane < LAT)
        outm[(size_t)node * LAT + lane] = val;
    else
        outs[(size_t)node * LAT + (lane - LAT)] = val;
}

extern "C" void kernel_launch(void* const* d_in, const int* in_sizes, int n_in,
                              void* d_out, int out_size, void* d_ws, size_t ws_size,
                              hipStream_t stream) {
    const float* x  = (const float*)d_in[0];
    const int*   ei = (const int*)d_in[1];
    const float* ew = (const float*)d_in[2];
    const float* W1 = (const float*)d_in[3];
    const float* b1 = (const float*)d_in[4];
    const float* Wm = (const float*)d_in[5];
    const float* bm = (const float*)d_in[6];
    const float* Ws = (const float*)d_in[7];
    const float* bs = (const float*)d_in[8];

    const int N = in_sizes[0] / DIM;     // 100000
    const int E = in_sizes[1] / 2;       // 1600000
    const int* src = ei;
    const int* dst = ei + E;

    // ---- workspace layout (~65 MB) ----
    char* w = (char*)d_ws;
    unsigned* axb = (unsigned*)w;            w += (size_t)N * DIM * 2;       // 25.6 MB bf16
    float* hw   = (float*)w;                 w += (size_t)N * 64 * 4;        // 25.6 MB f32
    float* dinv = (float*)w;                 w += (size_t)N * 4;
    int*   counts = (int*)w;                 w += (size_t)N * 4;
    int*   rowptr = (int*)w;                 w += (size_t)(N + 1) * 4;
    w = (char*)(((size_t)w + 255) & ~(size_t)255);
    int*   bsums  = (int*)w;                 w += 1024 * 4;
    unsigned short* w1t = (unsigned short*)w; w += DIM * DIM * 2;            // 32 KB
    unsigned short* wct = (unsigned short*)w; w += 64 * DIM * 2;             // 16 KB
    w = (char*)(((size_t)w + 255) & ~(size_t)255);
    int2*  csr    = (int2*)w;                // 12.8 MB

    float* outm = (float*)d_out;
    float* outs = outm + (size_t)N * LAT;

    const int B = 256;
    const int NB = (N + SCAN_ELEMS - 1) / SCAN_ELEMS;   // 98

    // 1. degree + dst histogram (+ weight prep, independent)
    hipMemsetAsync(counts, 0, (size_t)N * 4, stream);
    k_deg_init<<<(N + B - 1) / B, B, 0, stream>>>(dinv, N);
    k_edge_hist<<<(E + B - 1) / B, B, 0, stream>>>(dst, ew, dinv, counts, E);
    k_dinv<<<(N + B - 1) / B, B, 0, stream>>>(dinv, N);
    k_prep_w<<<(DIM * DIM + 64 * DIM + B - 1) / B, B, 0, stream>>>(W1, Wm, Ws, w1t, wct);

    // 2. CSR build: scan + scatter
    k_scan1<<<NB, B, 0, stream>>>(counts, rowptr, bsums, N);
    k_scan2<<<1, 1, 0, stream>>>(bsums, rowptr, NB, N, E);
    k_scan3<<<(N + B - 1) / B, B, 0, stream>>>(rowptr, bsums, N);
    hipMemsetAsync(counts, 0, (size_t)N * 4, stream);   // reuse as cursor
    k_scatter<<<(E + B - 1) / B, B, 0, stream>>>(src, dst, ew, dinv, rowptr, counts, csr, E);

    // 3. ax = Agg(x) -> bf16
    k_gather128<<<(N + 3) / 4, B, 0, stream>>>(csr, rowptr, dinv, x, axb, N);

    // 4. hw = relu(ax@W1+b1) @ [Wm|Ws]  (MFMA)
    k_mfma_mlp<<<(N + 63) / 64, B, 0, stream>>>((const unsigned short*)axb, w1t, wct, b1, hw, N);

    // 5. z = Agg(hw) + bias -> outputs
    k_gather64<<<(N + 3) / 4, B, 0, stream>>>(csr, rowptr, dinv, hw, bm, bs, outm, outs, N);
}

// Round 6
// 418.073 us; speedup vs baseline: 8.4194x; 1.2305x over previous
//
#include <hip/hip_runtime.h>

// VGAE encoder: 3x GCNConv (improved=True), N=100000, E=1600000.
//   ax = Agg(x) [bf16]; hw = relu(ax@W1+b1) @ [Wm|Ws] via MFMA; z = Agg(hw)+[bm|bs]
// R6: atomic-diet CSR build. R5's k_edge_hist (3.2M atomics, 143us) replaced by
// rank-pass (1.6M atomics) + atomic-free place. deg via segmented sum over the
// built CSR (deferred normalization: out[d] = dinv[d]*(sum ew*dinv[s]*x[s] + 2*dinv[d]*x[d])).

#define DIM 128
#define LAT 32
#define SCAN_ELEMS 1024   // 256 threads x 4

typedef short bf16x8 __attribute__((ext_vector_type(8)));
typedef float f32x4 __attribute__((ext_vector_type(4)));

__device__ __forceinline__ unsigned short f2bf(float f) {   // RNE
    unsigned u = __float_as_uint(f);
    return (unsigned short)((u + 0x7fffu + ((u >> 16) & 1u)) >> 16);
}

// pass 1: per-edge within-node rank; cursor ends as per-node counts
__global__ void k_rank(const int* __restrict__ dst, int* __restrict__ cursor,
                       int* __restrict__ rank, int E) {
    int e = blockIdx.x * blockDim.x + threadIdx.x;
    if (e < E) rank[e] = atomicAdd(&cursor[dst[e]], 1);
}

// ---- exclusive scan of counts -> rowptr ----
__global__ __launch_bounds__(256) void k_scan1(const int* __restrict__ counts,
                                               int* __restrict__ rowptr,
                                               int* __restrict__ bsums, int N) {
    __shared__ int sdata[256];
    const int t = threadIdx.x;
    const int base = blockIdx.x * SCAN_ELEMS + t * 4;
    int v[4];
#pragma unroll
    for (int j = 0; j < 4; ++j) {
        int idx = base + j;
        v[j] = (idx < N) ? counts[idx] : 0;
    }
    int tot = v[0] + v[1] + v[2] + v[3];
    sdata[t] = tot;
    __syncthreads();
    for (int off = 1; off < 256; off <<= 1) {
        int x = 0;
        if (t >= off) x = sdata[t - off];
        __syncthreads();
        if (t >= off) sdata[t] += x;
        __syncthreads();
    }
    int running = sdata[t] - tot;
#pragma unroll
    for (int j = 0; j < 4; ++j) {
        int idx = base + j;
        if (idx < N) rowptr[idx] = running;
        running += v[j];
    }
    if (t == 255) bsums[blockIdx.x] = sdata[255];
}

__global__ void k_scan2(int* __restrict__ bsums, int* __restrict__ rowptr, int NB, int N, int E) {
    int running = 0;
    for (int b = 0; b < NB; ++b) {
        int t = bsums[b];
        bsums[b] = running;
        running += t;
    }
    rowptr[N] = E;
}

__global__ void k_scan3(int* __restrict__ rowptr, const int* __restrict__ bsums, int N) {
    int i = blockIdx.x * blockDim.x + threadIdx.x;
    if (i < N) rowptr[i] += bsums[i >> 10];
}

// pass 2: place edges into CSR slots — NO atomics. record = {src, raw ew bits}
__global__ void k_place(const int* __restrict__ src, const int* __restrict__ dst,
                        const float* __restrict__ ew, const int* __restrict__ rank,
                        const int* __restrict__ rowptr, int2* __restrict__ csr, int E) {
    int e = blockIdx.x * blockDim.x + threadIdx.x;
    if (e < E)
        csr[rowptr[dst[e]] + rank[e]] = make_int2(src[e], __float_as_int(ew[e]));
}

// deg[i] = 2 + sum of incoming ew (from CSR, atomic-free) -> dinv in place
__global__ void k_degseg(const int2* __restrict__ csr, const int* __restrict__ rowptr,
                         float* __restrict__ dinv, int N) {
    int i = blockIdx.x * blockDim.x + threadIdx.x;
    if (i >= N) return;
    float deg = 2.0f;   // improved=True self-loop weight
    int p = rowptr[i], end = rowptr[i + 1];
    for (; p < end; ++p) deg += __int_as_float(csr[p].y);
    dinv[i] = (deg > 0.0f) ? rsqrtf(deg) : 0.0f;
}

// weight prep: w1t[c][k] = bf16(W1[k][c]); wct[c][k] = bf16([Wm|Ws][k][c])
__global__ void k_prep_w(const float* __restrict__ W1, const float* __restrict__ Wm,
                         const float* __restrict__ Ws, unsigned short* __restrict__ w1t,
                         unsigned short* __restrict__ wct) {
    int i = blockIdx.x * 256 + threadIdx.x;
    if (i < DIM * DIM) {
        int c = i >> 7, k = i & 127;
        w1t[c * DIM + k] = f2bf(W1[k * DIM + c]);
    }
    i -= DIM * DIM;
    if (i >= 0 && i < 64 * DIM) {
        int c = i >> 7, k = i & 127;
        wct[c * DIM + k] = f2bf((c < LAT) ? Wm[k * LAT + c] : Ws[k * LAT + (c - LAT)]);
    }
}

// one wave per node; deferred norm: acc = 2*di*x[d] + sum ew*dinv[s]*x[s]; out = di*acc (bf16)
__global__ __launch_bounds__(256) void k_gather128(const int2* __restrict__ csr,
                                                   const int* __restrict__ rowptr,
                                                   const float* __restrict__ dinv,
                                                   const float* __restrict__ xin,
                                                   unsigned* __restrict__ axb_u, int N) {
    int node = (blockIdx.x * 256 + threadIdx.x) >> 6;
    int lane = threadIdx.x & 63;
    if (node >= N) return;
    float di = dinv[node];
    float sl = 2.0f * di;
    float2 acc = reinterpret_cast<const float2*>(xin + (size_t)node * DIM)[lane];
    acc.x *= sl; acc.y *= sl;
    int p = rowptr[node], end = rowptr[node + 1];
    for (; p + 1 < end; p += 2) {
        int2 e0 = csr[p];
        int2 e1 = csr[p + 1];
        float n0 = __int_as_float(e0.y) * dinv[e0.x];   // broadcast load
        float n1 = __int_as_float(e1.y) * dinv[e1.x];
        float2 u0 = reinterpret_cast<const float2*>(xin + (size_t)e0.x * DIM)[lane];
        float2 u1 = reinterpret_cast<const float2*>(xin + (size_t)e1.x * DIM)[lane];
        acc.x = fmaf(u0.x, n0, acc.x); acc.y = fmaf(u0.y, n0, acc.y);
        acc.x = fmaf(u1.x, n1, acc.x); acc.y = fmaf(u1.y, n1, acc.y);
    }
    if (p < end) {
        int2 e0 = csr[p];
        float n0 = __int_as_float(e0.y) * dinv[e0.x];
        float2 u0 = reinterpret_cast<const float2*>(xin + (size_t)e0.x * DIM)[lane];
        acc.x = fmaf(u0.x, n0, acc.x); acc.y = fmaf(u0.y, n0, acc.y);
    }
    acc.x *= di; acc.y *= di;
    axb_u[(size_t)node * 64 + lane] =
        (unsigned)f2bf(acc.x) | ((unsigned)f2bf(acc.y) << 16);
}

// MFMA MLP: hw = relu(axb @ W1 + b1) @ Wcat.  Block = 64 rows, 4 waves x 16 rows.
__global__ __launch_bounds__(256) void k_mfma_mlp(const unsigned short* __restrict__ axb,
                                                  const unsigned short* __restrict__ w1t,
                                                  const unsigned short* __restrict__ wct,
                                                  const float* __restrict__ b1,
                                                  float* __restrict__ hw, int N) {
    __shared__ __align__(16) unsigned short hs[4][16][136];  // +8 pad: bank spread
    const int wave = threadIdx.x >> 6;
    const int lane = threadIdx.x & 63;
    const int lrow = lane & 15;
    const int lk = lane >> 4;            // 0..3
    const int R0 = blockIdx.x * 64 + wave * 16;
    const bool active = (R0 < N);        // N%16==0: active waves fully in-bounds

    if (active) {
        f32x4 acc[8];
#pragma unroll
        for (int t = 0; t < 8; ++t) acc[t] = (f32x4){0.f, 0.f, 0.f, 0.f};
        const unsigned short* arow = axb + (size_t)(R0 + lrow) * DIM + lk * 8;
#pragma unroll
        for (int kt = 0; kt < 4; ++kt) {
            bf16x8 a = *reinterpret_cast<const bf16x8*>(arow + kt * 32);
#pragma unroll
            for (int t = 0; t < 8; ++t) {
                bf16x8 b = *reinterpret_cast<const bf16x8*>(
                    w1t + (size_t)(t * 16 + lrow) * DIM + kt * 32 + lk * 8);
                acc[t] = __builtin_amdgcn_mfma_f32_16x16x32_bf16(a, b, acc[t], 0, 0, 0);
            }
        }
#pragma unroll
        for (int t = 0; t < 8; ++t) {
#pragma unroll
            for (int r = 0; r < 4; ++r) {
                int col = t * 16 + lrow;
                float v = acc[t][r] + b1[col];
                hs[wave][lk * 4 + r][col] = f2bf(v > 0.f ? v : 0.f);
            }
        }
    }
    __syncthreads();
    if (active) {
        f32x4 acc2[4];
#pragma unroll
        for (int t = 0; t < 4; ++t) acc2[t] = (f32x4){0.f, 0.f, 0.f, 0.f};
        const unsigned short* hrow = &hs[wave][lrow][0];
#pragma unroll
        for (int kt = 0; kt < 4; ++kt) {
            bf16x8 a = *reinterpret_cast<const bf16x8*>(hrow + kt * 32 + lk * 8);
#pragma unroll
            for (int t = 0; t < 4; ++t) {
                bf16x8 b = *reinterpret_cast<const bf16x8*>(
                    wct + (size_t)(t * 16 + lrow) * DIM + kt * 32 + lk * 8);
                acc2[t] = __builtin_amdgcn_mfma_f32_16x16x32_bf16(a, b, acc2[t], 0, 0, 0);
            }
        }
#pragma unroll
        for (int t = 0; t < 4; ++t)
#pragma unroll
            for (int r = 0; r < 4; ++r)
                hw[(size_t)(R0 + lk * 4 + r) * 64 + t * 16 + lrow] = acc2[t][r];
    }
}

// one wave per node over 64 dims; deferred norm + bias, split outputs
__global__ __launch_bounds__(256) void k_gather64(const int2* __restrict__ csr,
                                                  const int* __restrict__ rowptr,
                                                  const float* __restrict__ dinv,
                                                  const float* __restrict__ hw,
                                                  const float* __restrict__ bm,
                                                  const float* __restrict__ bs,
                                                  float* __restrict__ outm,
                                                  float* __restrict__ outs, int N) {
    int node = (blockIdx.x * 256 + threadIdx.x) >> 6;
    int lane = threadIdx.x & 63;
    if (node >= N) return;
    float di = dinv[node];
    float acc = hw[(size_t)node * 64 + lane] * (2.0f * di);
    int p = rowptr[node], end = rowptr[node + 1];
    for (; p + 1 < end; p += 2) {
        int2 e0 = csr[p];
        int2 e1 = csr[p + 1];
        float n0 = __int_as_float(e0.y) * dinv[e0.x];
        float n1 = __int_as_float(e1.y) * dinv[e1.x];
        float u0 = hw[(size_t)e0.x * 64 + lane];
        float u1 = hw[(size_t)e1.x * 64 + lane];
        acc = fmaf(u0, n0, acc);
        acc = fmaf(u1, n1, acc);
    }
    if (p < end) {
        int2 e0 = csr[p];
        acc = fmaf(hw[(size_t)e0.x * 64 + lane], __int_as_float(e0.y) * dinv[e0.x], acc);
    }
    float val = acc * di + ((lane < LAT) ? bm[lane] : bs[lane - LAT]);
    if (lane < LAT)
        outm[(size_t)node * LAT + lane] = val;
    else
        outs[(size_t)node * LAT + (lane - LAT)] = val;
}

extern "C" void kernel_launch(void* const* d_in, const int* in_sizes, int n_in,
                              void* d_out, int out_size, void* d_ws, size_t ws_size,
                              hipStream_t stream) {
    const float* x  = (const float*)d_in[0];
    const int*   ei = (const int*)d_in[1];
    const float* ew = (const float*)d_in[2];
    const float* W1 = (const float*)d_in[3];
    const float* b1 = (const float*)d_in[4];
    const float* Wm = (const float*)d_in[5];
    const float* bm = (const float*)d_in[6];
    const float* Ws = (const float*)d_in[7];
    const float* bs = (const float*)d_in[8];

    const int N = in_sizes[0] / DIM;     // 100000
    const int E = in_sizes[1] / 2;       // 1600000
    const int* src = ei;
    const int* dst = ei + E;

    // ---- workspace layout (~72 MB) ----
    char* w = (char*)d_ws;
    unsigned* axb = (unsigned*)w;            w += (size_t)N * DIM * 2;       // 25.6 MB bf16
    float* hw   = (float*)w;                 w += (size_t)N * 64 * 4;        // 25.6 MB f32
    float* dinv = (float*)w;                 w += (size_t)N * 4;
    int*   cursor = (int*)w;                 w += (size_t)N * 4;             // rank cursor == counts
    int*   rowptr = (int*)w;                 w += (size_t)(N + 1) * 4;
    int*   rank   = (int*)w;                 w += (size_t)E * 4;             // 6.4 MB
    w = (char*)(((size_t)w + 255) & ~(size_t)255);
    int*   bsums  = (int*)w;                 w += 1024 * 4;
    unsigned short* w1t = (unsigned short*)w; w += DIM * DIM * 2;            // 32 KB
    unsigned short* wct = (unsigned short*)w; w += 64 * DIM * 2;             // 16 KB
    w = (char*)(((size_t)w + 255) & ~(size_t)255);
    int2*  csr    = (int2*)w;                // 12.8 MB

    float* outm = (float*)d_out;
    float* outs = outm + (size_t)N * LAT;

    const int B = 256;
    const int NB = (N + SCAN_ELEMS - 1) / SCAN_ELEMS;   // 98

    // 1. rank pass (cursor -> counts) + weight prep
    hipMemsetAsync(cursor, 0, (size_t)N * 4, stream);
    k_rank<<<(E + B - 1) / B, B, 0, stream>>>(dst, cursor, rank, E);
    k_prep_w<<<(DIM * DIM + 64 * DIM + B - 1) / B, B, 0, stream>>>(W1, Wm, Ws, w1t, wct);

    // 2. scan counts -> rowptr; place edges (atomic-free); deg -> dinv
    k_scan1<<<NB, B, 0, stream>>>(cursor, rowptr, bsums, N);
    k_scan2<<<1, 1, 0, stream>>>(bsums, rowptr, NB, N, E);
    k_scan3<<<(N + B - 1) / B, B, 0, stream>>>(rowptr, bsums, N);
    k_place<<<(E + B - 1) / B, B, 0, stream>>>(src, dst, ew, rank, rowptr, csr, E);
    k_degseg<<<(N + B - 1) / B, B, 0, stream>>>(csr, rowptr, dinv, N);

    // 3. ax = Agg(x) -> bf16
    k_gather128<<<(N + 3) / 4, B, 0, stream>>>(csr, rowptr, dinv, x, axb, N);

    // 4. hw = relu(ax@W1+b1) @ [Wm|Ws]  (MFMA)
    k_mfma_mlp<<<(N + 63) / 64, B, 0, stream>>>((const unsigned short*)axb, w1t, wct, b1, hw, N);

    // 5. z = Agg(hw) + bias -> outputs
    k_gather64<<<(N + 3) / 4, B, 0, stream>>>(csr, rowptr, dinv, hw, bm, bs, outm, outs, N);
}

// Round 7
// 407.596 us; speedup vs baseline: 8.6358x; 1.0257x over previous
//
#include <hip/hip_runtime.h>

// VGAE encoder: 3x GCNConv (improved=True), N=100000, E=1600000.
//   xb = bf16(x); ax = Agg(xb) [bf16]; hw = relu(ax@W1+b1)@[Wm|Ws] (MFMA, bf16 out);
//   z = Agg(hw) + [bm|bs]
// R7: bf16 gather operands. R6's k_gather128 was traffic-bound (FETCH 418 MB,
// 2.9 TB/s TCC path); bf16 x halves per-edge row reads. gather64 reworked to
// packed-pair loads + half-wave edge split (broadcast CSR reads).

#define DIM 128
#define LAT 32
#define SCAN_ELEMS 1024   // 256 threads x 4

typedef short bf16x8 __attribute__((ext_vector_type(8)));
typedef float f32x4 __attribute__((ext_vector_type(4)));

__device__ __forceinline__ unsigned short f2bf(float f) {   // RNE
    unsigned u = __float_as_uint(f);
    return (unsigned short)((u + 0x7fffu + ((u >> 16) & 1u)) >> 16);
}
__device__ __forceinline__ unsigned packbf(float a, float b) {
    return (unsigned)f2bf(a) | ((unsigned)f2bf(b) << 16);
}
__device__ __forceinline__ float2 bfp2f(unsigned u) {
    float2 r;
    r.x = __uint_as_float(u << 16);
    r.y = __uint_as_float(u & 0xffff0000u);
    return r;
}

// x [N,128] f32 -> packed bf16 pairs (uint2 per thread = 4 dims)
__global__ void k_x2bf(const float* __restrict__ x, uint2* __restrict__ xb, int n4) {
    int i = blockIdx.x * blockDim.x + threadIdx.x;
    if (i < n4) {
        float4 v = reinterpret_cast<const float4*>(x)[i];
        xb[i] = make_uint2(packbf(v.x, v.y), packbf(v.z, v.w));
    }
}

// pass 1: per-edge within-node rank; cursor ends as per-node counts
__global__ void k_rank(const int* __restrict__ dst, int* __restrict__ cursor,
                       int* __restrict__ rank, int E) {
    int e = blockIdx.x * blockDim.x + threadIdx.x;
    if (e < E) rank[e] = atomicAdd(&cursor[dst[e]], 1);
}

// ---- exclusive scan of counts -> rowptr ----
__global__ __launch_bounds__(256) void k_scan1(const int* __restrict__ counts,
                                               int* __restrict__ rowptr,
                                               int* __restrict__ bsums, int N) {
    __shared__ int sdata[256];
    const int t = threadIdx.x;
    const int base = blockIdx.x * SCAN_ELEMS + t * 4;
    int v[4];
#pragma unroll
    for (int j = 0; j < 4; ++j) {
        int idx = base + j;
        v[j] = (idx < N) ? counts[idx] : 0;
    }
    int tot = v[0] + v[1] + v[2] + v[3];
    sdata[t] = tot;
    __syncthreads();
    for (int off = 1; off < 256; off <<= 1) {
        int x = 0;
        if (t >= off) x = sdata[t - off];
        __syncthreads();
        if (t >= off) sdata[t] += x;
        __syncthreads();
    }
    int running = sdata[t] - tot;
#pragma unroll
    for (int j = 0; j < 4; ++j) {
        int idx = base + j;
        if (idx < N) rowptr[idx] = running;
        running += v[j];
    }
    if (t == 255) bsums[blockIdx.x] = sdata[255];
}

__global__ void k_scan2(int* __restrict__ bsums, int* __restrict__ rowptr, int NB, int N, int E) {
    int running = 0;
    for (int b = 0; b < NB; ++b) {
        int t = bsums[b];
        bsums[b] = running;
        running += t;
    }
    rowptr[N] = E;
}

__global__ void k_scan3(int* __restrict__ rowptr, const int* __restrict__ bsums, int N) {
    int i = blockIdx.x * blockDim.x + threadIdx.x;
    if (i < N) rowptr[i] += bsums[i >> 10];
}

// pass 2: place edges into CSR slots — NO atomics. record = {src, raw ew bits}
__global__ void k_place(const int* __restrict__ src, const int* __restrict__ dst,
                        const float* __restrict__ ew, const int* __restrict__ rank,
                        const int* __restrict__ rowptr, int2* __restrict__ csr, int E) {
    int e = blockIdx.x * blockDim.x + threadIdx.x;
    if (e < E)
        csr[rowptr[dst[e]] + rank[e]] = make_int2(src[e], __float_as_int(ew[e]));
}

// deg[i] = 2 + sum of incoming ew (from CSR, atomic-free) -> dinv in place
__global__ void k_degseg(const int2* __restrict__ csr, const int* __restrict__ rowptr,
                         float* __restrict__ dinv, int N) {
    int i = blockIdx.x * blockDim.x + threadIdx.x;
    if (i >= N) return;
    float deg = 2.0f;   // improved=True self-loop weight
    int p = rowptr[i], end = rowptr[i + 1];
    for (; p < end; ++p) deg += __int_as_float(csr[p].y);
    dinv[i] = (deg > 0.0f) ? rsqrtf(deg) : 0.0f;
}

// weight prep: w1t[c][k] = bf16(W1[k][c]); wct[c][k] = bf16([Wm|Ws][k][c])
__global__ void k_prep_w(const float* __restrict__ W1, const float* __restrict__ Wm,
                         const float* __restrict__ Ws, unsigned short* __restrict__ w1t,
                         unsigned short* __restrict__ wct) {
    int i = blockIdx.x * 256 + threadIdx.x;
    if (i < DIM * DIM) {
        int c = i >> 7, k = i & 127;
        w1t[c * DIM + k] = f2bf(W1[k * DIM + c]);
    }
    i -= DIM * DIM;
    if (i >= 0 && i < 64 * DIM) {
        int c = i >> 7, k = i & 127;
        wct[c * DIM + k] = f2bf((c < LAT) ? Wm[k * LAT + c] : Ws[k * LAT + (c - LAT)]);
    }
}

// one wave per node; lane = bf16 dim-pair. deferred norm:
//   ax = di*(2*di*x[d] + sum ew*dinv[s]*x[s])
__global__ __launch_bounds__(256) void k_gather128(const int2* __restrict__ csr,
                                                   const int* __restrict__ rowptr,
                                                   const float* __restrict__ dinv,
                                                   const unsigned* __restrict__ xb,
                                                   unsigned* __restrict__ axb_u, int N) {
    int node = (blockIdx.x * 256 + threadIdx.x) >> 6;
    int lane = threadIdx.x & 63;
    if (node >= N) return;
    float di = dinv[node];
    float sl = 2.0f * di;
    float2 sv = bfp2f(xb[(size_t)node * 64 + lane]);
    float2 acc;
    acc.x = sv.x * sl; acc.y = sv.y * sl;
    int p = rowptr[node], end = rowptr[node + 1];
    for (; p + 1 < end; p += 2) {
        int2 e0 = csr[p];
        int2 e1 = csr[p + 1];
        float n0 = __int_as_float(e0.y) * dinv[e0.x];   // broadcast loads
        float n1 = __int_as_float(e1.y) * dinv[e1.x];
        float2 u0 = bfp2f(xb[(size_t)e0.x * 64 + lane]);
        float2 u1 = bfp2f(xb[(size_t)e1.x * 64 + lane]);
        acc.x = fmaf(u0.x, n0, acc.x); acc.y = fmaf(u0.y, n0, acc.y);
        acc.x = fmaf(u1.x, n1, acc.x); acc.y = fmaf(u1.y, n1, acc.y);
    }
    if (p < end) {
        int2 e0 = csr[p];
        float n0 = __int_as_float(e0.y) * dinv[e0.x];
        float2 u0 = bfp2f(xb[(size_t)e0.x * 64 + lane]);
        acc.x = fmaf(u0.x, n0, acc.x); acc.y = fmaf(u0.y, n0, acc.y);
    }
    axb_u[(size_t)node * 64 + lane] = packbf(acc.x * di, acc.y * di);
}

// MFMA MLP: hwb = bf16( relu(axb @ W1 + b1) @ Wcat ).  Block = 64 rows, 4 waves.
__global__ __launch_bounds__(256) void k_mfma_mlp(const unsigned short* __restrict__ axb,
                                                  const unsigned short* __restrict__ w1t,
                                                  const unsigned short* __restrict__ wct,
                                                  const float* __restrict__ b1,
                                                  unsigned short* __restrict__ hwb, int N) {
    __shared__ __align__(16) unsigned short hs[4][16][136];  // +8 pad: bank spread
    const int wave = threadIdx.x >> 6;
    const int lane = threadIdx.x & 63;
    const int lrow = lane & 15;
    const int lk = lane >> 4;            // 0..3
    const int R0 = blockIdx.x * 64 + wave * 16;
    const bool active = (R0 < N);        // N%16==0: active waves fully in-bounds

    if (active) {
        f32x4 acc[8];
#pragma unroll
        for (int t = 0; t < 8; ++t) acc[t] = (f32x4){0.f, 0.f, 0.f, 0.f};
        const unsigned short* arow = axb + (size_t)(R0 + lrow) * DIM + lk * 8;
#pragma unroll
        for (int kt = 0; kt < 4; ++kt) {
            bf16x8 a = *reinterpret_cast<const bf16x8*>(arow + kt * 32);
#pragma unroll
            for (int t = 0; t < 8; ++t) {
                bf16x8 b = *reinterpret_cast<const bf16x8*>(
                    w1t + (size_t)(t * 16 + lrow) * DIM + kt * 32 + lk * 8);
                acc[t] = __builtin_amdgcn_mfma_f32_16x16x32_bf16(a, b, acc[t], 0, 0, 0);
            }
        }
#pragma unroll
        for (int t = 0; t < 8; ++t) {
#pragma unroll
            for (int r = 0; r < 4; ++r) {
                int col = t * 16 + lrow;
                float v = acc[t][r] + b1[col];
                hs[wave][lk * 4 + r][col] = f2bf(v > 0.f ? v : 0.f);
            }
        }
    }
    __syncthreads();
    if (active) {
        f32x4 acc2[4];
#pragma unroll
        for (int t = 0; t < 4; ++t) acc2[t] = (f32x4){0.f, 0.f, 0.f, 0.f};
        const unsigned short* hrow = &hs[wave][lrow][0];
#pragma unroll
        for (int kt = 0; kt < 4; ++kt) {
            bf16x8 a = *reinterpret_cast<const bf16x8*>(hrow + kt * 32 + lk * 8);
#pragma unroll
            for (int t = 0; t < 4; ++t) {
                bf16x8 b = *reinterpret_cast<const bf16x8*>(
                    wct + (size_t)(t * 16 + lrow) * DIM + kt * 32 + lk * 8);
                acc2[t] = __builtin_amdgcn_mfma_f32_16x16x32_bf16(a, b, acc2[t], 0, 0, 0);
            }
        }
#pragma unroll
        for (int t = 0; t < 4; ++t)
#pragma unroll
            for (int r = 0; r < 4; ++r)
                hwb[(size_t)(R0 + lk * 4 + r) * 64 + t * 16 + lrow] = f2bf(acc2[t][r]);
    }
}

// wave per node; half-waves split even/odd edges (CSR load = broadcast per half);
// lane handles one bf16 dim-pair of hw's 64 dims; halves combined via shfl_xor(32).
__global__ __launch_bounds__(256) void k_gather64(const int2* __restrict__ csr,
                                                  const int* __restrict__ rowptr,
                                                  const float* __restrict__ dinv,
                                                  const unsigned* __restrict__ hwb,
                                                  const float* __restrict__ bm,
                                                  const float* __restrict__ bs,
                                                  float* __restrict__ outm,
                                                  float* __restrict__ outs, int N) {
    int node = (blockIdx.x * 256 + threadIdx.x) >> 6;
    int lane = threadIdx.x & 63;
    if (node >= N) return;
    const int half = lane >> 5;       // 0/1: even/odd edges
    const int dp = lane & 31;         // dim-pair 0..31 (dims 2dp, 2dp+1)
    float di = dinv[node];
    float2 acc = {0.f, 0.f};
    if (half == 0) {                  // self-loop counted once
        float2 v = bfp2f(hwb[(size_t)node * 32 + dp]);
        float s = 2.0f * di;
        acc.x = v.x * s; acc.y = v.y * s;
    }
    int p = rowptr[node] + half, end = rowptr[node + 1];
    for (; p < end; p += 2) {
        int2 e = csr[p];              // broadcast within half
        float n = __int_as_float(e.y) * dinv[e.x];
        float2 v = bfp2f(hwb[(size_t)e.x * 32 + dp]);
        acc.x = fmaf(v.x, n, acc.x);
        acc.y = fmaf(v.y, n, acc.y);
    }
    acc.x += __shfl_xor(acc.x, 32);
    acc.y += __shfl_xor(acc.y, 32);
    if (half == 0) {
        int d0 = dp * 2;
        float2 val;
        if (dp < 16) {
            val.x = acc.x * di + bm[d0];
            val.y = acc.y * di + bm[d0 + 1];
            reinterpret_cast<float2*>(outm + (size_t)node * LAT)[dp] = val;
        } else {
            val.x = acc.x * di + bs[d0 - 32];
            val.y = acc.y * di + bs[d0 - 31];
            reinterpret_cast<float2*>(outs + (size_t)node * LAT)[dp - 16] = val;
        }
    }
}

extern "C" void kernel_launch(void* const* d_in, const int* in_sizes, int n_in,
                              void* d_out, int out_size, void* d_ws, size_t ws_size,
                              hipStream_t stream) {
    const float* x  = (const float*)d_in[0];
    const int*   ei = (const int*)d_in[1];
    const float* ew = (const float*)d_in[2];
    const float* W1 = (const float*)d_in[3];
    const float* b1 = (const float*)d_in[4];
    const float* Wm = (const float*)d_in[5];
    const float* bm = (const float*)d_in[6];
    const float* Ws = (const float*)d_in[7];
    const float* bs = (const float*)d_in[8];

    const int N = in_sizes[0] / DIM;     // 100000
    const int E = in_sizes[1] / 2;       // 1600000
    const int* src = ei;
    const int* dst = ei + E;

    // ---- workspace layout (~85 MB) ----
    char* w = (char*)d_ws;
    unsigned* xb  = (unsigned*)w;            w += (size_t)N * DIM * 2;       // 25.6 MB bf16 x
    unsigned* axb = (unsigned*)w;            w += (size_t)N * DIM * 2;       // 25.6 MB bf16 ax
    unsigned short* hwb = (unsigned short*)w; w += (size_t)N * 64 * 2;       // 12.8 MB bf16 hw
    float* dinv = (float*)w;                 w += (size_t)N * 4;
    int*   cursor = (int*)w;                 w += (size_t)N * 4;             // rank cursor == counts
    int*   rowptr = (int*)w;                 w += (size_t)(N + 1) * 4;
    int*   rank   = (int*)w;                 w += (size_t)E * 4;             // 6.4 MB
    w = (char*)(((size_t)w + 255) & ~(size_t)255);
    int*   bsums  = (int*)w;                 w += 1024 * 4;
    unsigned short* w1t = (unsigned short*)w; w += DIM * DIM * 2;            // 32 KB
    unsigned short* wct = (unsigned short*)w; w += 64 * DIM * 2;             // 16 KB
    w = (char*)(((size_t)w + 255) & ~(size_t)255);
    int2*  csr    = (int2*)w;                // 12.8 MB

    float* outm = (float*)d_out;
    float* outs = outm + (size_t)N * LAT;

    const int B = 256;
    const int NB = (N + SCAN_ELEMS - 1) / SCAN_ELEMS;   // 98

    // 1. rank pass + independent prep (x->bf16, weights)
    hipMemsetAsync(cursor, 0, (size_t)N * 4, stream);
    k_rank<<<(E + B - 1) / B, B, 0, stream>>>(dst, cursor, rank, E);
    k_x2bf<<<((N * DIM / 4) + B - 1) / B, B, 0, stream>>>(x, (uint2*)xb, N * DIM / 4);
    k_prep_w<<<(DIM * DIM + 64 * DIM + B - 1) / B, B, 0, stream>>>(W1, Wm, Ws, w1t, wct);

    // 2. scan counts -> rowptr; place edges (atomic-free); deg -> dinv
    k_scan1<<<NB, B, 0, stream>>>(cursor, rowptr, bsums, N);
    k_scan2<<<1, 1, 0, stream>>>(bsums, rowptr, NB, N, E);
    k_scan3<<<(N + B - 1) / B, B, 0, stream>>>(rowptr, bsums, N);
    k_place<<<(E + B - 1) / B, B, 0, stream>>>(src, dst, ew, rank, rowptr, csr, E);
    k_degseg<<<(N + B - 1) / B, B, 0, stream>>>(csr, rowptr, dinv, N);

    // 3. ax = Agg(xb) -> bf16
    k_gather128<<<(N + 3) / 4, B, 0, stream>>>(csr, rowptr, dinv, xb, axb, N);

    // 4. hwb = bf16( relu(ax@W1+b1) @ [Wm|Ws] )  (MFMA)
    k_mfma_mlp<<<(N + 63) / 64, B, 0, stream>>>((const unsigned short*)axb, w1t, wct, b1, hwb, N);

    // 5. z = Agg(hwb) + bias -> outputs
    k_gather64<<<(N + 3) / 4, B, 0, stream>>>(csr, rowptr, dinv, (const unsigned*)hwb, bm, bs, outm, outs, N);
}

// Round 8
// 345.992 us; speedup vs baseline: 10.1735x; 1.1781x over previous
//
#include <hip/hip_runtime.h>

// VGAE encoder: 3x GCNConv (improved=True), N=100000, E=1600000.
//   xb = bf16(x); ax = Agg(xb) [bf16]; hw = relu(ax@W1+b1)@[Wm|Ws] (MFMA, bf16 out);
//   z = Agg(hw) + [bm|bs]
// R8: MLP (memory-level parallelism) in the gathers. R7's gather128 was
// latency-bound (1.7 TB/s, VALU 30%, 2 loads in flight). Now: half-wave edge
// split + unroll-2 = 4 independent row-loads in flight; halves combined via
// shfl_xor(32).

#define DIM 128
#define LAT 32
#define SCAN_ELEMS 1024   // 256 threads x 4

typedef short bf16x8 __attribute__((ext_vector_type(8)));
typedef float f32x4 __attribute__((ext_vector_type(4)));

__device__ __forceinline__ unsigned short f2bf(float f) {   // RNE
    unsigned u = __float_as_uint(f);
    return (unsigned short)((u + 0x7fffu + ((u >> 16) & 1u)) >> 16);
}
__device__ __forceinline__ unsigned packbf(float a, float b) {
    return (unsigned)f2bf(a) | ((unsigned)f2bf(b) << 16);
}
__device__ __forceinline__ float2 bfp2f(unsigned u) {
    float2 r;
    r.x = __uint_as_float(u << 16);
    r.y = __uint_as_float(u & 0xffff0000u);
    return r;
}

// x [N,128] f32 -> packed bf16 pairs (uint2 per thread = 4 dims)
__global__ void k_x2bf(const float* __restrict__ x, uint2* __restrict__ xb, int n4) {
    int i = blockIdx.x * blockDim.x + threadIdx.x;
    if (i < n4) {
        float4 v = reinterpret_cast<const float4*>(x)[i];
        xb[i] = make_uint2(packbf(v.x, v.y), packbf(v.z, v.w));
    }
}

// pass 1: per-edge within-node rank; cursor ends as per-node counts
__global__ void k_rank(const int* __restrict__ dst, int* __restrict__ cursor,
                       unsigned short* __restrict__ rank, int E) {
    int e = blockIdx.x * blockDim.x + threadIdx.x;
    if (e < E) rank[e] = (unsigned short)atomicAdd(&cursor[dst[e]], 1);
}

// ---- exclusive scan of counts -> rowptr ----
__global__ __launch_bounds__(256) void k_scan1(const int* __restrict__ counts,
                                               int* __restrict__ rowptr,
                                               int* __restrict__ bsums, int N) {
    __shared__ int sdata[256];
    const int t = threadIdx.x;
    const int base = blockIdx.x * SCAN_ELEMS + t * 4;
    int v[4];
#pragma unroll
    for (int j = 0; j < 4; ++j) {
        int idx = base + j;
        v[j] = (idx < N) ? counts[idx] : 0;
    }
    int tot = v[0] + v[1] + v[2] + v[3];
    sdata[t] = tot;
    __syncthreads();
    for (int off = 1; off < 256; off <<= 1) {
        int x = 0;
        if (t >= off) x = sdata[t - off];
        __syncthreads();
        if (t >= off) sdata[t] += x;
        __syncthreads();
    }
    int running = sdata[t] - tot;
#pragma unroll
    for (int j = 0; j < 4; ++j) {
        int idx = base + j;
        if (idx < N) rowptr[idx] = running;
        running += v[j];
    }
    if (t == 255) bsums[blockIdx.x] = sdata[255];
}

__global__ void k_scan2(int* __restrict__ bsums, int* __restrict__ rowptr, int NB, int N, int E) {
    int running = 0;
    for (int b = 0; b < NB; ++b) {
        int t = bsums[b];
        bsums[b] = running;
        running += t;
    }
    rowptr[N] = E;
}

__global__ void k_scan3(int* __restrict__ rowptr, const int* __restrict__ bsums, int N) {
    int i = blockIdx.x * blockDim.x + threadIdx.x;
    if (i < N) rowptr[i] += bsums[i >> 10];
}

// pass 2: place edges into CSR slots — NO atomics. record = {src, raw ew bits}
__global__ void k_place(const int* __restrict__ src, const int* __restrict__ dst,
                        const float* __restrict__ ew, const unsigned short* __restrict__ rank,
                        const int* __restrict__ rowptr, int2* __restrict__ csr, int E) {
    int e = blockIdx.x * blockDim.x + threadIdx.x;
    if (e < E)
        csr[rowptr[dst[e]] + rank[e]] = make_int2(src[e], __float_as_int(ew[e]));
}

// deg[i] = 2 + sum of incoming ew (from CSR, atomic-free) -> dinv in place
__global__ void k_degseg(const int2* __restrict__ csr, const int* __restrict__ rowptr,
                         float* __restrict__ dinv, int N) {
    int i = blockIdx.x * blockDim.x + threadIdx.x;
    if (i >= N) return;
    float deg = 2.0f;   // improved=True self-loop weight
    int p = rowptr[i], end = rowptr[i + 1];
    for (; p < end; ++p) deg += __int_as_float(csr[p].y);
    dinv[i] = (deg > 0.0f) ? rsqrtf(deg) : 0.0f;
}

// weight prep: w1t[c][k] = bf16(W1[k][c]); wct[c][k] = bf16([Wm|Ws][k][c])
__global__ void k_prep_w(const float* __restrict__ W1, const float* __restrict__ Wm,
                         const float* __restrict__ Ws, unsigned short* __restrict__ w1t,
                         unsigned short* __restrict__ wct) {
    int i = blockIdx.x * 256 + threadIdx.x;
    if (i < DIM * DIM) {
        int c = i >> 7, k = i & 127;
        w1t[c * DIM + k] = f2bf(W1[k * DIM + c]);
    }
    i -= DIM * DIM;
    if (i >= 0 && i < 64 * DIM) {
        int c = i >> 7, k = i & 127;
        wct[c * DIM + k] = f2bf((c < LAT) ? Wm[k * LAT + c] : Ws[k * LAT + (c - LAT)]);
    }
}

// wave per node; half-waves take contiguous edge chunks (convergent, +-1 iter);
// lane covers dims 4l..4l+3 via uint2 (32 lanes x 8B = 256B/row); unroll-2 per
// half = 4 row-loads in flight. Halves combined via shfl_xor(32).
// Deferred norm: ax = di*(2*di*x[d] + sum ew*dinv[s]*x[s]).
__global__ __launch_bounds__(256) void k_gather128(const int2* __restrict__ csr,
                                                   const int* __restrict__ rowptr,
                                                   const float* __restrict__ dinv,
                                                   const uint2* __restrict__ xb,
                                                   uint2* __restrict__ axb, int N) {
    int node = (blockIdx.x * 256 + threadIdx.x) >> 6;
    int lane = threadIdx.x & 63;
    if (node >= N) return;
    const int half = lane >> 5;
    const int l = lane & 31;
    float di = dinv[node];
    float4 acc = {0.f, 0.f, 0.f, 0.f};
    if (half == 0) {                  // self-loop once
        uint2 sv = xb[(size_t)node * 32 + l];
        float2 s0 = bfp2f(sv.x), s1 = bfp2f(sv.y);
        float sl = 2.0f * di;
        acc.x = s0.x * sl; acc.y = s0.y * sl;
        acc.z = s1.x * sl; acc.w = s1.y * sl;
    }
    int p0 = rowptr[node];
    int d = rowptr[node + 1] - p0;
    int c0 = (d + 1) >> 1;            // half 0 chunk size
    int p = p0 + (half ? c0 : 0);
    int end = p0 + (half ? d : c0);
    for (; p + 1 < end; p += 2) {
        int2 e0 = csr[p];
        int2 e1 = csr[p + 1];
        float n0 = __int_as_float(e0.y) * dinv[e0.x];
        float n1 = __int_as_float(e1.y) * dinv[e1.x];
        uint2 u0 = xb[(size_t)e0.x * 32 + l];
        uint2 u1 = xb[(size_t)e1.x * 32 + l];
        float2 a0 = bfp2f(u0.x), a1 = bfp2f(u0.y);
        float2 b0 = bfp2f(u1.x), b1 = bfp2f(u1.y);
        acc.x = fmaf(a0.x, n0, acc.x); acc.y = fmaf(a0.y, n0, acc.y);
        acc.z = fmaf(a1.x, n0, acc.z); acc.w = fmaf(a1.y, n0, acc.w);
        acc.x = fmaf(b0.x, n1, acc.x); acc.y = fmaf(b0.y, n1, acc.y);
        acc.z = fmaf(b1.x, n1, acc.z); acc.w = fmaf(b1.y, n1, acc.w);
    }
    if (p < end) {
        int2 e0 = csr[p];
        float n0 = __int_as_float(e0.y) * dinv[e0.x];
        uint2 u0 = xb[(size_t)e0.x * 32 + l];
        float2 a0 = bfp2f(u0.x), a1 = bfp2f(u0.y);
        acc.x = fmaf(a0.x, n0, acc.x); acc.y = fmaf(a0.y, n0, acc.y);
        acc.z = fmaf(a1.x, n0, acc.z); acc.w = fmaf(a1.y, n0, acc.w);
    }
    acc.x += __shfl_xor(acc.x, 32);
    acc.y += __shfl_xor(acc.y, 32);
    acc.z += __shfl_xor(acc.z, 32);
    acc.w += __shfl_xor(acc.w, 32);
    if (half == 0) {
        axb[(size_t)node * 32 + l] =
            make_uint2(packbf(acc.x * di, acc.y * di), packbf(acc.z * di, acc.w * di));
    }
}

// MFMA MLP: hwb = bf16( relu(axb @ W1 + b1) @ Wcat ).  Block = 64 rows, 4 waves.
__global__ __launch_bounds__(256) void k_mfma_mlp(const unsigned short* __restrict__ axb,
                                                  const unsigned short* __restrict__ w1t,
                                                  const unsigned short* __restrict__ wct,
                                                  const float* __restrict__ b1,
                                                  unsigned short* __restrict__ hwb, int N) {
    __shared__ __align__(16) unsigned short hs[4][16][136];  // +8 pad: bank spread
    const int wave = threadIdx.x >> 6;
    const int lane = threadIdx.x & 63;
    const int lrow = lane & 15;
    const int lk = lane >> 4;            // 0..3
    const int R0 = blockIdx.x * 64 + wave * 16;
    const bool active = (R0 < N);        // N%16==0: active waves fully in-bounds

    if (active) {
        f32x4 acc[8];
#pragma unroll
        for (int t = 0; t < 8; ++t) acc[t] = (f32x4){0.f, 0.f, 0.f, 0.f};
        const unsigned short* arow = axb + (size_t)(R0 + lrow) * DIM + lk * 8;
#pragma unroll
        for (int kt = 0; kt < 4; ++kt) {
            bf16x8 a = *reinterpret_cast<const bf16x8*>(arow + kt * 32);
#pragma unroll
            for (int t = 0; t < 8; ++t) {
                bf16x8 b = *reinterpret_cast<const bf16x8*>(
                    w1t + (size_t)(t * 16 + lrow) * DIM + kt * 32 + lk * 8);
                acc[t] = __builtin_amdgcn_mfma_f32_16x16x32_bf16(a, b, acc[t], 0, 0, 0);
            }
        }
#pragma unroll
        for (int t = 0; t < 8; ++t) {
#pragma unroll
            for (int r = 0; r < 4; ++r) {
                int col = t * 16 + lrow;
                float v = acc[t][r] + b1[col];
                hs[wave][lk * 4 + r][col] = f2bf(v > 0.f ? v : 0.f);
            }
        }
    }
    __syncthreads();
    if (active) {
        f32x4 acc2[4];
#pragma unroll
        for (int t = 0; t < 4; ++t) acc2[t] = (f32x4){0.f, 0.f, 0.f, 0.f};
        const unsigned short* hrow = &hs[wave][lrow][0];
#pragma unroll
        for (int kt = 0; kt < 4; ++kt) {
            bf16x8 a = *reinterpret_cast<const bf16x8*>(hrow + kt * 32 + lk * 8);
#pragma unroll
            for (int t = 0; t < 4; ++t) {
                bf16x8 b = *reinterpret_cast<const bf16x8*>(
                    wct + (size_t)(t * 16 + lrow) * DIM + kt * 32 + lk * 8);
                acc2[t] = __builtin_amdgcn_mfma_f32_16x16x32_bf16(a, b, acc2[t], 0, 0, 0);
            }
        }
#pragma unroll
        for (int t = 0; t < 4; ++t)
#pragma unroll
            for (int r = 0; r < 4; ++r)
                hwb[(size_t)(R0 + lk * 4 + r) * 64 + t * 16 + lrow] = f2bf(acc2[t][r]);
    }
}

// wave per node; half-wave contiguous edge chunks, lane = dim-pair (uint, 128B/row),
// unroll-2 per half = 4 row-loads in flight; shfl_xor(32) combine.
__global__ __launch_bounds__(256) void k_gather64(const int2* __restrict__ csr,
                                                  const int* __restrict__ rowptr,
                                                  const float* __restrict__ dinv,
                                                  const unsigned* __restrict__ hwb,
                                                  const float* __restrict__ bm,
                                                  const float* __restrict__ bs,
                                                  float* __restrict__ outm,
                                                  float* __restrict__ outs, int N) {
    int node = (blockIdx.x * 256 + threadIdx.x) >> 6;
    int lane = threadIdx.x & 63;
    if (node >= N) return;
    const int half = lane >> 5;
    const int dp = lane & 31;         // dim-pair 0..31 (dims 2dp, 2dp+1)
    float di = dinv[node];
    float2 acc = {0.f, 0.f};
    if (half == 0) {                  // self-loop once
        float2 v = bfp2f(hwb[(size_t)node * 32 + dp]);
        float s = 2.0f * di;
        acc.x = v.x * s; acc.y = v.y * s;
    }
    int p0 = rowptr[node];
    int d = rowptr[node + 1] - p0;
    int c0 = (d + 1) >> 1;
    int p = p0 + (half ? c0 : 0);
    int end = p0 + (half ? d : c0);
    for (; p + 1 < end; p += 2) {
        int2 e0 = csr[p];
        int2 e1 = csr[p + 1];
        float n0 = __int_as_float(e0.y) * dinv[e0.x];
        float n1 = __int_as_float(e1.y) * dinv[e1.x];
        float2 v0 = bfp2f(hwb[(size_t)e0.x * 32 + dp]);
        float2 v1 = bfp2f(hwb[(size_t)e1.x * 32 + dp]);
        acc.x = fmaf(v0.x, n0, acc.x); acc.y = fmaf(v0.y, n0, acc.y);
        acc.x = fmaf(v1.x, n1, acc.x); acc.y = fmaf(v1.y, n1, acc.y);
    }
    if (p < end) {
        int2 e = csr[p];
        float n = __int_as_float(e.y) * dinv[e.x];
        float2 v = bfp2f(hwb[(size_t)e.x * 32 + dp]);
        acc.x = fmaf(v.x, n, acc.x);
        acc.y = fmaf(v.y, n, acc.y);
    }
    acc.x += __shfl_xor(acc.x, 32);
    acc.y += __shfl_xor(acc.y, 32);
    if (half == 0) {
        int d0 = dp * 2;
        float2 val;
        if (dp < 16) {
            val.x = acc.x * di + bm[d0];
            val.y = acc.y * di + bm[d0 + 1];
            reinterpret_cast<float2*>(outm + (size_t)node * LAT)[dp] = val;
        } else {
            val.x = acc.x * di + bs[d0 - 32];
            val.y = acc.y * di + bs[d0 - 31];
            reinterpret_cast<float2*>(outs + (size_t)node * LAT)[dp - 16] = val;
        }
    }
}

extern "C" void kernel_launch(void* const* d_in, const int* in_sizes, int n_in,
                              void* d_out, int out_size, void* d_ws, size_t ws_size,
                              hipStream_t stream) {
    const float* x  = (const float*)d_in[0];
    const int*   ei = (const int*)d_in[1];
    const float* ew = (const float*)d_in[2];
    const float* W1 = (const float*)d_in[3];
    const float* b1 = (const float*)d_in[4];
    const float* Wm = (const float*)d_in[5];
    const float* bm = (const float*)d_in[6];
    const float* Ws = (const float*)d_in[7];
    const float* bs = (const float*)d_in[8];

    const int N = in_sizes[0] / DIM;     // 100000
    const int E = in_sizes[1] / 2;       // 1600000
    const int* src = ei;
    const int* dst = ei + E;

    // ---- workspace layout (~82 MB) ----
    char* w = (char*)d_ws;
    unsigned* xb  = (unsigned*)w;            w += (size_t)N * DIM * 2;       // 25.6 MB bf16 x
    unsigned* axb = (unsigned*)w;            w += (size_t)N * DIM * 2;       // 25.6 MB bf16 ax
    unsigned short* hwb = (unsigned short*)w; w += (size_t)N * 64 * 2;       // 12.8 MB bf16 hw
    float* dinv = (float*)w;                 w += (size_t)N * 4;
    int*   cursor = (int*)w;                 w += (size_t)N * 4;             // rank cursor == counts
    int*   rowptr = (int*)w;                 w += (size_t)(N + 1) * 4;
    unsigned short* rank = (unsigned short*)w; w += (size_t)E * 2;           // 3.2 MB
    w = (char*)(((size_t)w + 255) & ~(size_t)255);
    int*   bsums  = (int*)w;                 w += 1024 * 4;
    unsigned short* w1t = (unsigned short*)w; w += DIM * DIM * 2;            // 32 KB
    unsigned short* wct = (unsigned short*)w; w += 64 * DIM * 2;             // 16 KB
    w = (char*)(((size_t)w + 255) & ~(size_t)255);
    int2*  csr    = (int2*)w;                // 12.8 MB

    float* outm = (float*)d_out;
    float* outs = outm + (size_t)N * LAT;

    const int B = 256;
    const int NB = (N + SCAN_ELEMS - 1) / SCAN_ELEMS;   // 98

    // 1. rank pass + independent prep (x->bf16, weights)
    hipMemsetAsync(cursor, 0, (size_t)N * 4, stream);
    k_rank<<<(E + B - 1) / B, B, 0, stream>>>(dst, cursor, rank, E);
    k_x2bf<<<((N * DIM / 4) + B - 1) / B, B, 0, stream>>>(x, (uint2*)xb, N * DIM / 4);
    k_prep_w<<<(DIM * DIM + 64 * DIM + B - 1) / B, B, 0, stream>>>(W1, Wm, Ws, w1t, wct);

    // 2. scan counts -> rowptr; place edges (atomic-free); deg -> dinv
    k_scan1<<<NB, B, 0, stream>>>(cursor, rowptr, bsums, N);
    k_scan2<<<1, 1, 0, stream>>>(bsums, rowptr, NB, N, E);
    k_scan3<<<(N + B - 1) / B, B, 0, stream>>>(rowptr, bsums, N);
    k_place<<<(E + B - 1) / B, B, 0, stream>>>(src, dst, ew, rank, rowptr, csr, E);
    k_degseg<<<(N + B - 1) / B, B, 0, stream>>>(csr, rowptr, dinv, N);

    // 3. ax = Agg(xb) -> bf16
    k_gather128<<<(N + 3) / 4, B, 0, stream>>>(csr, rowptr, dinv, (const uint2*)xb, (uint2*)axb, N);

    // 4. hwb = bf16( relu(ax@W1+b1) @ [Wm|Ws] )  (MFMA)
    k_mfma_mlp<<<(N + 63) / 64, B, 0, stream>>>((const unsigned short*)axb, w1t, wct, b1, hwb, N);

    // 5. z = Agg(hwb) + bias -> outputs
    k_gather64<<<(N + 3) / 4, B, 0, stream>>>(csr, rowptr, dinv, (const unsigned*)hwb, bm, bs, outm, outs, N);
}

// Round 9
// 314.372 us; speedup vs baseline: 11.1967x; 1.1006x over previous
//
#include <hip/hip_runtime.h>

// VGAE encoder: 3x GCNConv (improved=True), N=100000, E=1600000.
//   xb = bf16(x); ax = Agg(xb) [bf16]; hw = relu(ax@W1+b1)@[Wm|Ws] (MFMA, bf16 out);
//   z = Agg(hw) + [bm|bs]
// R9: (a) unroll-4 per half-wave in both gathers -> 8 row-loads in flight
// (R8 showed stream count is the lever); (b) k_rank cursor padded to one
// counter per 128B line -> kills TCC line-level atomic serialization.

#define DIM 128
#define LAT 32
#define SCAN_ELEMS 1024   // 256 threads x 4
#define CPAD 32           // cursor padding stride (ints) = 128B line

typedef short bf16x8 __attribute__((ext_vector_type(8)));
typedef float f32x4 __attribute__((ext_vector_type(4)));

__device__ __forceinline__ unsigned short f2bf(float f) {   // RNE
    unsigned u = __float_as_uint(f);
    return (unsigned short)((u + 0x7fffu + ((u >> 16) & 1u)) >> 16);
}
__device__ __forceinline__ unsigned packbf(float a, float b) {
    return (unsigned)f2bf(a) | ((unsigned)f2bf(b) << 16);
}
__device__ __forceinline__ float2 bfp2f(unsigned u) {
    float2 r;
    r.x = __uint_as_float(u << 16);
    r.y = __uint_as_float(u & 0xffff0000u);
    return r;
}

// x [N,128] f32 -> packed bf16 pairs (uint2 per thread = 4 dims)
__global__ void k_x2bf(const float* __restrict__ x, uint2* __restrict__ xb, int n4) {
    int i = blockIdx.x * blockDim.x + threadIdx.x;
    if (i < n4) {
        float4 v = reinterpret_cast<const float4*>(x)[i];
        xb[i] = make_uint2(packbf(v.x, v.y), packbf(v.z, v.w));
    }
}

// pass 1: per-edge within-node rank; padded cursor (1 counter / 128B line)
__global__ void k_rank(const int* __restrict__ dst, int* __restrict__ cursorPad,
                       unsigned short* __restrict__ rank, int E) {
    int e = blockIdx.x * blockDim.x + threadIdx.x;
    if (e < E) rank[e] = (unsigned short)atomicAdd(&cursorPad[(size_t)dst[e] * CPAD], 1);
}

// ---- exclusive scan of padded counts -> rowptr ----
__global__ __launch_bounds__(256) void k_scan1(const int* __restrict__ countsPad,
                                               int* __restrict__ rowptr,
                                               int* __restrict__ bsums, int N) {
    __shared__ int sdata[256];
    const int t = threadIdx.x;
    const int base = blockIdx.x * SCAN_ELEMS + t * 4;
    int v[4];
#pragma unroll
    for (int j = 0; j < 4; ++j) {
        int idx = base + j;
        v[j] = (idx < N) ? countsPad[(size_t)idx * CPAD] : 0;
    }
    int tot = v[0] + v[1] + v[2] + v[3];
    sdata[t] = tot;
    __syncthreads();
    for (int off = 1; off < 256; off <<= 1) {
        int x = 0;
        if (t >= off) x = sdata[t - off];
        __syncthreads();
        if (t >= off) sdata[t] += x;
        __syncthreads();
    }
    int running = sdata[t] - tot;
#pragma unroll
    for (int j = 0; j < 4; ++j) {
        int idx = base + j;
        if (idx < N) rowptr[idx] = running;
        running += v[j];
    }
    if (t == 255) bsums[blockIdx.x] = sdata[255];
}

__global__ void k_scan2(int* __restrict__ bsums, int* __restrict__ rowptr, int NB, int N, int E) {
    int running = 0;
    for (int b = 0; b < NB; ++b) {
        int t = bsums[b];
        bsums[b] = running;
        running += t;
    }
    rowptr[N] = E;
}

__global__ void k_scan3(int* __restrict__ rowptr, const int* __restrict__ bsums, int N) {
    int i = blockIdx.x * blockDim.x + threadIdx.x;
    if (i < N) rowptr[i] += bsums[i >> 10];
}

// pass 2: place edges into CSR slots — NO atomics. record = {src, raw ew bits}
__global__ void k_place(const int* __restrict__ src, const int* __restrict__ dst,
                        const float* __restrict__ ew, const unsigned short* __restrict__ rank,
                        const int* __restrict__ rowptr, int2* __restrict__ csr, int E) {
    int e = blockIdx.x * blockDim.x + threadIdx.x;
    if (e < E)
        csr[rowptr[dst[e]] + rank[e]] = make_int2(src[e], __float_as_int(ew[e]));
}

// deg[i] = 2 + sum of incoming ew (from CSR, atomic-free) -> dinv in place
__global__ void k_degseg(const int2* __restrict__ csr, const int* __restrict__ rowptr,
                         float* __restrict__ dinv, int N) {
    int i = blockIdx.x * blockDim.x + threadIdx.x;
    if (i >= N) return;
    float deg = 2.0f;   // improved=True self-loop weight
    int p = rowptr[i], end = rowptr[i + 1];
    for (; p < end; ++p) deg += __int_as_float(csr[p].y);
    dinv[i] = (deg > 0.0f) ? rsqrtf(deg) : 0.0f;
}

// weight prep: w1t[c][k] = bf16(W1[k][c]); wct[c][k] = bf16([Wm|Ws][k][c])
__global__ void k_prep_w(const float* __restrict__ W1, const float* __restrict__ Wm,
                         const float* __restrict__ Ws, unsigned short* __restrict__ w1t,
                         unsigned short* __restrict__ wct) {
    int i = blockIdx.x * 256 + threadIdx.x;
    if (i < DIM * DIM) {
        int c = i >> 7, k = i & 127;
        w1t[c * DIM + k] = f2bf(W1[k * DIM + c]);
    }
    i -= DIM * DIM;
    if (i >= 0 && i < 64 * DIM) {
        int c = i >> 7, k = i & 127;
        wct[c * DIM + k] = f2bf((c < LAT) ? Wm[k * LAT + c] : Ws[k * LAT + (c - LAT)]);
    }
}

// wave per node; half-wave contiguous edge chunks; lane = 4 dims (uint2);
// unroll-4 per half = 8 row-loads in flight. shfl_xor(32) combine.
// Deferred norm: ax = di*(2*di*x[d] + sum ew*dinv[s]*x[s]).
__global__ __launch_bounds__(256) void k_gather128(const int2* __restrict__ csr,
                                                   const int* __restrict__ rowptr,
                                                   const float* __restrict__ dinv,
                                                   const uint2* __restrict__ xb,
                                                   uint2* __restrict__ axb, int N) {
    int node = (blockIdx.x * 256 + threadIdx.x) >> 6;
    int lane = threadIdx.x & 63;
    if (node >= N) return;
    const int half = lane >> 5;
    const int l = lane & 31;
    float di = dinv[node];
    float4 acc = {0.f, 0.f, 0.f, 0.f};
    if (half == 0) {                  // self-loop once
        uint2 sv = xb[(size_t)node * 32 + l];
        float2 s0 = bfp2f(sv.x), s1 = bfp2f(sv.y);
        float sl = 2.0f * di;
        acc.x = s0.x * sl; acc.y = s0.y * sl;
        acc.z = s1.x * sl; acc.w = s1.y * sl;
    }
    int p0 = rowptr[node];
    int d = rowptr[node + 1] - p0;
    int c0 = (d + 1) >> 1;            // half 0 chunk size
    int p = p0 + (half ? c0 : 0);
    int end = p0 + (half ? d : c0);
    for (; p + 3 < end; p += 4) {
        int2 e0 = csr[p], e1 = csr[p + 1], e2 = csr[p + 2], e3 = csr[p + 3];
        float n0 = __int_as_float(e0.y) * dinv[e0.x];
        float n1 = __int_as_float(e1.y) * dinv[e1.x];
        float n2 = __int_as_float(e2.y) * dinv[e2.x];
        float n3 = __int_as_float(e3.y) * dinv[e3.x];
        uint2 u0 = xb[(size_t)e0.x * 32 + l];
        uint2 u1 = xb[(size_t)e1.x * 32 + l];
        uint2 u2 = xb[(size_t)e2.x * 32 + l];
        uint2 u3 = xb[(size_t)e3.x * 32 + l];
        float2 a0 = bfp2f(u0.x), a1 = bfp2f(u0.y);
        float2 b0 = bfp2f(u1.x), b1 = bfp2f(u1.y);
        float2 c0f = bfp2f(u2.x), c1 = bfp2f(u2.y);
        float2 d0 = bfp2f(u3.x), d1 = bfp2f(u3.y);
        acc.x = fmaf(a0.x, n0, acc.x); acc.y = fmaf(a0.y, n0, acc.y);
        acc.z = fmaf(a1.x, n0, acc.z); acc.w = fmaf(a1.y, n0, acc.w);
        acc.x = fmaf(b0.x, n1, acc.x); acc.y = fmaf(b0.y, n1, acc.y);
        acc.z = fmaf(b1.x, n1, acc.z); acc.w = fmaf(b1.y, n1, acc.w);
        acc.x = fmaf(c0f.x, n2, acc.x); acc.y = fmaf(c0f.y, n2, acc.y);
        acc.z = fmaf(c1.x, n2, acc.z); acc.w = fmaf(c1.y, n2, acc.w);
        acc.x = fmaf(d0.x, n3, acc.x); acc.y = fmaf(d0.y, n3, acc.y);
        acc.z = fmaf(d1.x, n3, acc.z); acc.w = fmaf(d1.y, n3, acc.w);
    }
    for (; p + 1 < end; p += 2) {
        int2 e0 = csr[p], e1 = csr[p + 1];
        float n0 = __int_as_float(e0.y) * dinv[e0.x];
        float n1 = __int_as_float(e1.y) * dinv[e1.x];
        uint2 u0 = xb[(size_t)e0.x * 32 + l];
        uint2 u1 = xb[(size_t)e1.x * 32 + l];
        float2 a0 = bfp2f(u0.x), a1 = bfp2f(u0.y);
        float2 b0 = bfp2f(u1.x), b1 = bfp2f(u1.y);
        acc.x = fmaf(a0.x, n0, acc.x); acc.y = fmaf(a0.y, n0, acc.y);
        acc.z = fmaf(a1.x, n0, acc.z); acc.w = fmaf(a1.y, n0, acc.w);
        acc.x = fmaf(b0.x, n1, acc.x); acc.y = fmaf(b0.y, n1, acc.y);
        acc.z = fmaf(b1.x, n1, acc.z); acc.w = fmaf(b1.y, n1, acc.w);
    }
    if (p < end) {
        int2 e0 = csr[p];
        float n0 = __int_as_float(e0.y) * dinv[e0.x];
        uint2 u0 = xb[(size_t)e0.x * 32 + l];
        float2 a0 = bfp2f(u0.x), a1 = bfp2f(u0.y);
        acc.x = fmaf(a0.x, n0, acc.x); acc.y = fmaf(a0.y, n0, acc.y);
        acc.z = fmaf(a1.x, n0, acc.z); acc.w = fmaf(a1.y, n0, acc.w);
    }
    acc.x += __shfl_xor(acc.x, 32);
    acc.y += __shfl_xor(acc.y, 32);
    acc.z += __shfl_xor(acc.z, 32);
    acc.w += __shfl_xor(acc.w, 32);
    if (half == 0) {
        axb[(size_t)node * 32 + l] =
            make_uint2(packbf(acc.x * di, acc.y * di), packbf(acc.z * di, acc.w * di));
    }
}

// MFMA MLP: hwb = bf16( relu(axb @ W1 + b1) @ Wcat ).  Block = 64 rows, 4 waves.
__global__ __launch_bounds__(256) void k_mfma_mlp(const unsigned short* __restrict__ axb,
                                                  const unsigned short* __restrict__ w1t,
                                                  const unsigned short* __restrict__ wct,
                                                  const float* __restrict__ b1,
                                                  unsigned short* __restrict__ hwb, int N) {
    __shared__ __align__(16) unsigned short hs[4][16][136];  // +8 pad: bank spread
    const int wave = threadIdx.x >> 6;
    const int lane = threadIdx.x & 63;
    const int lrow = lane & 15;
    const int lk = lane >> 4;            // 0..3
    const int R0 = blockIdx.x * 64 + wave * 16;
    const bool active = (R0 < N);        // N%16==0: active waves fully in-bounds

    if (active) {
        f32x4 acc[8];
#pragma unroll
        for (int t = 0; t < 8; ++t) acc[t] = (f32x4){0.f, 0.f, 0.f, 0.f};
        const unsigned short* arow = axb + (size_t)(R0 + lrow) * DIM + lk * 8;
#pragma unroll
        for (int kt = 0; kt < 4; ++kt) {
            bf16x8 a = *reinterpret_cast<const bf16x8*>(arow + kt * 32);
#pragma unroll
            for (int t = 0; t < 8; ++t) {
                bf16x8 b = *reinterpret_cast<const bf16x8*>(
                    w1t + (size_t)(t * 16 + lrow) * DIM + kt * 32 + lk * 8);
                acc[t] = __builtin_amdgcn_mfma_f32_16x16x32_bf16(a, b, acc[t], 0, 0, 0);
            }
        }
#pragma unroll
        for (int t = 0; t < 8; ++t) {
#pragma unroll
            for (int r = 0; r < 4; ++r) {
                int col = t * 16 + lrow;
                float v = acc[t][r] + b1[col];
                hs[wave][lk * 4 + r][col] = f2bf(v > 0.f ? v : 0.f);
            }
        }
    }
    __syncthreads();
    if (active) {
        f32x4 acc2[4];
#pragma unroll
        for (int t = 0; t < 4; ++t) acc2[t] = (f32x4){0.f, 0.f, 0.f, 0.f};
        const unsigned short* hrow = &hs[wave][lrow][0];
#pragma unroll
        for (int kt = 0; kt < 4; ++kt) {
            bf16x8 a = *reinterpret_cast<const bf16x8*>(hrow + kt * 32 + lk * 8);
#pragma unroll
            for (int t = 0; t < 4; ++t) {
                bf16x8 b = *reinterpret_cast<const bf16x8*>(
                    wct + (size_t)(t * 16 + lrow) * DIM + kt * 32 + lk * 8);
                acc2[t] = __builtin_amdgcn_mfma_f32_16x16x32_bf16(a, b, acc2[t], 0, 0, 0);
            }
        }
#pragma unroll
        for (int t = 0; t < 4; ++t)
#pragma unroll
            for (int r = 0; r < 4; ++r)
                hwb[(size_t)(R0 + lk * 4 + r) * 64 + t * 16 + lrow] = f2bf(acc2[t][r]);
    }
}

// wave per node; half-wave chunks, lane = dim-pair; unroll-4 per half = 8 streams.
__global__ __launch_bounds__(256) void k_gather64(const int2* __restrict__ csr,
                                                  const int* __restrict__ rowptr,
                                                  const float* __restrict__ dinv,
                                                  const unsigned* __restrict__ hwb,
                                                  const float* __restrict__ bm,
                                                  const float* __restrict__ bs,
                                                  float* __restrict__ outm,
                                                  float* __restrict__ outs, int N) {
    int node = (blockIdx.x * 256 + threadIdx.x) >> 6;
    int lane = threadIdx.x & 63;
    if (node >= N) return;
    const int half = lane >> 5;
    const int dp = lane & 31;         // dim-pair 0..31 (dims 2dp, 2dp+1)
    float di = dinv[node];
    float2 acc = {0.f, 0.f};
    if (half == 0) {                  // self-loop once
        float2 v = bfp2f(hwb[(size_t)node * 32 + dp]);
        float s = 2.0f * di;
        acc.x = v.x * s; acc.y = v.y * s;
    }
    int p0 = rowptr[node];
    int d = rowptr[node + 1] - p0;
    int c0 = (d + 1) >> 1;
    int p = p0 + (half ? c0 : 0);
    int end = p0 + (half ? d : c0);
    for (; p + 3 < end; p += 4) {
        int2 e0 = csr[p], e1 = csr[p + 1], e2 = csr[p + 2], e3 = csr[p + 3];
        float n0 = __int_as_float(e0.y) * dinv[e0.x];
        float n1 = __int_as_float(e1.y) * dinv[e1.x];
        float n2 = __int_as_float(e2.y) * dinv[e2.x];
        float n3 = __int_as_float(e3.y) * dinv[e3.x];
        float2 v0 = bfp2f(hwb[(size_t)e0.x * 32 + dp]);
        float2 v1 = bfp2f(hwb[(size_t)e1.x * 32 + dp]);
        float2 v2 = bfp2f(hwb[(size_t)e2.x * 32 + dp]);
        float2 v3 = bfp2f(hwb[(size_t)e3.x * 32 + dp]);
        acc.x = fmaf(v0.x, n0, acc.x); acc.y = fmaf(v0.y, n0, acc.y);
        acc.x = fmaf(v1.x, n1, acc.x); acc.y = fmaf(v1.y, n1, acc.y);
        acc.x = fmaf(v2.x, n2, acc.x); acc.y = fmaf(v2.y, n2, acc.y);
        acc.x = fmaf(v3.x, n3, acc.x); acc.y = fmaf(v3.y, n3, acc.y);
    }
    for (; p + 1 < end; p += 2) {
        int2 e0 = csr[p], e1 = csr[p + 1];
        float n0 = __int_as_float(e0.y) * dinv[e0.x];
        float n1 = __int_as_float(e1.y) * dinv[e1.x];
        float2 v0 = bfp2f(hwb[(size_t)e0.x * 32 + dp]);
        float2 v1 = bfp2f(hwb[(size_t)e1.x * 32 + dp]);
        acc.x = fmaf(v0.x, n0, acc.x); acc.y = fmaf(v0.y, n0, acc.y);
        acc.x = fmaf(v1.x, n1, acc.x); acc.y = fmaf(v1.y, n1, acc.y);
    }
    if (p < end) {
        int2 e = csr[p];
        float n = __int_as_float(e.y) * dinv[e.x];
        float2 v = bfp2f(hwb[(size_t)e.x * 32 + dp]);
        acc.x = fmaf(v.x, n, acc.x);
        acc.y = fmaf(v.y, n, acc.y);
    }
    acc.x += __shfl_xor(acc.x, 32);
    acc.y += __shfl_xor(acc.y, 32);
    if (half == 0) {
        int d0 = dp * 2;
        float2 val;
        if (dp < 16) {
            val.x = acc.x * di + bm[d0];
            val.y = acc.y * di + bm[d0 + 1];
            reinterpret_cast<float2*>(outm + (size_t)node * LAT)[dp] = val;
        } else {
            val.x = acc.x * di + bs[d0 - 32];
            val.y = acc.y * di + bs[d0 - 31];
            reinterpret_cast<float2*>(outs + (size_t)node * LAT)[dp - 16] = val;
        }
    }
}

extern "C" void kernel_launch(void* const* d_in, const int* in_sizes, int n_in,
                              void* d_out, int out_size, void* d_ws, size_t ws_size,
                              hipStream_t stream) {
    const float* x  = (const float*)d_in[0];
    const int*   ei = (const int*)d_in[1];
    const float* ew = (const float*)d_in[2];
    const float* W1 = (const float*)d_in[3];
    const float* b1 = (const float*)d_in[4];
    const float* Wm = (const float*)d_in[5];
    const float* bm = (const float*)d_in[6];
    const float* Ws = (const float*)d_in[7];
    const float* bs = (const float*)d_in[8];

    const int N = in_sizes[0] / DIM;     // 100000
    const int E = in_sizes[1] / 2;       // 1600000
    const int* src = ei;
    const int* dst = ei + E;

    // ---- workspace layout (~94 MB) ----
    char* w = (char*)d_ws;
    unsigned* xb  = (unsigned*)w;            w += (size_t)N * DIM * 2;       // 25.6 MB bf16 x
    unsigned* axb = (unsigned*)w;            w += (size_t)N * DIM * 2;       // 25.6 MB bf16 ax
    unsigned short* hwb = (unsigned short*)w; w += (size_t)N * 64 * 2;       // 12.8 MB bf16 hw
    float* dinv = (float*)w;                 w += (size_t)N * 4;
    int*   rowptr = (int*)w;                 w += (size_t)(N + 1) * 4;
    unsigned short* rank = (unsigned short*)w; w += (size_t)E * 2;           // 3.2 MB
    w = (char*)(((size_t)w + 255) & ~(size_t)255);
    int*   bsums  = (int*)w;                 w += 1024 * 4;
    unsigned short* w1t = (unsigned short*)w; w += DIM * DIM * 2;            // 32 KB
    unsigned short* wct = (unsigned short*)w; w += 64 * DIM * 2;             // 16 KB
    w = (char*)(((size_t)w + 255) & ~(size_t)255);
    int*   cursorPad = (int*)w;              w += (size_t)N * CPAD * 4;      // 12.8 MB padded
    w = (char*)(((size_t)w + 255) & ~(size_t)255);
    int2*  csr    = (int2*)w;                // 12.8 MB

    float* outm = (float*)d_out;
    float* outs = outm + (size_t)N * LAT;

    const int B = 256;
    const int NB = (N + SCAN_ELEMS - 1) / SCAN_ELEMS;   // 98

    // 1. rank pass (padded cursor) + independent prep (x->bf16, weights)
    hipMemsetAsync(cursorPad, 0, (size_t)N * CPAD * 4, stream);
    k_rank<<<(E + B - 1) / B, B, 0, stream>>>(dst, cursorPad, rank, E);
    k_x2bf<<<((N * DIM / 4) + B - 1) / B, B, 0, stream>>>(x, (uint2*)xb, N * DIM / 4);
    k_prep_w<<<(DIM * DIM + 64 * DIM + B - 1) / B, B, 0, stream>>>(W1, Wm, Ws, w1t, wct);

    // 2. scan padded counts -> rowptr; place edges (atomic-free); deg -> dinv
    k_scan1<<<NB, B, 0, stream>>>(cursorPad, rowptr, bsums, N);
    k_scan2<<<1, 1, 0, stream>>>(bsums, rowptr, NB, N, E);
    k_scan3<<<(N + B - 1) / B, B, 0, stream>>>(rowptr, bsums, N);
    k_place<<<(E + B - 1) / B, B, 0, stream>>>(src, dst, ew, rank, rowptr, csr, E);
    k_degseg<<<(N + B - 1) / B, B, 0, stream>>>(csr, rowptr, dinv, N);

    // 3. ax = Agg(xb) -> bf16
    k_gather128<<<(N + 3) / 4, B, 0, stream>>>(csr, rowptr, dinv, (const uint2*)xb, (uint2*)axb, N);

    // 4. hwb = bf16( relu(ax@W1+b1) @ [Wm|Ws] )  (MFMA)
    k_mfma_mlp<<<(N + 63) / 64, B, 0, stream>>>((const unsigned short*)axb, w1t, wct, b1, hwb, N);

    // 5. z = Agg(hwb) + bias -> outputs
    k_gather64<<<(N + 3) / 4, B, 0, stream>>>(csr, rowptr, dinv, (const unsigned*)hwb, bm, bs, outm, outs, N);
}

// Round 10
// 307.201 us; speedup vs baseline: 11.4581x; 1.0233x over previous
//
#include <hip/hip_runtime.h>

// VGAE encoder: 3x GCNConv (improved=True), N=100000, E=1600000.
//   xb = bf16(x); ax = Agg(xb) [bf16]; hw = relu(ax@W1+b1)@[Wm|Ws] (MFMA, bf16 out);
//   z = Agg(hw) + [bm|bs]
// R10: quarter-wave interleaved gathers. R9 showed stream count is the lever but
// VALU hit 44%; quarter-split (16 lanes x uint4 per row) cuts wave-instrs/edge
// ~40% and runs 4 edges concurrently at VGPR<=64 (8 waves/SIMD preserved).

#define DIM 128
#define LAT 32
#define SCAN_ELEMS 1024   // 256 threads x 4
#define CPAD 32           // cursor padding stride (ints) = 128B line

typedef short bf16x8 __attribute__((ext_vector_type(8)));
typedef float f32x4 __attribute__((ext_vector_type(4)));

__device__ __forceinline__ unsigned short f2bf(float f) {   // RNE
    unsigned u = __float_as_uint(f);
    return (unsigned short)((u + 0x7fffu + ((u >> 16) & 1u)) >> 16);
}
__device__ __forceinline__ unsigned packbf(float a, float b) {
    return (unsigned)f2bf(a) | ((unsigned)f2bf(b) << 16);
}
__device__ __forceinline__ float2 bfp2f(unsigned u) {
    float2 r;
    r.x = __uint_as_float(u << 16);
    r.y = __uint_as_float(u & 0xffff0000u);
    return r;
}

// x [N,128] f32 -> packed bf16 pairs (uint2 per thread = 4 dims)
__global__ void k_x2bf(const float* __restrict__ x, uint2* __restrict__ xb, int n4) {
    int i = blockIdx.x * blockDim.x + threadIdx.x;
    if (i < n4) {
        float4 v = reinterpret_cast<const float4*>(x)[i];
        xb[i] = make_uint2(packbf(v.x, v.y), packbf(v.z, v.w));
    }
}

// pass 1: per-edge within-node rank; padded cursor (1 counter / 128B line)
__global__ void k_rank(const int* __restrict__ dst, int* __restrict__ cursorPad,
                       unsigned short* __restrict__ rank, int E) {
    int e = blockIdx.x * blockDim.x + threadIdx.x;
    if (e < E) rank[e] = (unsigned short)atomicAdd(&cursorPad[(size_t)dst[e] * CPAD], 1);
}

// ---- exclusive scan of padded counts -> rowptr ----
__global__ __launch_bounds__(256) void k_scan1(const int* __restrict__ countsPad,
                                               int* __restrict__ rowptr,
                                               int* __restrict__ bsums, int N) {
    __shared__ int sdata[256];
    const int t = threadIdx.x;
    const int base = blockIdx.x * SCAN_ELEMS + t * 4;
    int v[4];
#pragma unroll
    for (int j = 0; j < 4; ++j) {
        int idx = base + j;
        v[j] = (idx < N) ? countsPad[(size_t)idx * CPAD] : 0;
    }
    int tot = v[0] + v[1] + v[2] + v[3];
    sdata[t] = tot;
    __syncthreads();
    for (int off = 1; off < 256; off <<= 1) {
        int x = 0;
        if (t >= off) x = sdata[t - off];
        __syncthreads();
        if (t >= off) sdata[t] += x;
        __syncthreads();
    }
    int running = sdata[t] - tot;
#pragma unroll
    for (int j = 0; j < 4; ++j) {
        int idx = base + j;
        if (idx < N) rowptr[idx] = running;
        running += v[j];
    }
    if (t == 255) bsums[blockIdx.x] = sdata[255];
}

__global__ void k_scan2(int* __restrict__ bsums, int* __restrict__ rowptr, int NB, int N, int E) {
    int running = 0;
    for (int b = 0; b < NB; ++b) {
        int t = bsums[b];
        bsums[b] = running;
        running += t;
    }
    rowptr[N] = E;
}

__global__ void k_scan3(int* __restrict__ rowptr, const int* __restrict__ bsums, int N) {
    int i = blockIdx.x * blockDim.x + threadIdx.x;
    if (i < N) rowptr[i] += bsums[i >> 10];
}

// pass 2: place edges into CSR slots — NO atomics. record = {src, raw ew bits}
__global__ void k_place(const int* __restrict__ src, const int* __restrict__ dst,
                        const float* __restrict__ ew, const unsigned short* __restrict__ rank,
                        const int* __restrict__ rowptr, int2* __restrict__ csr, int E) {
    int e = blockIdx.x * blockDim.x + threadIdx.x;
    if (e < E)
        csr[rowptr[dst[e]] + rank[e]] = make_int2(src[e], __float_as_int(ew[e]));
}

// deg[i] = 2 + sum of incoming ew (from CSR, atomic-free) -> dinv in place
__global__ void k_degseg(const int2* __restrict__ csr, const int* __restrict__ rowptr,
                         float* __restrict__ dinv, int N) {
    int i = blockIdx.x * blockDim.x + threadIdx.x;
    if (i >= N) return;
    float deg = 2.0f;   // improved=True self-loop weight
    int p = rowptr[i], end = rowptr[i + 1];
    for (; p < end; ++p) deg += __int_as_float(csr[p].y);
    dinv[i] = (deg > 0.0f) ? rsqrtf(deg) : 0.0f;
}

// weight prep: w1t[c][k] = bf16(W1[k][c]); wct[c][k] = bf16([Wm|Ws][k][c])
__global__ void k_prep_w(const float* __restrict__ W1, const float* __restrict__ Wm,
                         const float* __restrict__ Ws, unsigned short* __restrict__ w1t,
                         unsigned short* __restrict__ wct) {
    int i = blockIdx.x * 256 + threadIdx.x;
    if (i < DIM * DIM) {
        int c = i >> 7, k = i & 127;
        w1t[c * DIM + k] = f2bf(W1[k * DIM + c]);
    }
    i -= DIM * DIM;
    if (i >= 0 && i < 64 * DIM) {
        int c = i >> 7, k = i & 127;
        wct[c * DIM + k] = f2bf((c < LAT) ? Wm[k * LAT + c] : Ws[k * LAT + (c - LAT)]);
    }
}

// wave per node; quarter q=lane>>4 handles edges p0+q, p0+q+4, ... (interleaved);
// 16 lanes x uint4 (16B) = 256B row; unroll-2 per quarter = 8 row-streams/wave,
// 4 edges concurrent. Combine quarters via shfl_xor(16/32); quarter 0 writes.
// Deferred norm: ax = di*(2*di*x[d] + sum ew*dinv[s]*x[s]).
__global__ __launch_bounds__(256) void k_gather128(const int2* __restrict__ csr,
                                                   const int* __restrict__ rowptr,
                                                   const float* __restrict__ dinv,
                                                   const uint4* __restrict__ xb,
                                                   uint4* __restrict__ axb, int N) {
    int node = (blockIdx.x * 256 + threadIdx.x) >> 6;
    int lane = threadIdx.x & 63;
    if (node >= N) return;
    const int q = lane >> 4;
    const int l = lane & 15;
    float di = dinv[node];
    float acc[8];
#pragma unroll
    for (int j = 0; j < 8; ++j) acc[j] = 0.f;
    if (q == 0) {                  // self-loop once
        uint4 sv = xb[(size_t)node * 16 + l];
        float sl = 2.0f * di;
        float2 s0 = bfp2f(sv.x), s1 = bfp2f(sv.y), s2 = bfp2f(sv.z), s3 = bfp2f(sv.w);
        acc[0] = s0.x * sl; acc[1] = s0.y * sl;
        acc[2] = s1.x * sl; acc[3] = s1.y * sl;
        acc[4] = s2.x * sl; acc[5] = s2.y * sl;
        acc[6] = s3.x * sl; acc[7] = s3.y * sl;
    }
    int p = rowptr[node] + q;
    int end = rowptr[node + 1];
    for (; p + 4 < end; p += 8) {       // unroll-2 within quarter (stride 4)
        int2 e0 = csr[p];
        int2 e1 = csr[p + 4];
        float n0 = __int_as_float(e0.y) * dinv[e0.x];
        float n1 = __int_as_float(e1.y) * dinv[e1.x];
        uint4 u0 = xb[(size_t)e0.x * 16 + l];
        uint4 u1 = xb[(size_t)e1.x * 16 + l];
        float2 a0 = bfp2f(u0.x), a1 = bfp2f(u0.y), a2 = bfp2f(u0.z), a3 = bfp2f(u0.w);
        acc[0] = fmaf(a0.x, n0, acc[0]); acc[1] = fmaf(a0.y, n0, acc[1]);
        acc[2] = fmaf(a1.x, n0, acc[2]); acc[3] = fmaf(a1.y, n0, acc[3]);
        acc[4] = fmaf(a2.x, n0, acc[4]); acc[5] = fmaf(a2.y, n0, acc[5]);
        acc[6] = fmaf(a3.x, n0, acc[6]); acc[7] = fmaf(a3.y, n0, acc[7]);
        float2 b0 = bfp2f(u1.x), b1 = bfp2f(u1.y), b2 = bfp2f(u1.z), b3 = bfp2f(u1.w);
        acc[0] = fmaf(b0.x, n1, acc[0]); acc[1] = fmaf(b0.y, n1, acc[1]);
        acc[2] = fmaf(b1.x, n1, acc[2]); acc[3] = fmaf(b1.y, n1, acc[3]);
        acc[4] = fmaf(b2.x, n1, acc[4]); acc[5] = fmaf(b2.y, n1, acc[5]);
        acc[6] = fmaf(b3.x, n1, acc[6]); acc[7] = fmaf(b3.y, n1, acc[7]);
    }
    if (p < end) {
        int2 e0 = csr[p];
        float n0 = __int_as_float(e0.y) * dinv[e0.x];
        uint4 u0 = xb[(size_t)e0.x * 16 + l];
        float2 a0 = bfp2f(u0.x), a1 = bfp2f(u0.y), a2 = bfp2f(u0.z), a3 = bfp2f(u0.w);
        acc[0] = fmaf(a0.x, n0, acc[0]); acc[1] = fmaf(a0.y, n0, acc[1]);
        acc[2] = fmaf(a1.x, n0, acc[2]); acc[3] = fmaf(a1.y, n0, acc[3]);
        acc[4] = fmaf(a2.x, n0, acc[4]); acc[5] = fmaf(a2.y, n0, acc[5]);
        acc[6] = fmaf(a3.x, n0, acc[6]); acc[7] = fmaf(a3.y, n0, acc[7]);
    }
#pragma unroll
    for (int j = 0; j < 8; ++j) {
        acc[j] += __shfl_xor(acc[j], 16);
        acc[j] += __shfl_xor(acc[j], 32);
    }
    if (q == 0) {
        uint4 o;
        o.x = packbf(acc[0] * di, acc[1] * di);
        o.y = packbf(acc[2] * di, acc[3] * di);
        o.z = packbf(acc[4] * di, acc[5] * di);
        o.w = packbf(acc[6] * di, acc[7] * di);
        axb[(size_t)node * 16 + l] = o;
    }
}

// MFMA MLP: hwb = bf16( relu(axb @ W1 + b1) @ Wcat ).  Block = 64 rows, 4 waves.
__global__ __launch_bounds__(256) void k_mfma_mlp(const unsigned short* __restrict__ axb,
                                                  const unsigned short* __restrict__ w1t,
                                                  const unsigned short* __restrict__ wct,
                                                  const float* __restrict__ b1,
                                                  unsigned short* __restrict__ hwb, int N) {
    __shared__ __align__(16) unsigned short hs[4][16][136];  // +8 pad: bank spread
    const int wave = threadIdx.x >> 6;
    const int lane = threadIdx.x & 63;
    const int lrow = lane & 15;
    const int lk = lane >> 4;            // 0..3
    const int R0 = blockIdx.x * 64 + wave * 16;
    const bool active = (R0 < N);        // N%16==0: active waves fully in-bounds

    if (active) {
        f32x4 acc[8];
#pragma unroll
        for (int t = 0; t < 8; ++t) acc[t] = (f32x4){0.f, 0.f, 0.f, 0.f};
        const unsigned short* arow = axb + (size_t)(R0 + lrow) * DIM + lk * 8;
#pragma unroll
        for (int kt = 0; kt < 4; ++kt) {
            bf16x8 a = *reinterpret_cast<const bf16x8*>(arow + kt * 32);
#pragma unroll
            for (int t = 0; t < 8; ++t) {
                bf16x8 b = *reinterpret_cast<const bf16x8*>(
                    w1t + (size_t)(t * 16 + lrow) * DIM + kt * 32 + lk * 8);
                acc[t] = __builtin_amdgcn_mfma_f32_16x16x32_bf16(a, b, acc[t], 0, 0, 0);
            }
        }
#pragma unroll
        for (int t = 0; t < 8; ++t) {
#pragma unroll
            for (int r = 0; r < 4; ++r) {
                int col = t * 16 + lrow;
                float v = acc[t][r] + b1[col];
                hs[wave][lk * 4 + r][col] = f2bf(v > 0.f ? v : 0.f);
            }
        }
    }
    __syncthreads();
    if (active) {
        f32x4 acc2[4];
#pragma unroll
        for (int t = 0; t < 4; ++t) acc2[t] = (f32x4){0.f, 0.f, 0.f, 0.f};
        const unsigned short* hrow = &hs[wave][lrow][0];
#pragma unroll
        for (int kt = 0; kt < 4; ++kt) {
            bf16x8 a = *reinterpret_cast<const bf16x8*>(hrow + kt * 32 + lk * 8);
#pragma unroll
            for (int t = 0; t < 4; ++t) {
                bf16x8 b = *reinterpret_cast<const bf16x8*>(
                    wct + (size_t)(t * 16 + lrow) * DIM + kt * 32 + lk * 8);
                acc2[t] = __builtin_amdgcn_mfma_f32_16x16x32_bf16(a, b, acc2[t], 0, 0, 0);
            }
        }
#pragma unroll
        for (int t = 0; t < 4; ++t)
#pragma unroll
            for (int r = 0; r < 4; ++r)
                hwb[(size_t)(R0 + lk * 4 + r) * 64 + t * 16 + lrow] = f2bf(acc2[t][r]);
    }
}

// wave per node; quarter-interleaved edges; 16 lanes x uint2 (8B) = 128B row;
// unroll-2 per quarter; shfl_xor(16/32) combine; quarter 0 writes float4.
__global__ __launch_bounds__(256) void k_gather64(const int2* __restrict__ csr,
                                                  const int* __restrict__ rowptr,
                                                  const float* __restrict__ dinv,
                                                  const uint2* __restrict__ hwb,
                                                  const float* __restrict__ bm,
                                                  const float* __restrict__ bs,
                                                  float* __restrict__ outm,
                                                  float* __restrict__ outs, int N) {
    int node = (blockIdx.x * 256 + threadIdx.x) >> 6;
    int lane = threadIdx.x & 63;
    if (node >= N) return;
    const int q = lane >> 4;
    const int l = lane & 15;          // dims 4l..4l+3
    float di = dinv[node];
    float acc[4];
#pragma unroll
    for (int j = 0; j < 4; ++j) acc[j] = 0.f;
    if (q == 0) {                     // self-loop once
        uint2 sv = hwb[(size_t)node * 16 + l];
        float sl = 2.0f * di;
        float2 s0 = bfp2f(sv.x), s1 = bfp2f(sv.y);
        acc[0] = s0.x * sl; acc[1] = s0.y * sl;
        acc[2] = s1.x * sl; acc[3] = s1.y * sl;
    }
    int p = rowptr[node] + q;
    int end = rowptr[node + 1];
    for (; p + 4 < end; p += 8) {
        int2 e0 = csr[p];
        int2 e1 = csr[p + 4];
        float n0 = __int_as_float(e0.y) * dinv[e0.x];
        float n1 = __int_as_float(e1.y) * dinv[e1.x];
        uint2 u0 = hwb[(size_t)e0.x * 16 + l];
        uint2 u1 = hwb[(size_t)e1.x * 16 + l];
        float2 a0 = bfp2f(u0.x), a1 = bfp2f(u0.y);
        float2 b0 = bfp2f(u1.x), b1 = bfp2f(u1.y);
        acc[0] = fmaf(a0.x, n0, acc[0]); acc[1] = fmaf(a0.y, n0, acc[1]);
        acc[2] = fmaf(a1.x, n0, acc[2]); acc[3] = fmaf(a1.y, n0, acc[3]);
        acc[0] = fmaf(b0.x, n1, acc[0]); acc[1] = fmaf(b0.y, n1, acc[1]);
        acc[2] = fmaf(b1.x, n1, acc[2]); acc[3] = fmaf(b1.y, n1, acc[3]);
    }
    if (p < end) {
        int2 e0 = csr[p];
        float n0 = __int_as_float(e0.y) * dinv[e0.x];
        uint2 u0 = hwb[(size_t)e0.x * 16 + l];
        float2 a0 = bfp2f(u0.x), a1 = bfp2f(u0.y);
        acc[0] = fmaf(a0.x, n0, acc[0]); acc[1] = fmaf(a0.y, n0, acc[1]);
        acc[2] = fmaf(a1.x, n0, acc[2]); acc[3] = fmaf(a1.y, n0, acc[3]);
    }
#pragma unroll
    for (int j = 0; j < 4; ++j) {
        acc[j] += __shfl_xor(acc[j], 16);
        acc[j] += __shfl_xor(acc[j], 32);
    }
    if (q == 0) {
        if (l < 8) {
            float4 bb = reinterpret_cast<const float4*>(bm)[l];
            float4 val;
            val.x = acc[0] * di + bb.x;
            val.y = acc[1] * di + bb.y;
            val.z = acc[2] * di + bb.z;
            val.w = acc[3] * di + bb.w;
            reinterpret_cast<float4*>(outm + (size_t)node * LAT)[l] = val;
        } else {
            float4 bb = reinterpret_cast<const float4*>(bs)[l - 8];
            float4 val;
            val.x = acc[0] * di + bb.x;
            val.y = acc[1] * di + bb.y;
            val.z = acc[2] * di + bb.z;
            val.w = acc[3] * di + bb.w;
            reinterpret_cast<float4*>(outs + (size_t)node * LAT)[l - 8] = val;
        }
    }
}

extern "C" void kernel_launch(void* const* d_in, const int* in_sizes, int n_in,
                              void* d_out, int out_size, void* d_ws, size_t ws_size,
                              hipStream_t stream) {
    const float* x  = (const float*)d_in[0];
    const int*   ei = (const int*)d_in[1];
    const float* ew = (const float*)d_in[2];
    const float* W1 = (const float*)d_in[3];
    const float* b1 = (const float*)d_in[4];
    const float* Wm = (const float*)d_in[5];
    const float* bm = (const float*)d_in[6];
    const float* Ws = (const float*)d_in[7];
    const float* bs = (const float*)d_in[8];

    const int N = in_sizes[0] / DIM;     // 100000
    const int E = in_sizes[1] / 2;       // 1600000
    const int* src = ei;
    const int* dst = ei + E;

    // ---- workspace layout (~94 MB) ----
    char* w = (char*)d_ws;
    unsigned* xb  = (unsigned*)w;            w += (size_t)N * DIM * 2;       // 25.6 MB bf16 x
    unsigned* axb = (unsigned*)w;            w += (size_t)N * DIM * 2;       // 25.6 MB bf16 ax
    unsigned short* hwb = (unsigned short*)w; w += (size_t)N * 64 * 2;       // 12.8 MB bf16 hw
    float* dinv = (float*)w;                 w += (size_t)N * 4;
    int*   rowptr = (int*)w;                 w += (size_t)(N + 1) * 4;
    unsigned short* rank = (unsigned short*)w; w += (size_t)E * 2;           // 3.2 MB
    w = (char*)(((size_t)w + 255) & ~(size_t)255);
    int*   bsums  = (int*)w;                 w += 1024 * 4;
    unsigned short* w1t = (unsigned short*)w; w += DIM * DIM * 2;            // 32 KB
    unsigned short* wct = (unsigned short*)w; w += 64 * DIM * 2;             // 16 KB
    w = (char*)(((size_t)w + 255) & ~(size_t)255);
    int*   cursorPad = (int*)w;              w += (size_t)N * CPAD * 4;      // 12.8 MB padded
    w = (char*)(((size_t)w + 255) & ~(size_t)255);
    int2*  csr    = (int2*)w;                // 12.8 MB

    float* outm = (float*)d_out;
    float* outs = outm + (size_t)N * LAT;

    const int B = 256;
    const int NB = (N + SCAN_ELEMS - 1) / SCAN_ELEMS;   // 98

    // 1. rank pass (padded cursor) + independent prep (x->bf16, weights)
    hipMemsetAsync(cursorPad, 0, (size_t)N * CPAD * 4, stream);
    k_rank<<<(E + B - 1) / B, B, 0, stream>>>(dst, cursorPad, rank, E);
    k_x2bf<<<((N * DIM / 4) + B - 1) / B, B, 0, stream>>>(x, (uint2*)xb, N * DIM / 4);
    k_prep_w<<<(DIM * DIM + 64 * DIM + B - 1) / B, B, 0, stream>>>(W1, Wm, Ws, w1t, wct);

    // 2. scan padded counts -> rowptr; place edges (atomic-free); deg -> dinv
    k_scan1<<<NB, B, 0, stream>>>(cursorPad, rowptr, bsums, N);
    k_scan2<<<1, 1, 0, stream>>>(bsums, rowptr, NB, N, E);
    k_scan3<<<(N + B - 1) / B, B, 0, stream>>>(rowptr, bsums, N);
    k_place<<<(E + B - 1) / B, B, 0, stream>>>(src, dst, ew, rank, rowptr, csr, E);
    k_degseg<<<(N + B - 1) / B, B, 0, stream>>>(csr, rowptr, dinv, N);

    // 3. ax = Agg(xb) -> bf16
    k_gather128<<<(N + 3) / 4, B, 0, stream>>>(csr, rowptr, dinv, (const uint4*)xb, (uint4*)axb, N);

    // 4. hwb = bf16( relu(ax@W1+b1) @ [Wm|Ws] )  (MFMA)
    k_mfma_mlp<<<(N + 63) / 64, B, 0, stream>>>((const unsigned short*)axb, w1t, wct, b1, hwb, N);

    // 5. z = Agg(hwb) + bias -> outputs
    k_gather64<<<(N + 3) / 4, B, 0, stream>>>(csr, rowptr, dinv, (const uint2*)hwb, bm, bs, outm, outs, N);
}

// Round 11
// 305.678 us; speedup vs baseline: 11.5152x; 1.0050x over previous
//
#include <hip/hip_runtime.h>

// VGAE encoder: 3x GCNConv (improved=True), N=100000, E=1600000.
//   xb = bf16(x); ax = Agg(xb) [bf16]; hw = relu(ax@W1+b1)@[Wm|Ws] (MFMA, bf16 out);
//   z = Agg(hw) + [bm|bs]
// R11: (a) fuse rank+x2bf+prep_w into one role-split kernel (stream serialization
// was hiding ~16us of independent work behind the atomic-bound rank); (b) drop
// scan2 (fold block-sum prefix into scan3); (c) unroll-4 per quarter in gathers.
// R10 lesson: cursor line-padding = null (atomic write-through is per-op) -> reverted.

#define DIM 128
#define LAT 32
#define SCAN_ELEMS 1024   // 256 threads x 4

typedef short bf16x8 __attribute__((ext_vector_type(8)));
typedef float f32x4 __attribute__((ext_vector_type(4)));

__device__ __forceinline__ unsigned short f2bf(float f) {   // RNE
    unsigned u = __float_as_uint(f);
    return (unsigned short)((u + 0x7fffu + ((u >> 16) & 1u)) >> 16);
}
__device__ __forceinline__ unsigned packbf(float a, float b) {
    return (unsigned)f2bf(a) | ((unsigned)f2bf(b) << 16);
}
__device__ __forceinline__ float2 bfp2f(unsigned u) {
    float2 r;
    r.x = __uint_as_float(u << 16);
    r.y = __uint_as_float(u & 0xffff0000u);
    return r;
}

// FUSED prep: blocks [0,RB): edge rank (4 edges/thread, 4 atomics in flight);
// [RB,RB+XB): x f32->bf16 (16 floats/thread); rest: weight transpose+cast.
__global__ __launch_bounds__(256) void k_prep(const int* __restrict__ dst,
                                              int* __restrict__ cursor,
                                              unsigned short* __restrict__ rank, int E,
                                              const float* __restrict__ x,
                                              uint4* __restrict__ xb,
                                              const float* __restrict__ W1,
                                              const float* __restrict__ Wm,
                                              const float* __restrict__ Ws,
                                              unsigned short* __restrict__ w1t,
                                              unsigned short* __restrict__ wct,
                                              int RB, int XB) {
    const int b = blockIdx.x;
    if (b < RB) {
        int idx = b * 1024 + threadIdx.x * 4;
        if (idx + 3 < E) {
            int4 d4 = *reinterpret_cast<const int4*>(dst + idx);
            unsigned short r0 = (unsigned short)atomicAdd(&cursor[d4.x], 1);
            unsigned short r1 = (unsigned short)atomicAdd(&cursor[d4.y], 1);
            unsigned short r2 = (unsigned short)atomicAdd(&cursor[d4.z], 1);
            unsigned short r3 = (unsigned short)atomicAdd(&cursor[d4.w], 1);
            ushort4 r = {r0, r1, r2, r3};
            *reinterpret_cast<ushort4*>(rank + idx) = r;
        } else {
            for (int j = 0; j < 4 && idx + j < E; ++j)
                rank[idx + j] = (unsigned short)atomicAdd(&cursor[dst[idx + j]], 1);
        }
    } else if (b < RB + XB) {
        // 16 consecutive floats -> 16 bf16 (two uint4)
        size_t i = ((size_t)(b - RB) * 256 + threadIdx.x) * 16;
        const float4* xin = reinterpret_cast<const float4*>(x + i);
        float4 v0 = xin[0], v1 = xin[1], v2 = xin[2], v3 = xin[3];
        uint4 o0, o1;
        o0.x = packbf(v0.x, v0.y); o0.y = packbf(v0.z, v0.w);
        o0.z = packbf(v1.x, v1.y); o0.w = packbf(v1.z, v1.w);
        o1.x = packbf(v2.x, v2.y); o1.y = packbf(v2.z, v2.w);
        o1.z = packbf(v3.x, v3.y); o1.w = packbf(v3.z, v3.w);
        xb[i / 8] = o0;
        xb[i / 8 + 1] = o1;
    } else {
        int i = (b - RB - XB) * 256 + threadIdx.x;
        if (i < DIM * DIM) {
            int c = i >> 7, k = i & 127;
            w1t[c * DIM + k] = f2bf(W1[k * DIM + c]);
        }
        i -= DIM * DIM;
        if (i >= 0 && i < 64 * DIM) {
            int c = i >> 7, k = i & 127;
            wct[c * DIM + k] = f2bf((c < LAT) ? Wm[k * LAT + c] : Ws[k * LAT + (c - LAT)]);
        }
    }
}

// ---- scan: per-block exclusive scan of counts -> rowptr + block sums ----
__global__ __launch_bounds__(256) void k_scan1(const int* __restrict__ counts,
                                               int* __restrict__ rowptr,
                                               int* __restrict__ bsums, int N) {
    __shared__ int sdata[256];
    const int t = threadIdx.x;
    const int base = blockIdx.x * SCAN_ELEMS + t * 4;
    int v[4];
#pragma unroll
    for (int j = 0; j < 4; ++j) {
        int idx = base + j;
        v[j] = (idx < N) ? counts[idx] : 0;
    }
    int tot = v[0] + v[1] + v[2] + v[3];
    sdata[t] = tot;
    __syncthreads();
    for (int off = 1; off < 256; off <<= 1) {
        int x = 0;
        if (t >= off) x = sdata[t - off];
        __syncthreads();
        if (t >= off) sdata[t] += x;
        __syncthreads();
    }
    int running = sdata[t] - tot;
#pragma unroll
    for (int j = 0; j < 4; ++j) {
        int idx = base + j;
        if (idx < N) rowptr[idx] = running;
        running += v[j];
    }
    if (t == 255) bsums[blockIdx.x] = sdata[255];
}

// scan fixup: each block recomputes prefix of bsums (tiny), adds to its tile.
__global__ __launch_bounds__(256) void k_scanfix(int* __restrict__ rowptr,
                                                 const int* __restrict__ bsums,
                                                 int N, int E) {
    __shared__ int pfx;
    if (threadIdx.x == 0) {
        int s = 0;
        for (int j = 0; j < (int)blockIdx.x; ++j) s += bsums[j];
        pfx = s;
        if (blockIdx.x == 0) rowptr[N] = E;
    }
    __syncthreads();
    int s = pfx;
    int base = blockIdx.x * SCAN_ELEMS + threadIdx.x * 4;
#pragma unroll
    for (int j = 0; j < 4; ++j) {
        int idx = base + j;
        if (idx < N) rowptr[idx] += s;
    }
}

// place edges into CSR slots — NO atomics. record = {src, raw ew bits}
__global__ void k_place(const int* __restrict__ src, const int* __restrict__ dst,
                        const float* __restrict__ ew, const unsigned short* __restrict__ rank,
                        const int* __restrict__ rowptr, int2* __restrict__ csr, int E) {
    int e = blockIdx.x * blockDim.x + threadIdx.x;
    if (e < E)
        csr[rowptr[dst[e]] + rank[e]] = make_int2(src[e], __float_as_int(ew[e]));
}

// deg[i] = 2 + sum of incoming ew (from CSR, atomic-free) -> dinv in place
__global__ void k_degseg(const int2* __restrict__ csr, const int* __restrict__ rowptr,
                         float* __restrict__ dinv, int N) {
    int i = blockIdx.x * blockDim.x + threadIdx.x;
    if (i >= N) return;
    float deg = 2.0f;   // improved=True self-loop weight
    int p = rowptr[i], end = rowptr[i + 1];
    for (; p < end; ++p) deg += __int_as_float(csr[p].y);
    dinv[i] = (deg > 0.0f) ? rsqrtf(deg) : 0.0f;
}

// wave per node; quarter q handles edges p0+q, p0+q+4,... (interleaved);
// 16 lanes x uint4 = 256B row; unroll-4 per quarter = 16 row-streams/wave.
// Combine quarters via shfl_xor(16/32); quarter 0 writes.
// Deferred norm: ax = di*(2*di*x[d] + sum ew*dinv[s]*x[s]).
__global__ __launch_bounds__(256) void k_gather128(const int2* __restrict__ csr,
                                                   const int* __restrict__ rowptr,
                                                   const float* __restrict__ dinv,
                                                   const uint4* __restrict__ xb,
                                                   uint4* __restrict__ axb, int N) {
    int node = (blockIdx.x * 256 + threadIdx.x) >> 6;
    int lane = threadIdx.x & 63;
    if (node >= N) return;
    const int q = lane >> 4;
    const int l = lane & 15;
    float di = dinv[node];
    float acc[8];
#pragma unroll
    for (int j = 0; j < 8; ++j) acc[j] = 0.f;
    if (q == 0) {                  // self-loop once
        uint4 sv = xb[(size_t)node * 16 + l];
        float sl = 2.0f * di;
        float2 s0 = bfp2f(sv.x), s1 = bfp2f(sv.y), s2 = bfp2f(sv.z), s3 = bfp2f(sv.w);
        acc[0] = s0.x * sl; acc[1] = s0.y * sl;
        acc[2] = s1.x * sl; acc[3] = s1.y * sl;
        acc[4] = s2.x * sl; acc[5] = s2.y * sl;
        acc[6] = s3.x * sl; acc[7] = s3.y * sl;
    }
    int p = rowptr[node] + q;
    int end = rowptr[node + 1];
    for (; p + 12 < end; p += 16) {     // unroll-4 within quarter (stride 4)
        int2 e0 = csr[p], e1 = csr[p + 4], e2 = csr[p + 8], e3 = csr[p + 12];
        float n0 = __int_as_float(e0.y) * dinv[e0.x];
        float n1 = __int_as_float(e1.y) * dinv[e1.x];
        float n2 = __int_as_float(e2.y) * dinv[e2.x];
        float n3 = __int_as_float(e3.y) * dinv[e3.x];
        uint4 u0 = xb[(size_t)e0.x * 16 + l];
        uint4 u1 = xb[(size_t)e1.x * 16 + l];
        uint4 u2 = xb[(size_t)e2.x * 16 + l];
        uint4 u3 = xb[(size_t)e3.x * 16 + l];
        {
            float2 a0 = bfp2f(u0.x), a1 = bfp2f(u0.y), a2 = bfp2f(u0.z), a3 = bfp2f(u0.w);
            acc[0] = fmaf(a0.x, n0, acc[0]); acc[1] = fmaf(a0.y, n0, acc[1]);
            acc[2] = fmaf(a1.x, n0, acc[2]); acc[3] = fmaf(a1.y, n0, acc[3]);
            acc[4] = fmaf(a2.x, n0, acc[4]); acc[5] = fmaf(a2.y, n0, acc[5]);
            acc[6] = fmaf(a3.x, n0, acc[6]); acc[7] = fmaf(a3.y, n0, acc[7]);
        }
        {
            float2 a0 = bfp2f(u1.x), a1 = bfp2f(u1.y), a2 = bfp2f(u1.z), a3 = bfp2f(u1.w);
            acc[0] = fmaf(a0.x, n1, acc[0]); acc[1] = fmaf(a0.y, n1, acc[1]);
            acc[2] = fmaf(a1.x, n1, acc[2]); acc[3] = fmaf(a1.y, n1, acc[3]);
            acc[4] = fmaf(a2.x, n1, acc[4]); acc[5] = fmaf(a2.y, n1, acc[5]);
            acc[6] = fmaf(a3.x, n1, acc[6]); acc[7] = fmaf(a3.y, n1, acc[7]);
        }
        {
            float2 a0 = bfp2f(u2.x), a1 = bfp2f(u2.y), a2 = bfp2f(u2.z), a3 = bfp2f(u2.w);
            acc[0] = fmaf(a0.x, n2, acc[0]); acc[1] = fmaf(a0.y, n2, acc[1]);
            acc[2] = fmaf(a1.x, n2, acc[2]); acc[3] = fmaf(a1.y, n2, acc[3]);
            acc[4] = fmaf(a2.x, n2, acc[4]); acc[5] = fmaf(a2.y, n2, acc[5]);
            acc[6] = fmaf(a3.x, n2, acc[6]); acc[7] = fmaf(a3.y, n2, acc[7]);
        }
        {
            float2 a0 = bfp2f(u3.x), a1 = bfp2f(u3.y), a2 = bfp2f(u3.z), a3 = bfp2f(u3.w);
            acc[0] = fmaf(a0.x, n3, acc[0]); acc[1] = fmaf(a0.y, n3, acc[1]);
            acc[2] = fmaf(a1.x, n3, acc[2]); acc[3] = fmaf(a1.y, n3, acc[3]);
            acc[4] = fmaf(a2.x, n3, acc[4]); acc[5] = fmaf(a2.y, n3, acc[5]);
            acc[6] = fmaf(a3.x, n3, acc[6]); acc[7] = fmaf(a3.y, n3, acc[7]);
        }
    }
    for (; p < end; p += 4) {
        int2 e0 = csr[p];
        float n0 = __int_as_float(e0.y) * dinv[e0.x];
        uint4 u0 = xb[(size_t)e0.x * 16 + l];
        float2 a0 = bfp2f(u0.x), a1 = bfp2f(u0.y), a2 = bfp2f(u0.z), a3 = bfp2f(u0.w);
        acc[0] = fmaf(a0.x, n0, acc[0]); acc[1] = fmaf(a0.y, n0, acc[1]);
        acc[2] = fmaf(a1.x, n0, acc[2]); acc[3] = fmaf(a1.y, n0, acc[3]);
        acc[4] = fmaf(a2.x, n0, acc[4]); acc[5] = fmaf(a2.y, n0, acc[5]);
        acc[6] = fmaf(a3.x, n0, acc[6]); acc[7] = fmaf(a3.y, n0, acc[7]);
    }
#pragma unroll
    for (int j = 0; j < 8; ++j) {
        acc[j] += __shfl_xor(acc[j], 16);
        acc[j] += __shfl_xor(acc[j], 32);
    }
    if (q == 0) {
        uint4 o;
        o.x = packbf(acc[0] * di, acc[1] * di);
        o.y = packbf(acc[2] * di, acc[3] * di);
        o.z = packbf(acc[4] * di, acc[5] * di);
        o.w = packbf(acc[6] * di, acc[7] * di);
        axb[(size_t)node * 16 + l] = o;
    }
}

// MFMA MLP: hwb = bf16( relu(axb @ W1 + b1) @ Wcat ).  Block = 64 rows, 4 waves.
__global__ __launch_bounds__(256) void k_mfma_mlp(const unsigned short* __restrict__ axb,
                                                  const unsigned short* __restrict__ w1t,
                                                  const unsigned short* __restrict__ wct,
                                                  const float* __restrict__ b1,
                                                  unsigned short* __restrict__ hwb, int N) {
    __shared__ __align__(16) unsigned short hs[4][16][136];  // +8 pad: bank spread
    const int wave = threadIdx.x >> 6;
    const int lane = threadIdx.x & 63;
    const int lrow = lane & 15;
    const int lk = lane >> 4;            // 0..3
    const int R0 = blockIdx.x * 64 + wave * 16;
    const bool active = (R0 < N);        // N%16==0: active waves fully in-bounds

    if (active) {
        f32x4 acc[8];
#pragma unroll
        for (int t = 0; t < 8; ++t) acc[t] = (f32x4){0.f, 0.f, 0.f, 0.f};
        const unsigned short* arow = axb + (size_t)(R0 + lrow) * DIM + lk * 8;
#pragma unroll
        for (int kt = 0; kt < 4; ++kt) {
            bf16x8 a = *reinterpret_cast<const bf16x8*>(arow + kt * 32);
#pragma unroll
            for (int t = 0; t < 8; ++t) {
                bf16x8 b = *reinterpret_cast<const bf16x8*>(
                    w1t + (size_t)(t * 16 + lrow) * DIM + kt * 32 + lk * 8);
                acc[t] = __builtin_amdgcn_mfma_f32_16x16x32_bf16(a, b, acc[t], 0, 0, 0);
            }
        }
#pragma unroll
        for (int t = 0; t < 8; ++t) {
#pragma unroll
            for (int r = 0; r < 4; ++r) {
                int col = t * 16 + lrow;
                float v = acc[t][r] + b1[col];
                hs[wave][lk * 4 + r][col] = f2bf(v > 0.f ? v : 0.f);
            }
        }
    }
    __syncthreads();
    if (active) {
        f32x4 acc2[4];
#pragma unroll
        for (int t = 0; t < 4; ++t) acc2[t] = (f32x4){0.f, 0.f, 0.f, 0.f};
        const unsigned short* hrow = &hs[wave][lrow][0];
#pragma unroll
        for (int kt = 0; kt < 4; ++kt) {
            bf16x8 a = *reinterpret_cast<const bf16x8*>(hrow + kt * 32 + lk * 8);
#pragma unroll
            for (int t = 0; t < 4; ++t) {
                bf16x8 b = *reinterpret_cast<const bf16x8*>(
                    wct + (size_t)(t * 16 + lrow) * DIM + kt * 32 + lk * 8);
                acc2[t] = __builtin_amdgcn_mfma_f32_16x16x32_bf16(a, b, acc2[t], 0, 0, 0);
            }
        }
#pragma unroll
        for (int t = 0; t < 4; ++t)
#pragma unroll
            for (int r = 0; r < 4; ++r)
                hwb[(size_t)(R0 + lk * 4 + r) * 64 + t * 16 + lrow] = f2bf(acc2[t][r]);
    }
}

// wave per node; quarter-interleaved edges; 16 lanes x uint2 = 128B row;
// unroll-4 per quarter = 16 streams; shfl_xor(16/32); quarter 0 writes float4.
__global__ __launch_bounds__(256) void k_gather64(const int2* __restrict__ csr,
                                                  const int* __restrict__ rowptr,
                                                  const float* __restrict__ dinv,
                                                  const uint2* __restrict__ hwb,
                                                  const float* __restrict__ bm,
                                                  const float* __restrict__ bs,
                                                  float* __restrict__ outm,
                                                  float* __restrict__ outs, int N) {
    int node = (blockIdx.x * 256 + threadIdx.x) >> 6;
    int lane = threadIdx.x & 63;
    if (node >= N) return;
    const int q = lane >> 4;
    const int l = lane & 15;          // dims 4l..4l+3
    float di = dinv[node];
    float acc[4];
#pragma unroll
    for (int j = 0; j < 4; ++j) acc[j] = 0.f;
    if (q == 0) {                     // self-loop once
        uint2 sv = hwb[(size_t)node * 16 + l];
        float sl = 2.0f * di;
        float2 s0 = bfp2f(sv.x), s1 = bfp2f(sv.y);
        acc[0] = s0.x * sl; acc[1] = s0.y * sl;
        acc[2] = s1.x * sl; acc[3] = s1.y * sl;
    }
    int p = rowptr[node] + q;
    int end = rowptr[node + 1];
    for (; p + 12 < end; p += 16) {
        int2 e0 = csr[p], e1 = csr[p + 4], e2 = csr[p + 8], e3 = csr[p + 12];
        float n0 = __int_as_float(e0.y) * dinv[e0.x];
        float n1 = __int_as_float(e1.y) * dinv[e1.x];
        float n2 = __int_as_float(e2.y) * dinv[e2.x];
        float n3 = __int_as_float(e3.y) * dinv[e3.x];
        uint2 u0 = hwb[(size_t)e0.x * 16 + l];
        uint2 u1 = hwb[(size_t)e1.x * 16 + l];
        uint2 u2 = hwb[(size_t)e2.x * 16 + l];
        uint2 u3 = hwb[(size_t)e3.x * 16 + l];
        float2 a0 = bfp2f(u0.x), a1 = bfp2f(u0.y);
        acc[0] = fmaf(a0.x, n0, acc[0]); acc[1] = fmaf(a0.y, n0, acc[1]);
        acc[2] = fmaf(a1.x, n0, acc[2]); acc[3] = fmaf(a1.y, n0, acc[3]);
        float2 b0 = bfp2f(u1.x), b1 = bfp2f(u1.y);
        acc[0] = fmaf(b0.x, n1, acc[0]); acc[1] = fmaf(b0.y, n1, acc[1]);
        acc[2] = fmaf(b1.x, n1, acc[2]); acc[3] = fmaf(b1.y, n1, acc[3]);
        float2 c0 = bfp2f(u2.x), c1 = bfp2f(u2.y);
        acc[0] = fmaf(c0.x, n2, acc[0]); acc[1] = fmaf(c0.y, n2, acc[1]);
        acc[2] = fmaf(c1.x, n2, acc[2]); acc[3] = fmaf(c1.y, n2, acc[3]);
        float2 d0 = bfp2f(u3.x), d1 = bfp2f(u3.y);
        acc[0] = fmaf(d0.x, n3, acc[0]); acc[1] = fmaf(d0.y, n3, acc[1]);
        acc[2] = fmaf(d1.x, n3, acc[2]); acc[3] = fmaf(d1.y, n3, acc[3]);
    }
    for (; p < end; p += 4) {
        int2 e0 = csr[p];
        float n0 = __int_as_float(e0.y) * dinv[e0.x];
        uint2 u0 = hwb[(size_t)e0.x * 16 + l];
        float2 a0 = bfp2f(u0.x), a1 = bfp2f(u0.y);
        acc[0] = fmaf(a0.x, n0, acc[0]); acc[1] = fmaf(a0.y, n0, acc[1]);
        acc[2] = fmaf(a1.x, n0, acc[2]); acc[3] = fmaf(a1.y, n0, acc[3]);
    }
#pragma unroll
    for (int j = 0; j < 4; ++j) {
        acc[j] += __shfl_xor(acc[j], 16);
        acc[j] += __shfl_xor(acc[j], 32);
    }
    if (q == 0) {
        if (l < 8) {
            float4 bb = reinterpret_cast<const float4*>(bm)[l];
            float4 val;
            val.x = acc[0] * di + bb.x;
            val.y = acc[1] * di + bb.y;
            val.z = acc[2] * di + bb.z;
            val.w = acc[3] * di + bb.w;
            reinterpret_cast<float4*>(outm + (size_t)node * LAT)[l] = val;
        } else {
            float4 bb = reinterpret_cast<const float4*>(bs)[l - 8];
            float4 val;
            val.x = acc[0] * di + bb.x;
            val.y = acc[1] * di + bb.y;
            val.z = acc[2] * di + bb.z;
            val.w = acc[3] * di + bb.w;
            reinterpret_cast<float4*>(outs + (size_t)node * LAT)[l - 8] = val;
        }
    }
}

extern "C" void kernel_launch(void* const* d_in, const int* in_sizes, int n_in,
                              void* d_out, int out_size, void* d_ws, size_t ws_size,
                              hipStream_t stream) {
    const float* x  = (const float*)d_in[0];
    const int*   ei = (const int*)d_in[1];
    const float* ew = (const float*)d_in[2];
    const float* W1 = (const float*)d_in[3];
    const float* b1 = (const float*)d_in[4];
    const float* Wm = (const float*)d_in[5];
    const float* bm = (const float*)d_in[6];
    const float* Ws = (const float*)d_in[7];
    const float* bs = (const float*)d_in[8];

    const int N = in_sizes[0] / DIM;     // 100000
    const int E = in_sizes[1] / 2;       // 1600000
    const int* src = ei;
    const int* dst = ei + E;

    // ---- workspace layout (~82 MB) ----
    char* w = (char*)d_ws;
    unsigned* xb  = (unsigned*)w;            w += (size_t)N * DIM * 2;       // 25.6 MB bf16 x
    unsigned* axb = (unsigned*)w;            w += (size_t)N * DIM * 2;       // 25.6 MB bf16 ax
    unsigned short* hwb = (unsigned short*)w; w += (size_t)N * 64 * 2;       // 12.8 MB bf16 hw
    float* dinv = (float*)w;                 w += (size_t)N * 4;
    int*   cursor = (int*)w;                 w += (size_t)N * 4;             // rank cursor == counts
    int*   rowptr = (int*)w;                 w += (size_t)(N + 1) * 4;
    unsigned short* rank = (unsigned short*)w; w += (size_t)E * 2;           // 3.2 MB
    w = (char*)(((size_t)w + 255) & ~(size_t)255);
    int*   bsums  = (int*)w;                 w += 1024 * 4;
    unsigned short* w1t = (unsigned short*)w; w += DIM * DIM * 2;            // 32 KB
    unsigned short* wct = (unsigned short*)w; w += 64 * DIM * 2;             // 16 KB
    w = (char*)(((size_t)w + 255) & ~(size_t)255);
    int2*  csr    = (int2*)w;                // 12.8 MB

    float* outm = (float*)d_out;
    float* outs = outm + (size_t)N * LAT;

    const int B = 256;
    const int NB = (N + SCAN_ELEMS - 1) / SCAN_ELEMS;   // 98
    const int RB = (E + 1023) / 1024;                   // 1563 rank blocks
    const int XB = (N * DIM / 16) / 256;                // 3125 x2bf blocks
    const int WB = (DIM * DIM + 64 * DIM) / 256;        // 96 weight blocks

    // 1. fused prep: rank (atomic-bound) overlapped with x->bf16 and weight prep
    hipMemsetAsync(cursor, 0, (size_t)N * 4, stream);
    k_prep<<<RB + XB + WB, B, 0, stream>>>(dst, cursor, rank, E, x, (uint4*)xb,
                                           W1, Wm, Ws, w1t, wct, RB, XB);

    // 2. scan counts -> rowptr (2 kernels); place edges (atomic-free); deg -> dinv
    k_scan1<<<NB, B, 0, stream>>>(cursor, rowptr, bsums, N);
    k_scanfix<<<NB, B, 0, stream>>>(rowptr, bsums, N, E);
    k_place<<<(E + B - 1) / B, B, 0, stream>>>(src, dst, ew, rank, rowptr, csr, E);
    k_degseg<<<(N + B - 1) / B, B, 0, stream>>>(csr, rowptr, dinv, N);

    // 3. ax = Agg(xb) -> bf16
    k_gather128<<<(N + 3) / 4, B, 0, stream>>>(csr, rowptr, dinv, (const uint4*)xb, (uint4*)axb, N);

    // 4. hwb = bf16( relu(ax@W1+b1) @ [Wm|Ws] )  (MFMA)
    k_mfma_mlp<<<(N + 63) / 64, B, 0, stream>>>((const unsigned short*)axb, w1t, wct, b1, hwb, N);

    // 5. z = Agg(hwb) + bias -> outputs
    k_gather64<<<(N + 3) / 4, B, 0, stream>>>(csr, rowptr, dinv, (const uint2*)hwb, bm, bs, outm, outs, N);
}

// Round 12
// 255.739 us; speedup vs baseline: 13.7638x; 1.1953x over previous
//
#include <hip/hip_runtime.h>

// VGAE encoder: 3x GCNConv (improved=True), N=100000, E=1600000.
//   xb = bf16(x); ax = Agg(xb); hw = relu(ax@W1+b1)@[Wm|Ws] (MFMA); z = Agg(hw)+[bm|bs]
// R12: ATOMIC-FREE CSR build via 2-level MSD bucket sort. Evidence: scattered
// device atomics ~22G/s (rank=70us) vs scattered writes ~64G/s (place=25us).
// New build: chunk-histogram(dst>>8) -> scan -> LDS-cursor scatter to buckets ->
// per-bucket exact placement + rowptr + dinv. Only LDS atomics (fast).

#define DIM 128
#define LAT 32
#define CHUNK 4096        // edges per histogram/scatter block
#define BSH 8             // bucket shift: bucket = dst>>8 (256 nodes/bucket)

typedef short bf16x8 __attribute__((ext_vector_type(8)));
typedef float f32x4 __attribute__((ext_vector_type(4)));

__device__ __forceinline__ unsigned short f2bf(float f) {   // RNE
    unsigned u = __float_as_uint(f);
    return (unsigned short)((u + 0x7fffu + ((u >> 16) & 1u)) >> 16);
}
__device__ __forceinline__ unsigned packbf(float a, float b) {
    return (unsigned)f2bf(a) | ((unsigned)f2bf(b) << 16);
}
__device__ __forceinline__ float2 bfp2f(unsigned u) {
    float2 r;
    r.x = __uint_as_float(u << 16);
    r.y = __uint_as_float(u & 0xffff0000u);
    return r;
}

// FUSED: blocks [0,NCH): per-chunk bucket histogram -> gh[bin*NCH+chunk];
// [NCH,NCH+XB): x f32->bf16; rest: weight transpose+cast.
__global__ __launch_bounds__(256) void k_hist(const int* __restrict__ dst, int E,
                                              int* __restrict__ gh, int NCH, int NBK,
                                              const float* __restrict__ x,
                                              uint4* __restrict__ xb,
                                              const float* __restrict__ W1,
                                              const float* __restrict__ Wm,
                                              const float* __restrict__ Ws,
                                              unsigned short* __restrict__ w1t,
                                              unsigned short* __restrict__ wct,
                                              int XB) {
    const int c = blockIdx.x;
    if (c < NCH) {
        __shared__ int h[512];
        for (int b = threadIdx.x; b < NBK; b += 256) h[b] = 0;
        __syncthreads();
        int end = min(E, (c + 1) * CHUNK);
        for (int e = c * CHUNK + threadIdx.x; e < end; e += 256)
            atomicAdd(&h[dst[e] >> BSH], 1);
        __syncthreads();
        for (int b = threadIdx.x; b < NBK; b += 256) gh[b * NCH + c] = h[b];
    } else if (c < NCH + XB) {
        size_t i = ((size_t)(c - NCH) * 256 + threadIdx.x) * 16;
        const float4* xin = reinterpret_cast<const float4*>(x + i);
        float4 v0 = xin[0], v1 = xin[1], v2 = xin[2], v3 = xin[3];
        uint4 o0, o1;
        o0.x = packbf(v0.x, v0.y); o0.y = packbf(v0.z, v0.w);
        o0.z = packbf(v1.x, v1.y); o0.w = packbf(v1.z, v1.w);
        o1.x = packbf(v2.x, v2.y); o1.y = packbf(v2.z, v2.w);
        o1.z = packbf(v3.x, v3.y); o1.w = packbf(v3.z, v3.w);
        xb[i / 8] = o0;
        xb[i / 8 + 1] = o1;
    } else {
        int i = (c - NCH - XB) * 256 + threadIdx.x;
        if (i < DIM * DIM) {
            int cc = i >> 7, k = i & 127;
            w1t[cc * DIM + k] = f2bf(W1[k * DIM + cc]);
        }
        i -= DIM * DIM;
        if (i >= 0 && i < 64 * DIM) {
            int cc = i >> 7, k = i & 127;
            wct[cc * DIM + k] = f2bf((cc < LAT) ? Wm[k * LAT + cc] : Ws[k * LAT + (cc - LAT)]);
        }
    }
}

// per-bucket total: btot[b] = sum over chunks of gh[b][*]
__global__ __launch_bounds__(256) void k_btot(const int* __restrict__ gh, int NCH,
                                              int* __restrict__ btot) {
    __shared__ int sdata[256];
    const int b = blockIdx.x;
    int sum = 0;
    for (int t = threadIdx.x; t < NCH; t += 256) sum += gh[b * NCH + t];
    sdata[threadIdx.x] = sum;
    __syncthreads();
    for (int off = 128; off > 0; off >>= 1) {
        if (threadIdx.x < off) sdata[threadIdx.x] += sdata[threadIdx.x + off];
        __syncthreads();
    }
    if (threadIdx.x == 0) btot[b] = sdata[0];
}

// per-bucket row scan: gh[b][c] -> bbase[b] + exclusive prefix (global positions).
// Each block serially rescans btot for its base (tiny), pair-per-thread HS scan.
__global__ __launch_bounds__(256) void k_rowscan(int* __restrict__ gh, int NCH, int NBK,
                                                 const int* __restrict__ btot,
                                                 int* __restrict__ bbase, int E) {
    __shared__ int sdata[256];
    __shared__ int basepfx;
    const int b = blockIdx.x;
    const int t = threadIdx.x;
    if (t == 0) {
        int s = 0;
        for (int j = 0; j < b; ++j) s += btot[j];
        basepfx = s;
        bbase[b] = s;
        if (b == NBK - 1) bbase[NBK] = s + btot[b];
    }
    __syncthreads();
    int i0 = 2 * t, i1 = 2 * t + 1;
    int v0 = (i0 < NCH) ? gh[b * NCH + i0] : 0;
    int v1 = (i1 < NCH) ? gh[b * NCH + i1] : 0;
    int tot = v0 + v1;
    sdata[t] = tot;
    __syncthreads();
    for (int off = 1; off < 256; off <<= 1) {
        int xv = 0;
        if (t >= off) xv = sdata[t - off];
        __syncthreads();
        if (t >= off) sdata[t] += xv;
        __syncthreads();
    }
    int pfx = basepfx + sdata[t] - tot;   // exclusive across pairs
    if (i0 < NCH) gh[b * NCH + i0] = pfx;
    if (i1 < NCH) gh[b * NCH + i1] = pfx + v0;
}

// scatter edges into bucket-ordered bkt[]: LDS cursors, NO global atomics.
// record = {src | (dst&255)<<17, ew bits}
__global__ __launch_bounds__(256) void k_bucket(const int* __restrict__ src,
                                                const int* __restrict__ dst,
                                                const float* __restrict__ ew,
                                                const int* __restrict__ gh, int NCH, int NBK,
                                                int2* __restrict__ bkt, int E) {
    __shared__ int cur[512];
    const int c = blockIdx.x;
    for (int b = threadIdx.x; b < NBK; b += 256) cur[b] = gh[b * NCH + c];
    __syncthreads();
    int end = min(E, (c + 1) * CHUNK);
    for (int e = c * CHUNK + threadIdx.x; e < end; e += 256) {
        int d = dst[e];
        int b = d >> BSH;
        int p = atomicAdd(&cur[b], 1);    // LDS atomic: fast
        bkt[p] = make_int2(src[e] | ((d & 255) << 17), __float_as_int(ew[e]));
    }
}

// per-bucket exact placement: rowptr + csr + deg/dinv, all LDS-local.
__global__ __launch_bounds__(256) void k_build(const int2* __restrict__ bkt,
                                               const int* __restrict__ bbase,
                                               int* __restrict__ rowptr,
                                               int2* __restrict__ csr,
                                               float* __restrict__ dinv, int N, int E) {
    __shared__ int cnt[256];
    __shared__ int offs[256];
    __shared__ int cnt2[256];
    __shared__ float degf[256];
    __shared__ int sdata[256];
    const int b = blockIdx.x;
    const int t = threadIdx.x;
    const int start = bbase[b], endb = bbase[b + 1];
    cnt[t] = 0; cnt2[t] = 0; degf[t] = 0.f;
    __syncthreads();
    for (int idx = start + t; idx < endb; idx += 256) {
        int2 rec = bkt[idx];
        int dl = (rec.x >> 17) & 255;
        atomicAdd(&cnt[dl], 1);
        atomicAdd(&degf[dl], __int_as_float(rec.y));
    }
    __syncthreads();
    int myc = cnt[t];
    sdata[t] = myc;
    __syncthreads();
    for (int off = 1; off < 256; off <<= 1) {
        int xv = 0;
        if (t >= off) xv = sdata[t - off];
        __syncthreads();
        if (t >= off) sdata[t] += xv;
        __syncthreads();
    }
    offs[t] = sdata[t] - myc;             // exclusive
    int node = (b << BSH) + t;
    if (node < N) {
        rowptr[node] = start + offs[t];
        float deg = 2.0f + degf[t];       // improved=True self-loop weight
        dinv[node] = (deg > 0.0f) ? rsqrtf(deg) : 0.0f;
    }
    if (b == 0 && t == 0) rowptr[N] = E;
    __syncthreads();
    for (int idx = start + t; idx < endb; idx += 256) {
        int2 rec = bkt[idx];
        int dl = (rec.x >> 17) & 255;
        int r = atomicAdd(&cnt2[dl], 1);
        csr[start + offs[dl] + r] = make_int2(rec.x & 0x1FFFF, rec.y);
    }
}

// wave per node; quarter q handles edges p0+q, p0+q+4,...; 16 lanes x uint4 = 256B row;
// unroll-4 per quarter; shfl_xor(16/32) combine; quarter 0 writes.
// Deferred norm: ax = di*(2*di*x[d] + sum ew*dinv[s]*x[s]).
__global__ __launch_bounds__(256) void k_gather128(const int2* __restrict__ csr,
                                                   const int* __restrict__ rowptr,
                                                   const float* __restrict__ dinv,
                                                   const uint4* __restrict__ xb,
                                                   uint4* __restrict__ axb, int N) {
    int node = (blockIdx.x * 256 + threadIdx.x) >> 6;
    int lane = threadIdx.x & 63;
    if (node >= N) return;
    const int q = lane >> 4;
    const int l = lane & 15;
    float di = dinv[node];
    float acc[8];
#pragma unroll
    for (int j = 0; j < 8; ++j) acc[j] = 0.f;
    if (q == 0) {                  // self-loop once
        uint4 sv = xb[(size_t)node * 16 + l];
        float sl = 2.0f * di;
        float2 s0 = bfp2f(sv.x), s1 = bfp2f(sv.y), s2 = bfp2f(sv.z), s3 = bfp2f(sv.w);
        acc[0] = s0.x * sl; acc[1] = s0.y * sl;
        acc[2] = s1.x * sl; acc[3] = s1.y * sl;
        acc[4] = s2.x * sl; acc[5] = s2.y * sl;
        acc[6] = s3.x * sl; acc[7] = s3.y * sl;
    }
    int p = rowptr[node] + q;
    int end = rowptr[node + 1];
    for (; p + 12 < end; p += 16) {
        int2 e0 = csr[p], e1 = csr[p + 4], e2 = csr[p + 8], e3 = csr[p + 12];
        float n0 = __int_as_float(e0.y) * dinv[e0.x];
        float n1 = __int_as_float(e1.y) * dinv[e1.x];
        float n2 = __int_as_float(e2.y) * dinv[e2.x];
        float n3 = __int_as_float(e3.y) * dinv[e3.x];
        uint4 u0 = xb[(size_t)e0.x * 16 + l];
        uint4 u1 = xb[(size_t)e1.x * 16 + l];
        uint4 u2 = xb[(size_t)e2.x * 16 + l];
        uint4 u3 = xb[(size_t)e3.x * 16 + l];
        {
            float2 a0 = bfp2f(u0.x), a1 = bfp2f(u0.y), a2 = bfp2f(u0.z), a3 = bfp2f(u0.w);
            acc[0] = fmaf(a0.x, n0, acc[0]); acc[1] = fmaf(a0.y, n0, acc[1]);
            acc[2] = fmaf(a1.x, n0, acc[2]); acc[3] = fmaf(a1.y, n0, acc[3]);
            acc[4] = fmaf(a2.x, n0, acc[4]); acc[5] = fmaf(a2.y, n0, acc[5]);
            acc[6] = fmaf(a3.x, n0, acc[6]); acc[7] = fmaf(a3.y, n0, acc[7]);
        }
        {
            float2 a0 = bfp2f(u1.x), a1 = bfp2f(u1.y), a2 = bfp2f(u1.z), a3 = bfp2f(u1.w);
            acc[0] = fmaf(a0.x, n1, acc[0]); acc[1] = fmaf(a0.y, n1, acc[1]);
            acc[2] = fmaf(a1.x, n1, acc[2]); acc[3] = fmaf(a1.y, n1, acc[3]);
            acc[4] = fmaf(a2.x, n1, acc[4]); acc[5] = fmaf(a2.y, n1, acc[5]);
            acc[6] = fmaf(a3.x, n1, acc[6]); acc[7] = fmaf(a3.y, n1, acc[7]);
        }
        {
            float2 a0 = bfp2f(u2.x), a1 = bfp2f(u2.y), a2 = bfp2f(u2.z), a3 = bfp2f(u2.w);
            acc[0] = fmaf(a0.x, n2, acc[0]); acc[1] = fmaf(a0.y, n2, acc[1]);
            acc[2] = fmaf(a1.x, n2, acc[2]); acc[3] = fmaf(a1.y, n2, acc[3]);
            acc[4] = fmaf(a2.x, n2, acc[4]); acc[5] = fmaf(a2.y, n2, acc[5]);
            acc[6] = fmaf(a3.x, n2, acc[6]); acc[7] = fmaf(a3.y, n2, acc[7]);
        }
        {
            float2 a0 = bfp2f(u3.x), a1 = bfp2f(u3.y), a2 = bfp2f(u3.z), a3 = bfp2f(u3.w);
            acc[0] = fmaf(a0.x, n3, acc[0]); acc[1] = fmaf(a0.y, n3, acc[1]);
            acc[2] = fmaf(a1.x, n3, acc[2]); acc[3] = fmaf(a1.y, n3, acc[3]);
            acc[4] = fmaf(a2.x, n3, acc[4]); acc[5] = fmaf(a2.y, n3, acc[5]);
            acc[6] = fmaf(a3.x, n3, acc[6]); acc[7] = fmaf(a3.y, n3, acc[7]);
        }
    }
    for (; p < end; p += 4) {
        int2 e0 = csr[p];
        float n0 = __int_as_float(e0.y) * dinv[e0.x];
        uint4 u0 = xb[(size_t)e0.x * 16 + l];
        float2 a0 = bfp2f(u0.x), a1 = bfp2f(u0.y), a2 = bfp2f(u0.z), a3 = bfp2f(u0.w);
        acc[0] = fmaf(a0.x, n0, acc[0]); acc[1] = fmaf(a0.y, n0, acc[1]);
        acc[2] = fmaf(a1.x, n0, acc[2]); acc[3] = fmaf(a1.y, n0, acc[3]);
        acc[4] = fmaf(a2.x, n0, acc[4]); acc[5] = fmaf(a2.y, n0, acc[5]);
        acc[6] = fmaf(a3.x, n0, acc[6]); acc[7] = fmaf(a3.y, n0, acc[7]);
    }
#pragma unroll
    for (int j = 0; j < 8; ++j) {
        acc[j] += __shfl_xor(acc[j], 16);
        acc[j] += __shfl_xor(acc[j], 32);
    }
    if (q == 0) {
        uint4 o;
        o.x = packbf(acc[0] * di, acc[1] * di);
        o.y = packbf(acc[2] * di, acc[3] * di);
        o.z = packbf(acc[4] * di, acc[5] * di);
        o.w = packbf(acc[6] * di, acc[7] * di);
        axb[(size_t)node * 16 + l] = o;
    }
}

// MFMA MLP: hwb = bf16( relu(axb @ W1 + b1) @ Wcat ).  Block = 64 rows, 4 waves.
__global__ __launch_bounds__(256) void k_mfma_mlp(const unsigned short* __restrict__ axb,
                                                  const unsigned short* __restrict__ w1t,
                                                  const unsigned short* __restrict__ wct,
                                                  const float* __restrict__ b1,
                                                  unsigned short* __restrict__ hwb, int N) {
    __shared__ __align__(16) unsigned short hs[4][16][136];  // +8 pad: bank spread
    const int wave = threadIdx.x >> 6;
    const int lane = threadIdx.x & 63;
    const int lrow = lane & 15;
    const int lk = lane >> 4;            // 0..3
    const int R0 = blockIdx.x * 64 + wave * 16;
    const bool active = (R0 < N);        // N%16==0: active waves fully in-bounds

    if (active) {
        f32x4 acc[8];
#pragma unroll
        for (int t = 0; t < 8; ++t) acc[t] = (f32x4){0.f, 0.f, 0.f, 0.f};
        const unsigned short* arow = axb + (size_t)(R0 + lrow) * DIM + lk * 8;
#pragma unroll
        for (int kt = 0; kt < 4; ++kt) {
            bf16x8 a = *reinterpret_cast<const bf16x8*>(arow + kt * 32);
#pragma unroll
            for (int t = 0; t < 8; ++t) {
                bf16x8 b = *reinterpret_cast<const bf16x8*>(
                    w1t + (size_t)(t * 16 + lrow) * DIM + kt * 32 + lk * 8);
                acc[t] = __builtin_amdgcn_mfma_f32_16x16x32_bf16(a, b, acc[t], 0, 0, 0);
            }
        }
#pragma unroll
        for (int t = 0; t < 8; ++t) {
#pragma unroll
            for (int r = 0; r < 4; ++r) {
                int col = t * 16 + lrow;
                float v = acc[t][r] + b1[col];
                hs[wave][lk * 4 + r][col] = f2bf(v > 0.f ? v : 0.f);
            }
        }
    }
    __syncthreads();
    if (active) {
        f32x4 acc2[4];
#pragma unroll
        for (int t = 0; t < 4; ++t) acc2[t] = (f32x4){0.f, 0.f, 0.f, 0.f};
        const unsigned short* hrow = &hs[wave][lrow][0];
#pragma unroll
        for (int kt = 0; kt < 4; ++kt) {
            bf16x8 a = *reinterpret_cast<const bf16x8*>(hrow + kt * 32 + lk * 8);
#pragma unroll
            for (int t = 0; t < 4; ++t) {
                bf16x8 b = *reinterpret_cast<const bf16x8*>(
                    wct + (size_t)(t * 16 + lrow) * DIM + kt * 32 + lk * 8);
                acc2[t] = __builtin_amdgcn_mfma_f32_16x16x32_bf16(a, b, acc2[t], 0, 0, 0);
            }
        }
#pragma unroll
        for (int t = 0; t < 4; ++t)
#pragma unroll
            for (int r = 0; r < 4; ++r)
                hwb[(size_t)(R0 + lk * 4 + r) * 64 + t * 16 + lrow] = f2bf(acc2[t][r]);
    }
}

// wave per node; quarter-interleaved edges; 16 lanes x uint2 = 128B row;
// unroll-4 per quarter; shfl_xor(16/32); quarter 0 writes float4.
__global__ __launch_bounds__(256) void k_gather64(const int2* __restrict__ csr,
                                                  const int* __restrict__ rowptr,
                                                  const float* __restrict__ dinv,
                                                  const uint2* __restrict__ hwb,
                                                  const float* __restrict__ bm,
                                                  const float* __restrict__ bs,
                                                  float* __restrict__ outm,
                                                  float* __restrict__ outs, int N) {
    int node = (blockIdx.x * 256 + threadIdx.x) >> 6;
    int lane = threadIdx.x & 63;
    if (node >= N) return;
    const int q = lane >> 4;
    const int l = lane & 15;          // dims 4l..4l+3
    float di = dinv[node];
    float acc[4];
#pragma unroll
    for (int j = 0; j < 4; ++j) acc[j] = 0.f;
    if (q == 0) {                     // self-loop once
        uint2 sv = hwb[(size_t)node * 16 + l];
        float sl = 2.0f * di;
        float2 s0 = bfp2f(sv.x), s1 = bfp2f(sv.y);
        acc[0] = s0.x * sl; acc[1] = s0.y * sl;
        acc[2] = s1.x * sl; acc[3] = s1.y * sl;
    }
    int p = rowptr[node] + q;
    int end = rowptr[node + 1];
    for (; p + 12 < end; p += 16) {
        int2 e0 = csr[p], e1 = csr[p + 4], e2 = csr[p + 8], e3 = csr[p + 12];
        float n0 = __int_as_float(e0.y) * dinv[e0.x];
        float n1 = __int_as_float(e1.y) * dinv[e1.x];
        float n2 = __int_as_float(e2.y) * dinv[e2.x];
        float n3 = __int_as_float(e3.y) * dinv[e3.x];
        uint2 u0 = hwb[(size_t)e0.x * 16 + l];
        uint2 u1 = hwb[(size_t)e1.x * 16 + l];
        uint2 u2 = hwb[(size_t)e2.x * 16 + l];
        uint2 u3 = hwb[(size_t)e3.x * 16 + l];
        float2 a0 = bfp2f(u0.x), a1 = bfp2f(u0.y);
        acc[0] = fmaf(a0.x, n0, acc[0]); acc[1] = fmaf(a0.y, n0, acc[1]);
        acc[2] = fmaf(a1.x, n0, acc[2]); acc[3] = fmaf(a1.y, n0, acc[3]);
        float2 b0 = bfp2f(u1.x), b1 = bfp2f(u1.y);
        acc[0] = fmaf(b0.x, n1, acc[0]); acc[1] = fmaf(b0.y, n1, acc[1]);
        acc[2] = fmaf(b1.x, n1, acc[2]); acc[3] = fmaf(b1.y, n1, acc[3]);
        float2 c0 = bfp2f(u2.x), c1 = bfp2f(u2.y);
        acc[0] = fmaf(c0.x, n2, acc[0]); acc[1] = fmaf(c0.y, n2, acc[1]);
        acc[2] = fmaf(c1.x, n2, acc[2]); acc[3] = fmaf(c1.y, n2, acc[3]);
        float2 d0 = bfp2f(u3.x), d1 = bfp2f(u3.y);
        acc[0] = fmaf(d0.x, n3, acc[0]); acc[1] = fmaf(d0.y, n3, acc[1]);
        acc[2] = fmaf(d1.x, n3, acc[2]); acc[3] = fmaf(d1.y, n3, acc[3]);
    }
    for (; p < end; p += 4) {
        int2 e0 = csr[p];
        float n0 = __int_as_float(e0.y) * dinv[e0.x];
        uint2 u0 = hwb[(size_t)e0.x * 16 + l];
        float2 a0 = bfp2f(u0.x), a1 = bfp2f(u0.y);
        acc[0] = fmaf(a0.x, n0, acc[0]); acc[1] = fmaf(a0.y, n0, acc[1]);
        acc[2] = fmaf(a1.x, n0, acc[2]); acc[3] = fmaf(a1.y, n0, acc[3]);
    }
#pragma unroll
    for (int j = 0; j < 4; ++j) {
        acc[j] += __shfl_xor(acc[j], 16);
        acc[j] += __shfl_xor(acc[j], 32);
    }
    if (q == 0) {
        if (l < 8) {
            float4 bb = reinterpret_cast<const float4*>(bm)[l];
            float4 val;
            val.x = acc[0] * di + bb.x;
            val.y = acc[1] * di + bb.y;
            val.z = acc[2] * di + bb.z;
            val.w = acc[3] * di + bb.w;
            reinterpret_cast<float4*>(outm + (size_t)node * LAT)[l] = val;
        } else {
            float4 bb = reinterpret_cast<const float4*>(bs)[l - 8];
            float4 val;
            val.x = acc[0] * di + bb.x;
            val.y = acc[1] * di + bb.y;
            val.z = acc[2] * di + bb.z;
            val.w = acc[3] * di + bb.w;
            reinterpret_cast<float4*>(outs + (size_t)node * LAT)[l - 8] = val;
        }
    }
}

extern "C" void kernel_launch(void* const* d_in, const int* in_sizes, int n_in,
                              void* d_out, int out_size, void* d_ws, size_t ws_size,
                              hipStream_t stream) {
    const float* x  = (const float*)d_in[0];
    const int*   ei = (const int*)d_in[1];
    const float* ew = (const float*)d_in[2];
    const float* W1 = (const float*)d_in[3];
    const float* b1 = (const float*)d_in[4];
    const float* Wm = (const float*)d_in[5];
    const float* bm = (const float*)d_in[6];
    const float* Ws = (const float*)d_in[7];
    const float* bs = (const float*)d_in[8];

    const int N = in_sizes[0] / DIM;     // 100000
    const int E = in_sizes[1] / 2;       // 1600000
    const int* src = ei;
    const int* dst = ei + E;

    const int NCH = (E + CHUNK - 1) / CHUNK;   // 391 chunks
    const int NBK = (N + 255) >> BSH;          // 391 buckets

    // ---- workspace layout (~91 MB) ----
    char* w = (char*)d_ws;
    unsigned* xb  = (unsigned*)w;            w += (size_t)N * DIM * 2;       // 25.6 MB bf16 x
    unsigned* axb = (unsigned*)w;            w += (size_t)N * DIM * 2;       // 25.6 MB bf16 ax
    unsigned short* hwb = (unsigned short*)w; w += (size_t)N * 64 * 2;       // 12.8 MB bf16 hw
    float* dinv = (float*)w;                 w += (size_t)N * 4;
    int*   rowptr = (int*)w;                 w += (size_t)(N + 1) * 4;
    w = (char*)(((size_t)w + 255) & ~(size_t)255);
    int*   gh    = (int*)w;                  w += (size_t)NBK * NCH * 4;     // 612 KB
    int*   btot  = (int*)w;                  w += (size_t)NBK * 4;
    int*   bbase = (int*)w;                  w += (size_t)(NBK + 1) * 4;
    w = (char*)(((size_t)w + 255) & ~(size_t)255);
    unsigned short* w1t = (unsigned short*)w; w += DIM * DIM * 2;            // 32 KB
    unsigned short* wct = (unsigned short*)w; w += 64 * DIM * 2;             // 16 KB
    w = (char*)(((size_t)w + 255) & ~(size_t)255);
    int2*  bkt   = (int2*)w;                 w += (size_t)E * 8;             // 12.8 MB
    w = (char*)(((size_t)w + 255) & ~(size_t)255);
    int2*  csr   = (int2*)w;                 // 12.8 MB

    float* outm = (float*)d_out;
    float* outs = outm + (size_t)N * LAT;

    const int B = 256;
    const int XB = (N * DIM / 16) / 256;                // 3125 x2bf blocks
    const int WB = (DIM * DIM + 64 * DIM) / 256;        // 96 weight blocks

    // 1. chunk histograms + x->bf16 + weight prep (fused, no atomics to global)
    k_hist<<<NCH + XB + WB, B, 0, stream>>>(dst, E, gh, NCH, NBK, x, (uint4*)xb,
                                            W1, Wm, Ws, w1t, wct, XB);
    // 2. bucket totals; scan gh in place to global positions
    k_btot<<<NBK, B, 0, stream>>>(gh, NCH, btot);
    k_rowscan<<<NBK, B, 0, stream>>>(gh, NCH, NBK, btot, bbase, E);
    // 3. scatter edges to bucket order (LDS cursors)
    k_bucket<<<NCH, B, 0, stream>>>(src, dst, ew, gh, NCH, NBK, bkt, E);
    // 4. per-bucket exact placement: rowptr, csr, dinv
    k_build<<<NBK, B, 0, stream>>>(bkt, bbase, rowptr, csr, dinv, N, E);

    // 5. ax = Agg(xb) -> bf16
    k_gather128<<<(N + 3) / 4, B, 0, stream>>>(csr, rowptr, dinv, (const uint4*)xb, (uint4*)axb, N);
    // 6. hwb = bf16( relu(ax@W1+b1) @ [Wm|Ws] )  (MFMA)
    k_mfma_mlp<<<(N + 63) / 64, B, 0, stream>>>((const unsigned short*)axb, w1t, wct, b1, hwb, N);
    // 7. z = Agg(hwb) + bias -> outputs
    k_gather64<<<(N + 3) / 4, B, 0, stream>>>(csr, rowptr, dinv, (const uint2*)hwb, bm, bs, outm, outs, N);
}